// Round 1
// baseline (1101.335 us; speedup 1.0000x reference)
//
#include <hip/hip_runtime.h>
#include <math.h>

#define T_DIM 256
#define B_DIM 32
#define N_DIM 64
#define F_INF 1024
#define D_T 272
#define H_DIM 8
#define DH_DIM 34
#define DFF_DIM 1024

// ---------------------------------------------------------------------------
// Elementwise: xn[b,n,t*4+d] = relu(x[t,b,n] * R_u[n*4+d])
// ---------------------------------------------------------------------------
__global__ void xn_kernel(const float* __restrict__ x, const float* __restrict__ Ru,
                          float* __restrict__ xn) {
    int idx = blockIdx.x * blockDim.x + threadIdx.x;
    if (idx >= B_DIM * N_DIM * F_INF) return;
    int f = idx & 1023;
    int bn = idx >> 10;
    int n = bn & 63;
    int b = bn >> 6;
    int t = f >> 2;
    int d = f & 3;
    float v = x[(t * B_DIM + b) * N_DIM + n] * Ru[(n << 2) + d];
    xn[idx] = fmaxf(v, 0.0f);
}

// ---------------------------------------------------------------------------
// Positional encoding: pe[t,b,0:8]=sin(times/scale_s), pe[t,b,8:16]=cos(...)
// ---------------------------------------------------------------------------
__global__ void pe_kernel(const float* __restrict__ times, float* __restrict__ pe) {
    int idx = blockIdx.x * blockDim.x + threadIdx.x;
    if (idx >= T_DIM * B_DIM * 8) return;
    int s = idx & 7;
    int tb = idx >> 3;
    float tv = times[tb];
    float scale = (float)pow(256.0, (double)s * (1.0 / 7.0));
    float st = tv / scale;
    pe[tb * 16 + s] = sinf(st);
    pe[tb * 16 + 8 + s] = cosf(st);
}

// ---------------------------------------------------------------------------
// Generic tiled f32 GEMM: C[M,N] = act(A[M,K] @ B[K,N] + bias[N])
// 64x64 tile, 256 threads, 4x4 per thread, K-tile 16. K must be %16, any M,N.
// ---------------------------------------------------------------------------
template <int ACT>
__global__ __launch_bounds__(256) void gemm_f32(const float* __restrict__ A,
                                                const float* __restrict__ B,
                                                const float* __restrict__ bias,
                                                float* __restrict__ C,
                                                int M, int N, int K) {
    __shared__ float As[16][64];
    __shared__ float Bs[16][64];
    const int n0 = blockIdx.x * 64;
    const int m0 = blockIdx.y * 64;
    const int tid = threadIdx.x;
    const int tx = tid & 15, ty = tid >> 4;
    float acc[4][4] = {};
    const int ar = tid >> 2;        // A row within tile (0..63)
    const int ac = (tid & 3) * 4;   // A k-col within tile (0,4,8,12)
    const int br = tid >> 4;        // B k-row within tile (0..15)
    const int bc = (tid & 15) * 4;  // B col within tile (0..60)

    for (int k0 = 0; k0 < K; k0 += 16) {
        // load A tile [64][16] -> As[k][m]
        {
            int gm = m0 + ar;
            float4 a4 = make_float4(0.f, 0.f, 0.f, 0.f);
            if (gm < M) a4 = *reinterpret_cast<const float4*>(&A[(size_t)gm * K + k0 + ac]);
            As[ac + 0][ar] = a4.x;
            As[ac + 1][ar] = a4.y;
            As[ac + 2][ar] = a4.z;
            As[ac + 3][ar] = a4.w;
        }
        // load B tile [16][64]
        {
            int gn = n0 + bc;
            int gk = k0 + br;
            float4 b4 = make_float4(0.f, 0.f, 0.f, 0.f);
            if (gn + 3 < N) {
                b4 = *reinterpret_cast<const float4*>(&B[(size_t)gk * N + gn]);
            } else {
                if (gn + 0 < N) b4.x = B[(size_t)gk * N + gn + 0];
                if (gn + 1 < N) b4.y = B[(size_t)gk * N + gn + 1];
                if (gn + 2 < N) b4.z = B[(size_t)gk * N + gn + 2];
            }
            *reinterpret_cast<float4*>(&Bs[br][bc]) = b4;
        }
        __syncthreads();
#pragma unroll
        for (int kk = 0; kk < 16; ++kk) {
            float a[4], b[4];
            *reinterpret_cast<float4*>(a) = *reinterpret_cast<const float4*>(&As[kk][ty * 4]);
            *reinterpret_cast<float4*>(b) = *reinterpret_cast<const float4*>(&Bs[kk][tx * 4]);
#pragma unroll
            for (int i = 0; i < 4; ++i)
#pragma unroll
                for (int j = 0; j < 4; ++j) acc[i][j] += a[i] * b[j];
        }
        __syncthreads();
    }
#pragma unroll
    for (int i = 0; i < 4; ++i) {
        int gm = m0 + ty * 4 + i;
        if (gm >= M) continue;
#pragma unroll
        for (int j = 0; j < 4; ++j) {
            int gn = n0 + tx * 4 + j;
            if (gn >= N) continue;
            float v = acc[i][j] + bias[gn];
            if (ACT == 1) v = fmaxf(v, 0.0f);
            C[(size_t)gm * N + gn] = v;
        }
    }
}

// ---------------------------------------------------------------------------
// s1[b,g] = (1/64) * sum_n val1[(b*64+n), g]
// ---------------------------------------------------------------------------
__global__ void reduce_s1_kernel(const float* __restrict__ val1, float* __restrict__ s1) {
    int idx = blockIdx.x * blockDim.x + threadIdx.x;
    if (idx >= B_DIM * F_INF) return;
    int b = idx >> 10;
    int g = idx & 1023;
    float s = 0.f;
#pragma unroll 8
    for (int n = 0; n < 64; ++n) s += val1[(size_t)((b << 6) + n) * F_INF + g];
    s1[idx] = s * (1.0f / 64.0f);
}

// ---------------------------------------------------------------------------
// seq[t,b,c] = (c<256) ? out2[b, t*4 + c%4] : pe[t,b,c-256]
// ---------------------------------------------------------------------------
__global__ void seq_kernel(const float* __restrict__ out2, const float* __restrict__ pe,
                           float* __restrict__ seq) {
    int idx = blockIdx.x * blockDim.x + threadIdx.x;
    if (idx >= T_DIM * B_DIM * D_T) return;
    int c = idx % D_T;
    int tb = idx / D_T;
    int b = tb % B_DIM;
    int t = tb / B_DIM;
    float v;
    if (c < 256)
        v = out2[b * 1024 + (t << 2) + (c & 3)];
    else
        v = pe[tb * 16 + (c - 256)];
    seq[idx] = v;
}

// ---------------------------------------------------------------------------
// Fused attention per (b,h): online softmax over valid (prefix) keys.
// One thread = one query row. K/V staged in LDS in 128-row chunks.
// ---------------------------------------------------------------------------
__global__ __launch_bounds__(256) void attn_kernel(const float* __restrict__ qkv,
                                                   const int* __restrict__ lengths,
                                                   float* __restrict__ attno) {
    const int bh = blockIdx.x;
    const int b = bh / H_DIM;
    const int h = bh % H_DIM;
    const int tid = threadIdx.x;  // query row
    __shared__ float Ks[128 * DH_DIM];
    __shared__ float Vs[128 * DH_DIM];
    const int len = lengths[b];
    const float scale = 1.0f / sqrtf(34.0f);

    float q[DH_DIM];
    const float* qp = &qkv[(size_t)(tid * B_DIM + b) * 816 + h * DH_DIM];
#pragma unroll
    for (int d = 0; d < DH_DIM; ++d) q[d] = qp[d];

    float m = -1e30f, l = 0.f;
    float acc[DH_DIM];
#pragma unroll
    for (int d = 0; d < DH_DIM; ++d) acc[d] = 0.f;

    for (int c0 = 0; c0 < T_DIM; c0 += 128) {
        __syncthreads();
        for (int idx = tid; idx < 128 * DH_DIM; idx += 256) {
            int j = idx / DH_DIM;
            int d = idx % DH_DIM;
            size_t row = (size_t)((c0 + j) * B_DIM + b) * 816;
            Ks[idx] = qkv[row + 272 + h * DH_DIM + d];
            Vs[idx] = qkv[row + 544 + h * DH_DIM + d];
        }
        __syncthreads();
        int jmax = len - c0;
        if (jmax > 128) jmax = 128;
        for (int j = 0; j < jmax; ++j) {
            const float* kp = &Ks[j * DH_DIM];
            float s = 0.f;
#pragma unroll
            for (int d = 0; d < DH_DIM; ++d) s += q[d] * kp[d];
            s *= scale;
            const float* vp = &Vs[j * DH_DIM];
            if (s > m) {
                float corr = expf(m - s);
                l = l * corr + 1.0f;
#pragma unroll
                for (int d = 0; d < DH_DIM; ++d) acc[d] = acc[d] * corr + vp[d];
                m = s;
            } else {
                float w = expf(s - m);
                l += w;
#pragma unroll
                for (int d = 0; d < DH_DIM; ++d) acc[d] += w * vp[d];
            }
        }
    }
    float inv = 1.0f / l;
    float* op = &attno[(size_t)(tid * B_DIM + b) * D_T + h * DH_DIM];
#pragma unroll
    for (int d = 0; d < DH_DIM; ++d) op[d] = acc[d] * inv;
}

// ---------------------------------------------------------------------------
// out[row,:] = LN(X[row,:] + Y[row,:]) * w + b   (row = t*B+b, width 272)
// one wave per row
// ---------------------------------------------------------------------------
__global__ __launch_bounds__(64) void ln_kernel(const float* __restrict__ X,
                                                const float* __restrict__ Y,
                                                const float* __restrict__ w,
                                                const float* __restrict__ bsh,
                                                float* __restrict__ out) {
    int row = blockIdx.x;
    int tid = threadIdx.x;
    const float* xr = X + (size_t)row * D_T;
    const float* yr = Y + (size_t)row * D_T;
    float v[5];
    float sum = 0.f, sumsq = 0.f;
#pragma unroll
    for (int k = 0; k < 5; ++k) {
        int c = tid + k * 64;
        float t = 0.f;
        if (c < D_T) t = xr[c] + yr[c];
        v[k] = t;
        sum += t;
        sumsq += t * t;
    }
#pragma unroll
    for (int off = 32; off; off >>= 1) {
        sum += __shfl_down(sum, off);
        sumsq += __shfl_down(sumsq, off);
    }
    sum = __shfl(sum, 0);
    sumsq = __shfl(sumsq, 0);
    float mu = sum * (1.0f / D_T);
    float var = sumsq * (1.0f / D_T) - mu * mu;
    float inv = 1.0f / sqrtf(var + 1e-5f);
    float* orow = out + (size_t)row * D_T;
#pragma unroll
    for (int k = 0; k < 5; ++k) {
        int c = tid + k * 64;
        if (c < D_T) orow[c] = (v[k] - mu) * inv * w[c] + bsh[c];
    }
}

// ---------------------------------------------------------------------------
// agg[b,c] = sum_{t<len_b} seq[t,b,c] / (len_b + 1)
// ---------------------------------------------------------------------------
__global__ void pool_kernel(const float* __restrict__ seq, const int* __restrict__ lengths,
                            float* __restrict__ agg) {
    int idx = blockIdx.x * blockDim.x + threadIdx.x;
    if (idx >= B_DIM * D_T) return;
    int b = idx / D_T;
    int c = idx % D_T;
    int len = lengths[b];
    float s = 0.f;
    for (int t = 0; t < len; ++t) s += seq[(size_t)(t * B_DIM + b) * D_T + c];
    agg[idx] = s / (float)(len + 1);
}

// ---------------------------------------------------------------------------
// Head: hid = relu(agg @ w1 + b1); logits = hid @ w2 + b2; softmax -> out
// one block per batch element
// ---------------------------------------------------------------------------
__global__ __launch_bounds__(320) void head_kernel(const float* __restrict__ agg,
                                                   const float* __restrict__ w1,
                                                   const float* __restrict__ b1,
                                                   const float* __restrict__ w2,
                                                   const float* __restrict__ b2,
                                                   float* __restrict__ out) {
    int b = blockIdx.x;
    int tid = threadIdx.x;
    __shared__ float hid[D_T];
    __shared__ float arow[D_T];
    if (tid < D_T) arow[tid] = agg[b * D_T + tid];
    __syncthreads();
    if (tid < D_T) {
        float s = b1[tid];
        for (int k = 0; k < D_T; ++k) s += arow[k] * w1[k * D_T + tid];
        hid[tid] = fmaxf(s, 0.f);
    }
    __syncthreads();
    if (tid == 0) {
        float l0 = b2[0], l1 = b2[1];
        for (int k = 0; k < D_T; ++k) {
            l0 += hid[k] * w2[k * 2 + 0];
            l1 += hid[k] * w2[k * 2 + 1];
        }
        float mx = fmaxf(l0, l1);
        float e0 = expf(l0 - mx), e1 = expf(l1 - mx);
        float inv = 1.0f / (e0 + e1);
        out[b * 2 + 0] = e0 * inv;
        out[b * 2 + 1] = e1 * inv;
    }
}

// ---------------------------------------------------------------------------
extern "C" void kernel_launch(void* const* d_in, const int* in_sizes, int n_in,
                              void* d_out, int out_size, void* d_ws, size_t ws_size,
                              hipStream_t stream) {
    const float* x      = (const float*)d_in[0];
    const float* times  = (const float*)d_in[1];
    const int*   lens   = (const int*)d_in[2];
    const float* R_u    = (const float*)d_in[3];
    const float* Wv1    = (const float*)d_in[4];
    const float* bv1    = (const float*)d_in[5];
    const float* Wv2    = (const float*)d_in[6];
    const float* bv2    = (const float*)d_in[7];
    const float* qkv_w  = (const float*)d_in[8];
    const float* qkv_b  = (const float*)d_in[9];
    const float* out_w  = (const float*)d_in[10];
    const float* out_b  = (const float*)d_in[11];
    const float* ln1_w  = (const float*)d_in[12];
    const float* ln1_b  = (const float*)d_in[13];
    const float* ln2_w  = (const float*)d_in[14];
    const float* ln2_b  = (const float*)d_in[15];
    const float* ffn_w1 = (const float*)d_in[16];
    const float* ffn_b1 = (const float*)d_in[17];
    const float* ffn_w2 = (const float*)d_in[18];
    const float* ffn_b2 = (const float*)d_in[19];
    const float* mlp_w1 = (const float*)d_in[20];
    const float* mlp_b1 = (const float*)d_in[21];
    const float* mlp_w2 = (const float*)d_in[22];
    const float* mlp_b2 = (const float*)d_in[23];
    float* outp = (float*)d_out;

    // workspace layout (floats)
    float* ws = (float*)d_ws;
    size_t off = 0;
    float* xn    = ws + off; off += (size_t)B_DIM * N_DIM * F_INF;  // 2,097,152
    float* val1  = ws + off; off += (size_t)B_DIM * N_DIM * F_INF;  // 2,097,152
    float* s1    = ws + off; off += (size_t)B_DIM * F_INF;          // 32,768
    float* out2  = ws + off; off += (size_t)B_DIM * F_INF;          // 32,768
    float* pe    = ws + off; off += (size_t)T_DIM * B_DIM * 16;     // 131,072
    float* seq   = ws + off; off += (size_t)T_DIM * B_DIM * D_T;    // 2,228,224
    float* qkvb  = ws + off; off += (size_t)T_DIM * B_DIM * 816;    // 6,684,672
    float* attno = ws + off; off += (size_t)T_DIM * B_DIM * D_T;
    float* tmp   = ws + off; off += (size_t)T_DIM * B_DIM * D_T;
    float* x1    = ws + off; off += (size_t)T_DIM * B_DIM * D_T;
    float* h1    = ws + off; off += (size_t)T_DIM * B_DIM * DFF_DIM; // 8,388,608
    float* agg   = ws + off; off += (size_t)B_DIM * D_T;
    if (ws_size < off * sizeof(float)) return;  // workspace too small

    const int TB = T_DIM * B_DIM;  // 8192 rows

    // Stage A: embeddings
    {
        int n = B_DIM * N_DIM * F_INF;
        xn_kernel<<<(n + 255) / 256, 256, 0, stream>>>(x, R_u, xn);
        int npe = T_DIM * B_DIM * 8;
        pe_kernel<<<(npe + 255) / 256, 256, 0, stream>>>(times, pe);
    }

    // Stage B: prop1 GEMM + reduce
    gemm_f32<1><<<dim3(1024 / 64, 2048 / 64), 256, 0, stream>>>(xn, Wv1, bv1, val1,
                                                                2048, 1024, 1024);
    {
        int n = B_DIM * F_INF;
        reduce_s1_kernel<<<(n + 255) / 256, 256, 0, stream>>>(val1, s1);
    }

    // Stage C: prop2 collapsed: out2 = relu(s1 @ Wv2 + bv2)   [32,1024]
    gemm_f32<1><<<dim3(1024 / 64, 1), 256, 0, stream>>>(s1, Wv2, bv2, out2, 32, 1024, 1024);

    // Stage D: build sequence [T,B,272]
    {
        int n = TB * D_T;
        seq_kernel<<<(n + 255) / 256, 256, 0, stream>>>(out2, pe, seq);
    }

    // Stage E: transformer layers
    for (int l = 0; l < 2; ++l) {
        const float* qw = qkv_w + (size_t)l * D_T * 816;
        const float* qb = qkv_b + (size_t)l * 816;
        const float* ow = out_w + (size_t)l * D_T * D_T;
        const float* ob = out_b + (size_t)l * D_T;
        const float* l1w = ln1_w + (size_t)l * D_T;
        const float* l1b = ln1_b + (size_t)l * D_T;
        const float* l2w = ln2_w + (size_t)l * D_T;
        const float* l2b = ln2_b + (size_t)l * D_T;
        const float* f1w = ffn_w1 + (size_t)l * D_T * DFF_DIM;
        const float* f1b = ffn_b1 + (size_t)l * DFF_DIM;
        const float* f2w = ffn_w2 + (size_t)l * DFF_DIM * D_T;
        const float* f2b = ffn_b2 + (size_t)l * D_T;

        // QKV: [8192,272]@[272,816]
        gemm_f32<0><<<dim3((816 + 63) / 64, TB / 64), 256, 0, stream>>>(seq, qw, qb, qkvb,
                                                                        TB, 816, D_T);
        // fused attention
        attn_kernel<<<B_DIM * H_DIM, 256, 0, stream>>>(qkvb, lens, attno);
        // out-proj: [8192,272]@[272,272]
        gemm_f32<0><<<dim3((D_T + 63) / 64, TB / 64), 256, 0, stream>>>(attno, ow, ob, tmp,
                                                                        TB, D_T, D_T);
        // x1 = LN(seq + tmp)
        ln_kernel<<<TB, 64, 0, stream>>>(seq, tmp, l1w, l1b, x1);
        // FFN1: relu([8192,272]@[272,1024])
        gemm_f32<1><<<dim3(DFF_DIM / 64, TB / 64), 256, 0, stream>>>(x1, f1w, f1b, h1,
                                                                     TB, DFF_DIM, D_T);
        // FFN2: [8192,1024]@[1024,272]
        gemm_f32<0><<<dim3((D_T + 63) / 64, TB / 64), 256, 0, stream>>>(h1, f2w, f2b, tmp,
                                                                        TB, D_T, DFF_DIM);
        // seq = LN(x1 + tmp)
        ln_kernel<<<TB, 64, 0, stream>>>(x1, tmp, l2w, l2b, seq);
    }

    // Stage F: masked mean pool
    {
        int n = B_DIM * D_T;
        pool_kernel<<<(n + 255) / 256, 256, 0, stream>>>(seq, lens, agg);
    }

    // Stage G: head + softmax
    head_kernel<<<B_DIM, 320, 0, stream>>>(agg, mlp_w1, mlp_b1, mlp_w2, mlp_b2, outp);
}

// Round 2
// 760.408 us; speedup vs baseline: 1.4483x; 1.4483x over previous
//
#include <hip/hip_runtime.h>
#include <math.h>

#define T_DIM 256
#define B_DIM 32
#define N_DIM 64
#define F_INF 1024
#define D_T 272
#define H_DIM 8
#define DH_DIM 34
#define DFF_DIM 1024

typedef unsigned int uint;
typedef short bf16x8 __attribute__((ext_vector_type(8)));
typedef float f32x4 __attribute__((ext_vector_type(4)));

__device__ __forceinline__ ushort f2bf(float f) {
    uint u = __float_as_uint(f);
    uint r = (u + 0x7fffu + ((u >> 16) & 1u)) >> 16;
    return (ushort)r;
}
__device__ __forceinline__ float bf2f(ushort u) {
    return __uint_as_float(((uint)u) << 16);
}

// ---------------------------------------------------------------------------
// xn[b,n,t*4+d] = relu(x[t,b,n] * R_u[n*4+d])  -> bf16
// ---------------------------------------------------------------------------
__global__ void xn_kernel(const float* __restrict__ x, const float* __restrict__ Ru,
                          ushort* __restrict__ xn) {
    int idx = blockIdx.x * blockDim.x + threadIdx.x;
    if (idx >= B_DIM * N_DIM * F_INF) return;
    int f = idx & 1023;
    int bn = idx >> 10;
    int n = bn & 63;
    int b = bn >> 6;
    int t = f >> 2;
    int d = f & 3;
    float v = x[(t * B_DIM + b) * N_DIM + n] * Ru[(n << 2) + d];
    xn[idx] = f2bf(fmaxf(v, 0.0f));
}

// ---------------------------------------------------------------------------
// positional encoding (f32)
// ---------------------------------------------------------------------------
__global__ void pe_kernel(const float* __restrict__ times, float* __restrict__ pe) {
    int idx = blockIdx.x * blockDim.x + threadIdx.x;
    if (idx >= T_DIM * B_DIM * 8) return;
    int s = idx & 7;
    int tb = idx >> 3;
    float tv = times[tb];
    float scale = (float)pow(256.0, (double)s * (1.0 / 7.0));
    float st = tv / scale;
    pe[tb * 16 + s] = sinf(st);
    pe[tb * 16 + 8 + s] = cosf(st);
}

// ---------------------------------------------------------------------------
// weight convert + transpose: in f32 [K,N] -> out bf16 [N,K]
// ---------------------------------------------------------------------------
__global__ void wconv_kernel(const float* __restrict__ in, ushort* __restrict__ out,
                             int K, int N) {
    int idx = blockIdx.x * blockDim.x + threadIdx.x;
    if (idx >= K * N) return;
    int k = idx / N;
    int n = idx - k * N;
    out[n * K + k] = f2bf(in[idx]);
}

// ---------------------------------------------------------------------------
// MFMA bf16 GEMM: C[M,N] = act(A[M,K] @ Bt[N,K]^T + bias[N])
// BM=128, BN=128, BK=32, 256 threads (4 waves, each 64x64).
// K-tail / N-tail zero-padded in LDS; row/col-guarded stores.
// ---------------------------------------------------------------------------
template <int ACT, int OUT_BF16>
__global__ __launch_bounds__(256) void gemm_mfma(const ushort* __restrict__ A,
                                                 const ushort* __restrict__ Bt,
                                                 const float* __restrict__ bias,
                                                 void* __restrict__ Cout,
                                                 int M, int N, int K) {
    __shared__ ushort As[128 * 32];
    __shared__ ushort Bs[128 * 32];
    const int tid = threadIdx.x;
    const int m0 = blockIdx.y * 128;
    const int n0 = blockIdx.x * 128;
    const int w = tid >> 6, lane = tid & 63;
    const int wm = (w >> 1) * 64, wn = (w & 1) * 64;
    const int lr = lane & 15, lk = lane >> 4;

    f32x4 acc[4][4];
#pragma unroll
    for (int i = 0; i < 4; ++i)
#pragma unroll
        for (int j = 0; j < 4; ++j) acc[i][j] = (f32x4){0.f, 0.f, 0.f, 0.f};

    const int sr = tid >> 2;        // staging row 0..63 (and +64)
    const int sc = (tid & 3) * 8;   // staging k-col 0,8,16,24
    const int schunk = sc >> 3;

    for (int k0 = 0; k0 < K; k0 += 32) {
        __syncthreads();
        // ---- stage A rows sr, sr+64 ----
#pragma unroll
        for (int rr = 0; rr < 2; ++rr) {
            int r = sr + rr * 64;
            int gm = m0 + r;
            int gk = k0 + sc;
            ushort v[8];
            if (gm < M && gk + 7 < K) {
                *reinterpret_cast<uint4*>(v) =
                    *reinterpret_cast<const uint4*>(&A[(size_t)gm * K + gk]);
            } else {
#pragma unroll
                for (int e = 0; e < 8; ++e) {
                    int kk = gk + e;
                    v[e] = (gm < M && kk < K) ? A[(size_t)gm * K + kk] : (ushort)0;
                }
            }
            int ch = schunk ^ ((r >> 1) & 3);
            *reinterpret_cast<uint4*>(&As[r * 32 + ch * 8]) = *reinterpret_cast<uint4*>(v);
        }
        // ---- stage Bt rows sr, sr+64 ----
#pragma unroll
        for (int rr = 0; rr < 2; ++rr) {
            int r = sr + rr * 64;
            int gn = n0 + r;
            int gk = k0 + sc;
            ushort v[8];
            if (gn < N && gk + 7 < K) {
                *reinterpret_cast<uint4*>(v) =
                    *reinterpret_cast<const uint4*>(&Bt[(size_t)gn * K + gk]);
            } else {
#pragma unroll
                for (int e = 0; e < 8; ++e) {
                    int kk = gk + e;
                    v[e] = (gn < N && kk < K) ? Bt[(size_t)gn * K + kk] : (ushort)0;
                }
            }
            int ch = schunk ^ ((r >> 1) & 3);
            *reinterpret_cast<uint4*>(&Bs[r * 32 + ch * 8]) = *reinterpret_cast<uint4*>(v);
        }
        __syncthreads();

        // ---- MFMA: each wave 64x64 = 4x4 tiles of 16x16, one K=32 step ----
        bf16x8 af[4], bf[4];
#pragma unroll
        for (int mt = 0; mt < 4; ++mt) {
            int row = wm + mt * 16 + lr;
            int ch = lk ^ ((row >> 1) & 3);
            af[mt] = *reinterpret_cast<const bf16x8*>(&As[row * 32 + ch * 8]);
        }
#pragma unroll
        for (int nt = 0; nt < 4; ++nt) {
            int row = wn + nt * 16 + lr;
            int ch = lk ^ ((row >> 1) & 3);
            bf[nt] = *reinterpret_cast<const bf16x8*>(&Bs[row * 32 + ch * 8]);
        }
#pragma unroll
        for (int mt = 0; mt < 4; ++mt)
#pragma unroll
            for (int nt = 0; nt < 4; ++nt)
                acc[mt][nt] = __builtin_amdgcn_mfma_f32_16x16x32_bf16(
                    af[mt], bf[nt], acc[mt][nt], 0, 0, 0);
    }

    // ---- epilogue: D layout col=lane&15, row=(lane>>4)*4+reg ----
#pragma unroll
    for (int nt = 0; nt < 4; ++nt) {
        int col = n0 + wn + nt * 16 + lr;
        if (col >= N) continue;
        float bv = bias[col];
#pragma unroll
        for (int mt = 0; mt < 4; ++mt) {
#pragma unroll
            for (int r = 0; r < 4; ++r) {
                int row = m0 + wm + mt * 16 + lk * 4 + r;
                if (row >= M) continue;
                float v = acc[mt][nt][r] + bv;
                if (ACT == 1) v = fmaxf(v, 0.0f);
                if (OUT_BF16)
                    ((ushort*)Cout)[(size_t)row * N + col] = f2bf(v);
                else
                    ((float*)Cout)[(size_t)row * N + col] = v;
            }
        }
    }
}

// ---------------------------------------------------------------------------
// s1[b,g] = (1/64) * sum_n val1[(b*64+n), g]   f32 in, bf16 out
// ---------------------------------------------------------------------------
__global__ void reduce_s1_kernel(const float* __restrict__ val1, ushort* __restrict__ s1) {
    int idx = blockIdx.x * blockDim.x + threadIdx.x;
    if (idx >= B_DIM * F_INF) return;
    int b = idx >> 10;
    int g = idx & 1023;
    float s = 0.f;
#pragma unroll 8
    for (int n = 0; n < 64; ++n) s += val1[(size_t)((b << 6) + n) * F_INF + g];
    s1[idx] = f2bf(s * (1.0f / 64.0f));
}

// ---------------------------------------------------------------------------
// seq[t,b,c] = (c<256) ? out2[b, t*4 + c%4] : pe[t,b,c-256]   -> bf16
// ---------------------------------------------------------------------------
__global__ void seq_kernel(const float* __restrict__ out2, const float* __restrict__ pe,
                           ushort* __restrict__ seq) {
    int idx = blockIdx.x * blockDim.x + threadIdx.x;
    if (idx >= T_DIM * B_DIM * D_T) return;
    int c = idx % D_T;
    int tb = idx / D_T;
    float v;
    if (c < 256)
        v = out2[(tb % B_DIM) * 1024 + ((tb / B_DIM) << 2) + (c & 3)];
    else
        v = pe[tb * 16 + (c - 256)];
    seq[idx] = f2bf(v);
}

// ---------------------------------------------------------------------------
// Fused attention per (b,h). One thread = one query row; K/V bf16 in LDS
// (row stride 40 elems = 80B, 16B-aligned). 8 keys per iteration, branch-free
// online softmax: one max/corr per 8 keys, 8-wide ILP in the dot phase.
// ---------------------------------------------------------------------------
__global__ __launch_bounds__(256) void attn_kernel(const float* __restrict__ qkv,
                                                   const int* __restrict__ lengths,
                                                   ushort* __restrict__ attno) {
    const int bh = blockIdx.x;
    const int b = bh >> 3;
    const int h = bh & 7;
    const int t = threadIdx.x;
    __shared__ ushort Ks[256 * 40];
    __shared__ ushort Vs[256 * 40];
    const int len = lengths[b];

    for (int idx = t; idx < 256 * 34; idx += 256) {
        int j = idx / 34;
        int d = idx - j * 34;
        size_t row = (size_t)(j * B_DIM + b) * 816 + h * 34 + d;
        Ks[j * 40 + d] = f2bf(qkv[row + 272]);
        Vs[j * 40 + d] = f2bf(qkv[row + 544]);
    }
    float q[34];
    {
        const float* qp = &qkv[(size_t)(t * B_DIM + b) * 816 + h * 34];
#pragma unroll
        for (int d = 0; d < 34; ++d) q[d] = qp[d];
    }
    __syncthreads();

    const float scale = 0.1714985851f;  // 1/sqrt(34)
    float m = -1e30f, l = 0.f;
    float acc[34];
#pragma unroll
    for (int d = 0; d < 34; ++d) acc[d] = 0.f;

    for (int j0 = 0; j0 < len; j0 += 8) {
        float s[8];
#pragma unroll
        for (int jj = 0; jj < 8; ++jj) {
            const uint* kr = reinterpret_cast<const uint*>(&Ks[(j0 + jj) * 40]);
            float sv = 0.f;
#pragma unroll
            for (int p = 0; p < 17; ++p) {
                uint u = kr[p];
                sv += q[2 * p] * __uint_as_float(u << 16);
                sv += q[2 * p + 1] * __uint_as_float(u & 0xffff0000u);
            }
            s[jj] = sv;
        }
        int jn = len - j0;  // >= 1
        float cmax = -1e30f;
#pragma unroll
        for (int jj = 0; jj < 8; ++jj) {
            s[jj] = (jj < jn) ? s[jj] * scale : -1e30f;
            cmax = fmaxf(cmax, s[jj]);
        }
        float mnew = fmaxf(m, cmax);
        float corr = __expf(m - mnew);
        float w[8], wsum = 0.f;
#pragma unroll
        for (int jj = 0; jj < 8; ++jj) {
            w[jj] = __expf(s[jj] - mnew);
            wsum += w[jj];
        }
        l = l * corr + wsum;
        m = mnew;
#pragma unroll
        for (int d = 0; d < 34; ++d) acc[d] *= corr;
#pragma unroll
        for (int jj = 0; jj < 8; ++jj) {
            const uint* vr = reinterpret_cast<const uint*>(&Vs[(j0 + jj) * 40]);
            float wv = w[jj];
#pragma unroll
            for (int p = 0; p < 17; ++p) {
                uint u = vr[p];
                acc[2 * p] += wv * __uint_as_float(u << 16);
                acc[2 * p + 1] += wv * __uint_as_float(u & 0xffff0000u);
            }
        }
    }
    float inv = 1.0f / l;
    ushort* op = &attno[(size_t)(t * B_DIM + b) * D_T + h * 34];
#pragma unroll
    for (int d = 0; d < 34; ++d) op[d] = f2bf(acc[d] * inv);
}

// ---------------------------------------------------------------------------
// LN: out = LN(bf16 X + f32 Y) * w + b  -> bf16. One wave per row (272 wide).
// ---------------------------------------------------------------------------
__global__ __launch_bounds__(64) void ln_kernel(const ushort* __restrict__ X,
                                                const float* __restrict__ Y,
                                                const float* __restrict__ w,
                                                const float* __restrict__ bsh,
                                                ushort* __restrict__ out) {
    int row = blockIdx.x;
    int tid = threadIdx.x;
    const ushort* xr = X + (size_t)row * D_T;
    const float* yr = Y + (size_t)row * D_T;
    float v[5];
    float sum = 0.f, sumsq = 0.f;
#pragma unroll
    for (int k = 0; k < 5; ++k) {
        int c = tid + k * 64;
        float t = 0.f;
        if (c < D_T) t = bf2f(xr[c]) + yr[c];
        v[k] = t;
        sum += t;
        sumsq += t * t;
    }
#pragma unroll
    for (int off = 32; off; off >>= 1) {
        sum += __shfl_down(sum, off);
        sumsq += __shfl_down(sumsq, off);
    }
    sum = __shfl(sum, 0);
    sumsq = __shfl(sumsq, 0);
    float mu = sum * (1.0f / D_T);
    float var = sumsq * (1.0f / D_T) - mu * mu;
    float inv = 1.0f / sqrtf(var + 1e-5f);
    ushort* orow = out + (size_t)row * D_T;
#pragma unroll
    for (int k = 0; k < 5; ++k) {
        int c = tid + k * 64;
        if (c < D_T) orow[c] = f2bf((v[k] - mu) * inv * w[c] + bsh[c]);
    }
}

// ---------------------------------------------------------------------------
// agg[b,c] = sum_{t<len_b} seq[t,b,c] / (len_b + 1)
// ---------------------------------------------------------------------------
__global__ void pool_kernel(const ushort* __restrict__ seq, const int* __restrict__ lengths,
                            float* __restrict__ agg) {
    int idx = blockIdx.x * blockDim.x + threadIdx.x;
    if (idx >= B_DIM * D_T) return;
    int b = idx / D_T;
    int c = idx % D_T;
    int len = lengths[b];
    float s = 0.f;
    for (int t = 0; t < len; ++t) s += bf2f(seq[(size_t)(t * B_DIM + b) * D_T + c]);
    agg[idx] = s / (float)(len + 1);
}

// ---------------------------------------------------------------------------
// Head (f32): hid = relu(agg@w1+b1); logits = hid@w2+b2; softmax
// ---------------------------------------------------------------------------
__global__ __launch_bounds__(320) void head_kernel(const float* __restrict__ agg,
                                                   const float* __restrict__ w1,
                                                   const float* __restrict__ b1,
                                                   const float* __restrict__ w2,
                                                   const float* __restrict__ b2,
                                                   float* __restrict__ out) {
    int b = blockIdx.x;
    int tid = threadIdx.x;
    __shared__ float hid[D_T];
    __shared__ float arow[D_T];
    if (tid < D_T) arow[tid] = agg[b * D_T + tid];
    __syncthreads();
    if (tid < D_T) {
        float s = b1[tid];
        for (int k = 0; k < D_T; ++k) s += arow[k] * w1[k * D_T + tid];
        hid[tid] = fmaxf(s, 0.f);
    }
    __syncthreads();
    if (tid == 0) {
        float l0 = b2[0], l1 = b2[1];
        for (int k = 0; k < D_T; ++k) {
            l0 += hid[k] * w2[k * 2 + 0];
            l1 += hid[k] * w2[k * 2 + 1];
        }
        float mx = fmaxf(l0, l1);
        float e0 = expf(l0 - mx), e1 = expf(l1 - mx);
        float inv = 1.0f / (e0 + e1);
        out[b * 2 + 0] = e0 * inv;
        out[b * 2 + 1] = e1 * inv;
    }
}

// ---------------------------------------------------------------------------
extern "C" void kernel_launch(void* const* d_in, const int* in_sizes, int n_in,
                              void* d_out, int out_size, void* d_ws, size_t ws_size,
                              hipStream_t stream) {
    const float* x      = (const float*)d_in[0];
    const float* times  = (const float*)d_in[1];
    const int*   lens   = (const int*)d_in[2];
    const float* R_u    = (const float*)d_in[3];
    const float* Wv1    = (const float*)d_in[4];
    const float* bv1    = (const float*)d_in[5];
    const float* Wv2    = (const float*)d_in[6];
    const float* bv2    = (const float*)d_in[7];
    const float* qkv_w  = (const float*)d_in[8];
    const float* qkv_b  = (const float*)d_in[9];
    const float* out_w  = (const float*)d_in[10];
    const float* out_b  = (const float*)d_in[11];
    const float* ln1_w  = (const float*)d_in[12];
    const float* ln1_b  = (const float*)d_in[13];
    const float* ln2_w  = (const float*)d_in[14];
    const float* ln2_b  = (const float*)d_in[15];
    const float* ffn_w1 = (const float*)d_in[16];
    const float* ffn_b1 = (const float*)d_in[17];
    const float* ffn_w2 = (const float*)d_in[18];
    const float* ffn_b2 = (const float*)d_in[19];
    const float* mlp_w1 = (const float*)d_in[20];
    const float* mlp_b1 = (const float*)d_in[21];
    const float* mlp_w2 = (const float*)d_in[22];
    const float* mlp_b2 = (const float*)d_in[23];
    float* outp = (float*)d_out;

    // workspace carve (256B-aligned chunks)
    char* base = (char*)d_ws;
    size_t used = 0;
    auto alloc = [&](size_t bytes) -> char* {
        char* p = base + used;
        used += (bytes + 255) & ~(size_t)255;
        return p;
    };
    const int TB = T_DIM * B_DIM;  // 8192

    ushort* xn    = (ushort*)alloc((size_t)2048 * 1024 * 2);
    float*  val1  = (float*) alloc((size_t)2048 * 1024 * 4);
    ushort* s1    = (ushort*)alloc((size_t)32 * 1024 * 2);
    float*  out2  = (float*) alloc((size_t)32 * 1024 * 4);
    float*  pe    = (float*) alloc((size_t)TB * 16 * 4);
    ushort* seq   = (ushort*)alloc((size_t)TB * D_T * 2);
    float*  qkvb  = (float*) alloc((size_t)TB * 816 * 4);
    ushort* attno = (ushort*)alloc((size_t)TB * D_T * 2);
    float*  tmp   = (float*) alloc((size_t)TB * D_T * 4);
    ushort* x1    = (ushort*)alloc((size_t)TB * D_T * 2);
    ushort* h1    = (ushort*)alloc((size_t)TB * DFF_DIM * 2);
    float*  agg   = (float*) alloc((size_t)B_DIM * D_T * 4);
    ushort* wv1t  = (ushort*)alloc((size_t)1024 * 1024 * 2);
    ushort* wv2t  = (ushort*)alloc((size_t)1024 * 1024 * 2);
    ushort* qkvwt[2]; ushort* outwt[2]; ushort* f1wt[2]; ushort* f2wt[2];
    for (int l = 0; l < 2; ++l) {
        qkvwt[l] = (ushort*)alloc((size_t)272 * 816 * 2);
        outwt[l] = (ushort*)alloc((size_t)272 * 272 * 2);
        f1wt[l]  = (ushort*)alloc((size_t)272 * 1024 * 2);
        f2wt[l]  = (ushort*)alloc((size_t)1024 * 272 * 2);
    }
    if (used > ws_size) return;

    // ---- weight convert+transpose (bf16) ----
    auto wconv = [&](const float* in, ushort* out, int K, int N) {
        int n = K * N;
        wconv_kernel<<<(n + 255) / 256, 256, 0, stream>>>(in, out, K, N);
    };
    wconv(Wv1, wv1t, 1024, 1024);
    wconv(Wv2, wv2t, 1024, 1024);
    for (int l = 0; l < 2; ++l) {
        wconv(qkv_w + (size_t)l * 272 * 816, qkvwt[l], 272, 816);
        wconv(out_w + (size_t)l * 272 * 272, outwt[l], 272, 272);
        wconv(ffn_w1 + (size_t)l * 272 * 1024, f1wt[l], 272, 1024);
        wconv(ffn_w2 + (size_t)l * 1024 * 272, f2wt[l], 1024, 272);
    }

    // ---- embeddings ----
    {
        int n = B_DIM * N_DIM * F_INF;
        xn_kernel<<<(n + 255) / 256, 256, 0, stream>>>(x, R_u, xn);
        int npe = TB * 8;
        pe_kernel<<<(npe + 255) / 256, 256, 0, stream>>>(times, pe);
    }

    // ---- prop1: val1 = relu(xn @ Wv1 + bv1)  [2048,1024] ----
    gemm_mfma<1, 0><<<dim3(8, 16), 256, 0, stream>>>(xn, wv1t, bv1, val1, 2048, 1024, 1024);
    {
        int n = B_DIM * F_INF;
        reduce_s1_kernel<<<(n + 255) / 256, 256, 0, stream>>>(val1, s1);
    }
    // ---- prop2 (collapsed): out2 = relu(s1 @ Wv2 + bv2)  [32,1024] ----
    gemm_mfma<1, 0><<<dim3(8, 1), 256, 0, stream>>>(s1, wv2t, bv2, out2, 32, 1024, 1024);

    // ---- sequence ----
    {
        int n = TB * D_T;
        seq_kernel<<<(n + 255) / 256, 256, 0, stream>>>(out2, pe, seq);
    }

    // ---- transformer layers ----
    for (int l = 0; l < 2; ++l) {
        const float* qb  = qkv_b + (size_t)l * 816;
        const float* ob  = out_b + (size_t)l * D_T;
        const float* l1w = ln1_w + (size_t)l * D_T;
        const float* l1b = ln1_b + (size_t)l * D_T;
        const float* l2w = ln2_w + (size_t)l * D_T;
        const float* l2b = ln2_b + (size_t)l * D_T;
        const float* f1b = ffn_b1 + (size_t)l * DFF_DIM;
        const float* f2b = ffn_b2 + (size_t)l * D_T;

        // QKV: [8192,272] @ [272,816] -> f32
        gemm_mfma<0, 0><<<dim3(7, 64), 256, 0, stream>>>(seq, qkvwt[l], qb, qkvb,
                                                         TB, 816, D_T);
        attn_kernel<<<B_DIM * H_DIM, 256, 0, stream>>>(qkvb, lens, attno);
        // out-proj: [8192,272] @ [272,272] -> f32
        gemm_mfma<0, 0><<<dim3(3, 64), 256, 0, stream>>>(attno, outwt[l], ob, tmp,
                                                         TB, D_T, D_T);
        ln_kernel<<<TB, 64, 0, stream>>>(seq, tmp, l1w, l1b, x1);
        // FFN1: relu([8192,272] @ [272,1024]) -> bf16
        gemm_mfma<1, 1><<<dim3(8, 64), 256, 0, stream>>>(x1, f1wt[l], f1b, h1,
                                                         TB, DFF_DIM, D_T);
        // FFN2: [8192,1024] @ [1024,272] -> f32
        gemm_mfma<0, 0><<<dim3(3, 64), 256, 0, stream>>>(h1, f2wt[l], f2b, tmp,
                                                         TB, D_T, DFF_DIM);
        ln_kernel<<<TB, 64, 0, stream>>>(x1, tmp, l2w, l2b, seq);
    }

    // ---- pool + head ----
    {
        int n = B_DIM * D_T;
        pool_kernel<<<(n + 255) / 256, 256, 0, stream>>>(seq, lens, agg);
    }
    head_kernel<<<B_DIM, 320, 0, stream>>>(agg, mlp_w1, mlp_b1, mlp_w2, mlp_b2, outp);
}

// Round 3
// 589.630 us; speedup vs baseline: 1.8678x; 1.2896x over previous
//
#include <hip/hip_runtime.h>
#include <math.h>

#define T_DIM 256
#define B_DIM 32
#define N_DIM 64
#define F_INF 1024
#define D_T 272
#define H_DIM 8
#define DH_DIM 34
#define DFF_DIM 1024

typedef unsigned int uint;
typedef short bf16x8 __attribute__((ext_vector_type(8)));
typedef float f32x4 __attribute__((ext_vector_type(4)));

__device__ __forceinline__ ushort f2bf(float f) {
    uint u = __float_as_uint(f);
    uint r = (u + 0x7fffu + ((u >> 16) & 1u)) >> 16;
    return (ushort)r;
}
__device__ __forceinline__ float bf2f(ushort u) {
    return __uint_as_float(((uint)u) << 16);
}

// ---------------------------------------------------------------------------
// xn[b,n,t*4+d] = relu(x[t,b,n] * R_u[n*4+d])  -> bf16
// ---------------------------------------------------------------------------
__global__ void xn_kernel(const float* __restrict__ x, const float* __restrict__ Ru,
                          ushort* __restrict__ xn) {
    int idx = blockIdx.x * blockDim.x + threadIdx.x;
    if (idx >= B_DIM * N_DIM * F_INF) return;
    int f = idx & 1023;
    int bn = idx >> 10;
    int n = bn & 63;
    int b = bn >> 6;
    int t = f >> 2;
    int d = f & 3;
    float v = x[(t * B_DIM + b) * N_DIM + n] * Ru[(n << 2) + d];
    xn[idx] = f2bf(fmaxf(v, 0.0f));
}

// ---------------------------------------------------------------------------
// positional encoding (f32)
// ---------------------------------------------------------------------------
__global__ void pe_kernel(const float* __restrict__ times, float* __restrict__ pe) {
    int idx = blockIdx.x * blockDim.x + threadIdx.x;
    if (idx >= T_DIM * B_DIM * 8) return;
    int s = idx & 7;
    int tb = idx >> 3;
    float tv = times[tb];
    float scale = (float)pow(256.0, (double)s * (1.0 / 7.0));
    float st = tv / scale;
    pe[tb * 16 + s] = sinf(st);
    pe[tb * 16 + 8 + s] = cosf(st);
}

// ---------------------------------------------------------------------------
// weight convert + transpose: in f32 [K,N] -> out bf16 [N,K]
// ---------------------------------------------------------------------------
__global__ void wconv_kernel(const float* __restrict__ in, ushort* __restrict__ out,
                             int K, int N) {
    int idx = blockIdx.x * blockDim.x + threadIdx.x;
    if (idx >= K * N) return;
    int k = idx / N;
    int n = idx - k * N;
    out[n * K + k] = f2bf(in[idx]);
}

// ---------------------------------------------------------------------------
// MFMA bf16 GEMM: C[M,N] = act(A[M,K] @ Bt[N,K]^T + bias[N])
// BM=128, BN=128, BK=32, 256 threads (4 waves, each 64x64).
// OUT_MODE: 0 = f32 flat, 1 = bf16 flat, 2 = bf16 head-padded QKV layout
//   (col -> (col/34)*40 + col%34, row stride 960; pads pre-zeroed).
// ---------------------------------------------------------------------------
template <int ACT, int OUT_MODE>
__global__ __launch_bounds__(256) void gemm_mfma(const ushort* __restrict__ A,
                                                 const ushort* __restrict__ Bt,
                                                 const float* __restrict__ bias,
                                                 void* __restrict__ Cout,
                                                 int M, int N, int K) {
    __shared__ ushort As[128 * 32];
    __shared__ ushort Bs[128 * 32];
    const int tid = threadIdx.x;
    const int m0 = blockIdx.y * 128;
    const int n0 = blockIdx.x * 128;
    const int w = tid >> 6, lane = tid & 63;
    const int wm = (w >> 1) * 64, wn = (w & 1) * 64;
    const int lr = lane & 15, lk = lane >> 4;

    f32x4 acc[4][4];
#pragma unroll
    for (int i = 0; i < 4; ++i)
#pragma unroll
        for (int j = 0; j < 4; ++j) acc[i][j] = (f32x4){0.f, 0.f, 0.f, 0.f};

    const int sr = tid >> 2;
    const int sc = (tid & 3) * 8;
    const int schunk = sc >> 3;

    for (int k0 = 0; k0 < K; k0 += 32) {
        __syncthreads();
#pragma unroll
        for (int rr = 0; rr < 2; ++rr) {
            int r = sr + rr * 64;
            int gm = m0 + r;
            int gk = k0 + sc;
            ushort v[8];
            if (gm < M && gk + 7 < K) {
                *reinterpret_cast<uint4*>(v) =
                    *reinterpret_cast<const uint4*>(&A[(size_t)gm * K + gk]);
            } else {
#pragma unroll
                for (int e = 0; e < 8; ++e) {
                    int kk = gk + e;
                    v[e] = (gm < M && kk < K) ? A[(size_t)gm * K + kk] : (ushort)0;
                }
            }
            int ch = schunk ^ ((r >> 1) & 3);
            *reinterpret_cast<uint4*>(&As[r * 32 + ch * 8]) = *reinterpret_cast<uint4*>(v);
        }
#pragma unroll
        for (int rr = 0; rr < 2; ++rr) {
            int r = sr + rr * 64;
            int gn = n0 + r;
            int gk = k0 + sc;
            ushort v[8];
            if (gn < N && gk + 7 < K) {
                *reinterpret_cast<uint4*>(v) =
                    *reinterpret_cast<const uint4*>(&Bt[(size_t)gn * K + gk]);
            } else {
#pragma unroll
                for (int e = 0; e < 8; ++e) {
                    int kk = gk + e;
                    v[e] = (gn < N && kk < K) ? Bt[(size_t)gn * K + kk] : (ushort)0;
                }
            }
            int ch = schunk ^ ((r >> 1) & 3);
            *reinterpret_cast<uint4*>(&Bs[r * 32 + ch * 8]) = *reinterpret_cast<uint4*>(v);
        }
        __syncthreads();

        bf16x8 af[4], bf[4];
#pragma unroll
        for (int mt = 0; mt < 4; ++mt) {
            int row = wm + mt * 16 + lr;
            int ch = lk ^ ((row >> 1) & 3);
            af[mt] = *reinterpret_cast<const bf16x8*>(&As[row * 32 + ch * 8]);
        }
#pragma unroll
        for (int nt = 0; nt < 4; ++nt) {
            int row = wn + nt * 16 + lr;
            int ch = lk ^ ((row >> 1) & 3);
            bf[nt] = *reinterpret_cast<const bf16x8*>(&Bs[row * 32 + ch * 8]);
        }
#pragma unroll
        for (int mt = 0; mt < 4; ++mt)
#pragma unroll
            for (int nt = 0; nt < 4; ++nt)
                acc[mt][nt] = __builtin_amdgcn_mfma_f32_16x16x32_bf16(
                    af[mt], bf[nt], acc[mt][nt], 0, 0, 0);
    }

#pragma unroll
    for (int nt = 0; nt < 4; ++nt) {
        int col = n0 + wn + nt * 16 + lr;
        if (col >= N) continue;
        float bv = bias[col];
        int g = 0, dcol = 0;
        if (OUT_MODE == 2) { g = col / 34; dcol = col - g * 34; }
#pragma unroll
        for (int mt = 0; mt < 4; ++mt) {
#pragma unroll
            for (int r = 0; r < 4; ++r) {
                int row = m0 + wm + mt * 16 + lk * 4 + r;
                if (row >= M) continue;
                float v = acc[mt][nt][r] + bv;
                if (ACT == 1) v = fmaxf(v, 0.0f);
                if (OUT_MODE == 0)
                    ((float*)Cout)[(size_t)row * N + col] = v;
                else if (OUT_MODE == 1)
                    ((ushort*)Cout)[(size_t)row * N + col] = f2bf(v);
                else
                    ((ushort*)Cout)[(size_t)row * 960 + g * 40 + dcol] = f2bf(v);
            }
        }
    }
}

// ---------------------------------------------------------------------------
// s1[b,g] = (1/64) * sum_n val1[(b*64+n), g]   f32 in, bf16 out
// ---------------------------------------------------------------------------
__global__ void reduce_s1_kernel(const float* __restrict__ val1, ushort* __restrict__ s1) {
    int idx = blockIdx.x * blockDim.x + threadIdx.x;
    if (idx >= B_DIM * F_INF) return;
    int b = idx >> 10;
    int g = idx & 1023;
    float s = 0.f;
#pragma unroll 8
    for (int n = 0; n < 64; ++n) s += val1[(size_t)((b << 6) + n) * F_INF + g];
    s1[idx] = f2bf(s * (1.0f / 64.0f));
}

// ---------------------------------------------------------------------------
// seq[t,b,c] = (c<256) ? out2[b, t*4 + c%4] : pe[t,b,c-256]   -> bf16
// ---------------------------------------------------------------------------
__global__ void seq_kernel(const float* __restrict__ out2, const float* __restrict__ pe,
                           ushort* __restrict__ seq) {
    int idx = blockIdx.x * blockDim.x + threadIdx.x;
    if (idx >= T_DIM * B_DIM * D_T) return;
    int c = idx % D_T;
    int tb = idx / D_T;
    float v;
    if (c < 256)
        v = out2[(tb % B_DIM) * 1024 + ((tb / B_DIM) << 2) + (c & 3)];
    else
        v = pe[tb * 16 + (c - 256)];
    seq[idx] = f2bf(v);
}

// ---------------------------------------------------------------------------
// MFMA flash attention. Block = (b,h), 4 waves x 64 queries, KV chunks of 64.
// qkv: bf16 head-padded [8192][24][40] (q sec 0..7, k sec 8..15, v sec 16..23).
// S raw-units online softmax (scale folded into exp); P bf16 in wave-private
// LDS with permuted cols j' = (j&15)*4 + (j>>4); V staged transposed with the
// same permutation so PV fragments are contiguous b128 reads.
// ---------------------------------------------------------------------------
__global__ __launch_bounds__(256) void attn_mfma(const ushort* __restrict__ qkv,
                                                 const int* __restrict__ lengths,
                                                 ushort* __restrict__ attno) {
    const int b = blockIdx.x >> 3;
    const int h = blockIdx.x & 7;
    const int tid = threadIdx.x;
    const int w = tid >> 6, lane = tid & 63;
    const int lr = lane & 15, lk = lane >> 4;
    __shared__ ushort Ks[64 * 40];
    __shared__ ushort Vt[48 * 72];
    __shared__ ushort Ps[4][64 * 72];
    const int len = lengths[b];
    const float scale = 0.1714985851f;  // 1/sqrt(34)
    const bf16x8 zv = {0, 0, 0, 0, 0, 0, 0, 0};

    // Q fragments (A operand): rows it*16+lr, k = lk*8+e (dh padded 34->64)
    bf16x8 qf0[4], qf1[4];
#pragma unroll
    for (int it = 0; it < 4; ++it) {
        int t = w * 64 + it * 16 + lr;
        const ushort* qrow = &qkv[(size_t)(t * 32 + b) * 960 + h * 40];
        qf0[it] = *reinterpret_cast<const bf16x8*>(qrow + lk * 8);
        qf1[it] = (lk == 0) ? *reinterpret_cast<const bf16x8*>(qrow + 32) : zv;
    }

    f32x4 oacc[4][3];
#pragma unroll
    for (int it = 0; it < 4; ++it)
#pragma unroll
        for (int dt = 0; dt < 3; ++dt) oacc[it][dt] = (f32x4){0.f, 0.f, 0.f, 0.f};
    float m[4][4], l[4][4];
#pragma unroll
    for (int it = 0; it < 4; ++it)
#pragma unroll
        for (int r = 0; r < 4; ++r) { m[it][r] = -1e30f; l[it][r] = 0.f; }

    const int nchunks = (len + 63) >> 6;
    for (int c = 0; c < nchunks; ++c) {
        __syncthreads();
        // stage K chunk rows (incl. zero pad cols 34..39 from global)
        for (int idx = tid; idx < 320; idx += 256) {
            int row = idx / 5, ch = idx - row * 5;
            int j = c * 64 + row;
            const ushort* kr = &qkv[(size_t)(j * 32 + b) * 960 + 320 + h * 40];
            *reinterpret_cast<bf16x8*>(&Ks[row * 40 + ch * 8]) =
                *reinterpret_cast<const bf16x8*>(kr + ch * 8);
        }
        // stage V transposed+permuted: Vt[d][j'], d rows 34..47 zero
        for (int idx = tid; idx < 64 * 48; idx += 256) {
            int j = idx / 48, d = idx - j * 48;
            ushort v = 0;
            if (d < 34) {
                int jj = c * 64 + j;
                v = qkv[(size_t)(jj * 32 + b) * 960 + 640 + h * 40 + d];
            }
            int jp = (j & 15) * 4 + (j >> 4);
            Vt[d * 72 + jp] = v;
        }
        __syncthreads();

        // K fragments (B operand): cols jt*16+lr, k = lk*8+e
        bf16x8 kf0[4], kf1[4];
#pragma unroll
        for (int jt = 0; jt < 4; ++jt) {
            int j = jt * 16 + lr;
            kf0[jt] = *reinterpret_cast<const bf16x8*>(&Ks[j * 40 + lk * 8]);
            kf1[jt] = (lk == 0) ? *reinterpret_cast<const bf16x8*>(&Ks[j * 40 + 32]) : zv;
        }

        const bool tail = (c * 64 + 64 > len);
#pragma unroll
        for (int it = 0; it < 4; ++it) {
            f32x4 sacc[4];
#pragma unroll
            for (int jt = 0; jt < 4; ++jt) sacc[jt] = (f32x4){0.f, 0.f, 0.f, 0.f};
#pragma unroll
            for (int jt = 0; jt < 4; ++jt) {
                sacc[jt] = __builtin_amdgcn_mfma_f32_16x16x32_bf16(qf0[it], kf0[jt],
                                                                   sacc[jt], 0, 0, 0);
                sacc[jt] = __builtin_amdgcn_mfma_f32_16x16x32_bf16(qf1[it], kf1[jt],
                                                                   sacc[jt], 0, 0, 0);
            }
            // mask + chunk row-max
            float cm[4] = {-1e30f, -1e30f, -1e30f, -1e30f};
#pragma unroll
            for (int jt = 0; jt < 4; ++jt) {
                bool dead = tail && (c * 64 + jt * 16 + lr >= len);
#pragma unroll
                for (int r = 0; r < 4; ++r) {
                    float sv = dead ? -1e30f : sacc[jt][r];
                    sacc[jt][r] = sv;
                    cm[r] = fmaxf(cm[r], sv);
                }
            }
#pragma unroll
            for (int mask = 1; mask <= 8; mask <<= 1)
#pragma unroll
                for (int r = 0; r < 4; ++r) cm[r] = fmaxf(cm[r], __shfl_xor(cm[r], mask));
            // rescale running state
#pragma unroll
            for (int r = 0; r < 4; ++r) {
                float mn = fmaxf(m[it][r], cm[r]);
                float corr = __expf((m[it][r] - mn) * scale);
                m[it][r] = mn;
                l[it][r] *= corr;
#pragma unroll
                for (int dt = 0; dt < 3; ++dt) oacc[it][dt][r] *= corr;
            }
            // exp + row-sum, P in-place
            float ls[4] = {0.f, 0.f, 0.f, 0.f};
#pragma unroll
            for (int jt = 0; jt < 4; ++jt)
#pragma unroll
                for (int r = 0; r < 4; ++r) {
                    float e = __expf((sacc[jt][r] - m[it][r]) * scale);
                    sacc[jt][r] = e;
                    ls[r] += e;
                }
#pragma unroll
            for (int mask = 1; mask <= 8; mask <<= 1)
#pragma unroll
                for (int r = 0; r < 4; ++r) ls[r] += __shfl_xor(ls[r], mask);
#pragma unroll
            for (int r = 0; r < 4; ++r) l[it][r] += ls[r];
            // write P rows: row i = it*16+lk*4+r, cols j' = lr*4 + jt (b64 pack)
#pragma unroll
            for (int r = 0; r < 4; ++r) {
                int i = it * 16 + lk * 4 + r;
                uint u0 = (uint)f2bf(sacc[0][r]) | ((uint)f2bf(sacc[1][r]) << 16);
                uint u1 = (uint)f2bf(sacc[2][r]) | ((uint)f2bf(sacc[3][r]) << 16);
                uint2 pk = make_uint2(u0, u1);
                *reinterpret_cast<uint2*>(&Ps[w][i * 72 + lr * 4]) = pk;
            }
        }

        // PV: O += P @ V  (both in permuted-j' space)
        bf16x8 vf[3][2], pf[4][2];
#pragma unroll
        for (int dt = 0; dt < 3; ++dt)
#pragma unroll
            for (int ks = 0; ks < 2; ++ks)
                vf[dt][ks] = *reinterpret_cast<const bf16x8*>(
                    &Vt[(dt * 16 + lr) * 72 + ks * 32 + lk * 8]);
#pragma unroll
        for (int it = 0; it < 4; ++it)
#pragma unroll
            for (int ks = 0; ks < 2; ++ks)
                pf[it][ks] = *reinterpret_cast<const bf16x8*>(
                    &Ps[w][(it * 16 + lr) * 72 + ks * 32 + lk * 8]);
#pragma unroll
        for (int it = 0; it < 4; ++it)
#pragma unroll
            for (int dt = 0; dt < 3; ++dt)
#pragma unroll
                for (int ks = 0; ks < 2; ++ks)
                    oacc[it][dt] = __builtin_amdgcn_mfma_f32_16x16x32_bf16(
                        pf[it][ks], vf[dt][ks], oacc[it][dt], 0, 0, 0);
    }

    // epilogue
#pragma unroll
    for (int it = 0; it < 4; ++it)
#pragma unroll
        for (int r = 0; r < 4; ++r) {
            float inv = 1.0f / l[it][r];
            int t = w * 64 + it * 16 + lk * 4 + r;
            ushort* orow = &attno[(size_t)(t * 32 + b) * 272 + h * 34];
#pragma unroll
            for (int dt = 0; dt < 3; ++dt) {
                int d = dt * 16 + lr;
                if (d < 34) orow[d] = f2bf(oacc[it][dt][r] * inv);
            }
        }
}

// ---------------------------------------------------------------------------
// LN: out = LN(bf16 X + f32 Y) * w + b  -> bf16. One wave per row (272 wide).
// ---------------------------------------------------------------------------
__global__ __launch_bounds__(64) void ln_kernel(const ushort* __restrict__ X,
                                                const float* __restrict__ Y,
                                                const float* __restrict__ w,
                                                const float* __restrict__ bsh,
                                                ushort* __restrict__ out) {
    int row = blockIdx.x;
    int tid = threadIdx.x;
    const ushort* xr = X + (size_t)row * D_T;
    const float* yr = Y + (size_t)row * D_T;
    float v[5];
    float sum = 0.f, sumsq = 0.f;
#pragma unroll
    for (int k = 0; k < 5; ++k) {
        int c = tid + k * 64;
        float t = 0.f;
        if (c < D_T) t = bf2f(xr[c]) + yr[c];
        v[k] = t;
        sum += t;
        sumsq += t * t;
    }
#pragma unroll
    for (int off = 32; off; off >>= 1) {
        sum += __shfl_down(sum, off);
        sumsq += __shfl_down(sumsq, off);
    }
    sum = __shfl(sum, 0);
    sumsq = __shfl(sumsq, 0);
    float mu = sum * (1.0f / D_T);
    float var = sumsq * (1.0f / D_T) - mu * mu;
    float inv = 1.0f / sqrtf(var + 1e-5f);
    ushort* orow = out + (size_t)row * D_T;
#pragma unroll
    for (int k = 0; k < 5; ++k) {
        int c = tid + k * 64;
        if (c < D_T) orow[c] = f2bf((v[k] - mu) * inv * w[c] + bsh[c]);
    }
}

// ---------------------------------------------------------------------------
// agg[b,c] = sum_{t<len_b} seq[t,b,c] / (len_b + 1)
// ---------------------------------------------------------------------------
__global__ void pool_kernel(const ushort* __restrict__ seq, const int* __restrict__ lengths,
                            float* __restrict__ agg) {
    int idx = blockIdx.x * blockDim.x + threadIdx.x;
    if (idx >= B_DIM * D_T) return;
    int b = idx / D_T;
    int c = idx % D_T;
    int len = lengths[b];
    float s = 0.f;
    for (int t = 0; t < len; ++t) s += bf2f(seq[(size_t)(t * B_DIM + b) * D_T + c]);
    agg[idx] = s / (float)(len + 1);
}

// ---------------------------------------------------------------------------
// Head (f32): hid = relu(agg@w1+b1); logits = hid@w2+b2; softmax
// ---------------------------------------------------------------------------
__global__ __launch_bounds__(320) void head_kernel(const float* __restrict__ agg,
                                                   const float* __restrict__ w1,
                                                   const float* __restrict__ b1,
                                                   const float* __restrict__ w2,
                                                   const float* __restrict__ b2,
                                                   float* __restrict__ out) {
    int b = blockIdx.x;
    int tid = threadIdx.x;
    __shared__ float hid[D_T];
    __shared__ float arow[D_T];
    if (tid < D_T) arow[tid] = agg[b * D_T + tid];
    __syncthreads();
    if (tid < D_T) {
        float s = b1[tid];
        for (int k = 0; k < D_T; ++k) s += arow[k] * w1[k * D_T + tid];
        hid[tid] = fmaxf(s, 0.f);
    }
    __syncthreads();
    if (tid == 0) {
        float l0 = b2[0], l1 = b2[1];
        for (int k = 0; k < D_T; ++k) {
            l0 += hid[k] * w2[k * 2 + 0];
            l1 += hid[k] * w2[k * 2 + 1];
        }
        float mx = fmaxf(l0, l1);
        float e0 = expf(l0 - mx), e1 = expf(l1 - mx);
        float inv = 1.0f / (e0 + e1);
        out[b * 2 + 0] = e0 * inv;
        out[b * 2 + 1] = e1 * inv;
    }
}

// ---------------------------------------------------------------------------
extern "C" void kernel_launch(void* const* d_in, const int* in_sizes, int n_in,
                              void* d_out, int out_size, void* d_ws, size_t ws_size,
                              hipStream_t stream) {
    const float* x      = (const float*)d_in[0];
    const float* times  = (const float*)d_in[1];
    const int*   lens   = (const int*)d_in[2];
    const float* R_u    = (const float*)d_in[3];
    const float* Wv1    = (const float*)d_in[4];
    const float* bv1    = (const float*)d_in[5];
    const float* Wv2    = (const float*)d_in[6];
    const float* bv2    = (const float*)d_in[7];
    const float* qkv_w  = (const float*)d_in[8];
    const float* qkv_b  = (const float*)d_in[9];
    const float* out_w  = (const float*)d_in[10];
    const float* out_b  = (const float*)d_in[11];
    const float* ln1_w  = (const float*)d_in[12];
    const float* ln1_b  = (const float*)d_in[13];
    const float* ln2_w  = (const float*)d_in[14];
    const float* ln2_b  = (const float*)d_in[15];
    const float* ffn_w1 = (const float*)d_in[16];
    const float* ffn_b1 = (const float*)d_in[17];
    const float* ffn_w2 = (const float*)d_in[18];
    const float* ffn_b2 = (const float*)d_in[19];
    const float* mlp_w1 = (const float*)d_in[20];
    const float* mlp_b1 = (const float*)d_in[21];
    const float* mlp_w2 = (const float*)d_in[22];
    const float* mlp_b2 = (const float*)d_in[23];
    float* outp = (float*)d_out;

    char* base = (char*)d_ws;
    size_t used = 0;
    auto alloc = [&](size_t bytes) -> char* {
        char* p = base + used;
        used += (bytes + 255) & ~(size_t)255;
        return p;
    };
    const int TB = T_DIM * B_DIM;  // 8192

    ushort* xn    = (ushort*)alloc((size_t)2048 * 1024 * 2);
    float*  val1  = (float*) alloc((size_t)2048 * 1024 * 4);
    ushort* s1    = (ushort*)alloc((size_t)32 * 1024 * 2);
    float*  out2  = (float*) alloc((size_t)32 * 1024 * 4);
    float*  pe    = (float*) alloc((size_t)TB * 16 * 4);
    ushort* seq   = (ushort*)alloc((size_t)TB * D_T * 2);
    ushort* qkvb  = (ushort*)alloc((size_t)TB * 960 * 2);   // head-padded bf16
    ushort* attno = (ushort*)alloc((size_t)TB * D_T * 2);
    float*  tmp   = (float*) alloc((size_t)TB * D_T * 4);
    ushort* x1    = (ushort*)alloc((size_t)TB * D_T * 2);
    ushort* h1    = (ushort*)alloc((size_t)TB * DFF_DIM * 2);
    float*  agg   = (float*) alloc((size_t)B_DIM * D_T * 4);
    ushort* wv1t  = (ushort*)alloc((size_t)1024 * 1024 * 2);
    ushort* wv2t  = (ushort*)alloc((size_t)1024 * 1024 * 2);
    ushort* qkvwt[2]; ushort* outwt[2]; ushort* f1wt[2]; ushort* f2wt[2];
    for (int l = 0; l < 2; ++l) {
        qkvwt[l] = (ushort*)alloc((size_t)272 * 816 * 2);
        outwt[l] = (ushort*)alloc((size_t)272 * 272 * 2);
        f1wt[l]  = (ushort*)alloc((size_t)272 * 1024 * 2);
        f2wt[l]  = (ushort*)alloc((size_t)1024 * 272 * 2);
    }
    if (used > ws_size) return;

    auto wconv = [&](const float* in, ushort* out, int K, int N) {
        int n = K * N;
        wconv_kernel<<<(n + 255) / 256, 256, 0, stream>>>(in, out, K, N);
    };
    wconv(Wv1, wv1t, 1024, 1024);
    wconv(Wv2, wv2t, 1024, 1024);
    for (int l = 0; l < 2; ++l) {
        wconv(qkv_w + (size_t)l * 272 * 816, qkvwt[l], 272, 816);
        wconv(out_w + (size_t)l * 272 * 272, outwt[l], 272, 272);
        wconv(ffn_w1 + (size_t)l * 272 * 1024, f1wt[l], 272, 1024);
        wconv(ffn_w2 + (size_t)l * 1024 * 272, f2wt[l], 1024, 272);
    }

    {
        int n = B_DIM * N_DIM * F_INF;
        xn_kernel<<<(n + 255) / 256, 256, 0, stream>>>(x, R_u, xn);
        int npe = TB * 8;
        pe_kernel<<<(npe + 255) / 256, 256, 0, stream>>>(times, pe);
    }

    gemm_mfma<1, 0><<<dim3(8, 16), 256, 0, stream>>>(xn, wv1t, bv1, val1, 2048, 1024, 1024);
    {
        int n = B_DIM * F_INF;
        reduce_s1_kernel<<<(n + 255) / 256, 256, 0, stream>>>(val1, s1);
    }
    gemm_mfma<1, 0><<<dim3(8, 1), 256, 0, stream>>>(s1, wv2t, bv2, out2, 32, 1024, 1024);

    {
        int n = TB * D_T;
        seq_kernel<<<(n + 255) / 256, 256, 0, stream>>>(out2, pe, seq);
    }

    // zero the head-padded QKV buffer once (pads d=34..39 must be 0)
    hipMemsetAsync(qkvb, 0, (size_t)TB * 960 * 2, stream);

    for (int l = 0; l < 2; ++l) {
        const float* qb  = qkv_b + (size_t)l * 816;
        const float* ob  = out_b + (size_t)l * D_T;
        const float* l1w = ln1_w + (size_t)l * D_T;
        const float* l1b = ln1_b + (size_t)l * D_T;
        const float* l2w = ln2_w + (size_t)l * D_T;
        const float* l2b = ln2_b + (size_t)l * D_T;
        const float* f1b = ffn_b1 + (size_t)l * DFF_DIM;
        const float* f2b = ffn_b2 + (size_t)l * D_T;

        // QKV: [8192,272] @ [272,816] -> bf16 head-padded
        gemm_mfma<0, 2><<<dim3(7, 64), 256, 0, stream>>>(seq, qkvwt[l], qb, qkvb,
                                                         TB, 816, D_T);
        attn_mfma<<<B_DIM * H_DIM, 256, 0, stream>>>(qkvb, lens, attno);
        // out-proj: [8192,272] @ [272,272] -> f32
        gemm_mfma<0, 0><<<dim3(3, 64), 256, 0, stream>>>(attno, outwt[l], ob, tmp,
                                                         TB, D_T, D_T);
        ln_kernel<<<TB, 64, 0, stream>>>(seq, tmp, l1w, l1b, x1);
        // FFN1: relu([8192,272] @ [272,1024]) -> bf16
        gemm_mfma<1, 1><<<dim3(8, 64), 256, 0, stream>>>(x1, f1wt[l], f1b, h1,
                                                         TB, DFF_DIM, D_T);
        // FFN2: [8192,1024] @ [1024,272] -> f32
        gemm_mfma<0, 0><<<dim3(3, 64), 256, 0, stream>>>(h1, f2wt[l], f2b, tmp,
                                                         TB, D_T, DFF_DIM);
        ln_kernel<<<TB, 64, 0, stream>>>(x1, tmp, l2w, l2b, seq);
    }

    {
        int n = B_DIM * D_T;
        pool_kernel<<<(n + 255) / 256, 256, 0, stream>>>(seq, lens, agg);
    }
    head_kernel<<<B_DIM, 320, 0, stream>>>(agg, mlp_w1, mlp_b1, mlp_w2, mlp_b2, outp);
}

// Round 4
// 542.328 us; speedup vs baseline: 2.0308x; 1.0872x over previous
//
#include <hip/hip_runtime.h>
#include <math.h>

#define T_DIM 256
#define B_DIM 32
#define N_DIM 64
#define F_INF 1024
#define D_T 272
#define H_DIM 8
#define DH_DIM 34
#define DFF_DIM 1024

typedef unsigned int uint;
typedef short bf16x8 __attribute__((ext_vector_type(8)));
typedef float f32x4 __attribute__((ext_vector_type(4)));

__device__ __forceinline__ ushort f2bf(float f) {
    uint u = __float_as_uint(f);
    uint r = (u + 0x7fffu + ((u >> 16) & 1u)) >> 16;
    return (ushort)r;
}
__device__ __forceinline__ float bf2f(ushort u) {
    return __uint_as_float(((uint)u) << 16);
}

// ---------------------------------------------------------------------------
// xn[b,n,t*4+d] = relu(x[t,b,n] * R_u[n*4+d])  -> bf16
// ---------------------------------------------------------------------------
__global__ void xn_kernel(const float* __restrict__ x, const float* __restrict__ Ru,
                          ushort* __restrict__ xn) {
    int idx = blockIdx.x * blockDim.x + threadIdx.x;
    if (idx >= B_DIM * N_DIM * F_INF) return;
    int f = idx & 1023;
    int bn = idx >> 10;
    int n = bn & 63;
    int b = bn >> 6;
    int t = f >> 2;
    int d = f & 3;
    float v = x[(t * B_DIM + b) * N_DIM + n] * Ru[(n << 2) + d];
    xn[idx] = f2bf(fmaxf(v, 0.0f));
}

// ---------------------------------------------------------------------------
// positional encoding (f32)
// ---------------------------------------------------------------------------
__global__ void pe_kernel(const float* __restrict__ times, float* __restrict__ pe) {
    int idx = blockIdx.x * blockDim.x + threadIdx.x;
    if (idx >= T_DIM * B_DIM * 8) return;
    int s = idx & 7;
    int tb = idx >> 3;
    float tv = times[tb];
    float scale = (float)pow(256.0, (double)s * (1.0 / 7.0));
    float st = tv / scale;
    pe[tb * 16 + s] = sinf(st);
    pe[tb * 16 + 8 + s] = cosf(st);
}

// ---------------------------------------------------------------------------
// weight convert + transpose: in f32 [K,N] -> out bf16 [N,K]
// ---------------------------------------------------------------------------
__global__ void wconv_kernel(const float* __restrict__ in, ushort* __restrict__ out,
                             int K, int N) {
    int idx = blockIdx.x * blockDim.x + threadIdx.x;
    if (idx >= K * N) return;
    int k = idx / N;
    int n = idx - k * N;
    out[n * K + k] = f2bf(in[idx]);
}

// ---------------------------------------------------------------------------
// MFMA bf16 GEMM: C[M,N] = act(A[M,K] @ Bt[N,K]^T + bias[N])
// BM=128, BN=128, BK=32, 256 threads (4 waves, each 64x64).
// OUT_MODE: 0 = f32 flat, 1 = bf16 flat, 2 = bf16 head-padded QKV layout
//   (col -> (col/34)*40 + col%34, row stride 960; pads pre-zeroed).
// ---------------------------------------------------------------------------
template <int ACT, int OUT_MODE>
__global__ __launch_bounds__(256) void gemm_mfma(const ushort* __restrict__ A,
                                                 const ushort* __restrict__ Bt,
                                                 const float* __restrict__ bias,
                                                 void* __restrict__ Cout,
                                                 int M, int N, int K) {
    __shared__ ushort As[128 * 32];
    __shared__ ushort Bs[128 * 32];
    const int tid = threadIdx.x;
    const int m0 = blockIdx.y * 128;
    const int n0 = blockIdx.x * 128;
    const int w = tid >> 6, lane = tid & 63;
    const int wm = (w >> 1) * 64, wn = (w & 1) * 64;
    const int lr = lane & 15, lk = lane >> 4;

    f32x4 acc[4][4];
#pragma unroll
    for (int i = 0; i < 4; ++i)
#pragma unroll
        for (int j = 0; j < 4; ++j) acc[i][j] = (f32x4){0.f, 0.f, 0.f, 0.f};

    const int sr = tid >> 2;
    const int sc = (tid & 3) * 8;
    const int schunk = sc >> 3;

    for (int k0 = 0; k0 < K; k0 += 32) {
        __syncthreads();
#pragma unroll
        for (int rr = 0; rr < 2; ++rr) {
            int r = sr + rr * 64;
            int gm = m0 + r;
            int gk = k0 + sc;
            ushort v[8];
            if (gm < M && gk + 7 < K) {
                *reinterpret_cast<uint4*>(v) =
                    *reinterpret_cast<const uint4*>(&A[(size_t)gm * K + gk]);
            } else {
#pragma unroll
                for (int e = 0; e < 8; ++e) {
                    int kk = gk + e;
                    v[e] = (gm < M && kk < K) ? A[(size_t)gm * K + kk] : (ushort)0;
                }
            }
            int ch = schunk ^ ((r >> 1) & 3);
            *reinterpret_cast<uint4*>(&As[r * 32 + ch * 8]) = *reinterpret_cast<uint4*>(v);
        }
#pragma unroll
        for (int rr = 0; rr < 2; ++rr) {
            int r = sr + rr * 64;
            int gn = n0 + r;
            int gk = k0 + sc;
            ushort v[8];
            if (gn < N && gk + 7 < K) {
                *reinterpret_cast<uint4*>(v) =
                    *reinterpret_cast<const uint4*>(&Bt[(size_t)gn * K + gk]);
            } else {
#pragma unroll
                for (int e = 0; e < 8; ++e) {
                    int kk = gk + e;
                    v[e] = (gn < N && kk < K) ? Bt[(size_t)gn * K + kk] : (ushort)0;
                }
            }
            int ch = schunk ^ ((r >> 1) & 3);
            *reinterpret_cast<uint4*>(&Bs[r * 32 + ch * 8]) = *reinterpret_cast<uint4*>(v);
        }
        __syncthreads();

        bf16x8 af[4], bf[4];
#pragma unroll
        for (int mt = 0; mt < 4; ++mt) {
            int row = wm + mt * 16 + lr;
            int ch = lk ^ ((row >> 1) & 3);
            af[mt] = *reinterpret_cast<const bf16x8*>(&As[row * 32 + ch * 8]);
        }
#pragma unroll
        for (int nt = 0; nt < 4; ++nt) {
            int row = wn + nt * 16 + lr;
            int ch = lk ^ ((row >> 1) & 3);
            bf[nt] = *reinterpret_cast<const bf16x8*>(&Bs[row * 32 + ch * 8]);
        }
#pragma unroll
        for (int mt = 0; mt < 4; ++mt)
#pragma unroll
            for (int nt = 0; nt < 4; ++nt)
                acc[mt][nt] = __builtin_amdgcn_mfma_f32_16x16x32_bf16(
                    af[mt], bf[nt], acc[mt][nt], 0, 0, 0);
    }

#pragma unroll
    for (int nt = 0; nt < 4; ++nt) {
        int col = n0 + wn + nt * 16 + lr;
        if (col >= N) continue;
        float bv = bias[col];
        int g = 0, dcol = 0;
        if (OUT_MODE == 2) { g = col / 34; dcol = col - g * 34; }
#pragma unroll
        for (int mt = 0; mt < 4; ++mt) {
#pragma unroll
            for (int r = 0; r < 4; ++r) {
                int row = m0 + wm + mt * 16 + lk * 4 + r;
                if (row >= M) continue;
                float v = acc[mt][nt][r] + bv;
                if (ACT == 1) v = fmaxf(v, 0.0f);
                if (OUT_MODE == 0)
                    ((float*)Cout)[(size_t)row * N + col] = v;
                else if (OUT_MODE == 1)
                    ((ushort*)Cout)[(size_t)row * N + col] = f2bf(v);
                else
                    ((ushort*)Cout)[(size_t)row * 960 + g * 40 + dcol] = f2bf(v);
            }
        }
    }
}

// ---------------------------------------------------------------------------
// s1[b,g] = (1/64) * sum_n val1[(b*64+n), g]   f32 in, bf16 out
// ---------------------------------------------------------------------------
__global__ void reduce_s1_kernel(const float* __restrict__ val1, ushort* __restrict__ s1) {
    int idx = blockIdx.x * blockDim.x + threadIdx.x;
    if (idx >= B_DIM * F_INF) return;
    int b = idx >> 10;
    int g = idx & 1023;
    float s = 0.f;
#pragma unroll 8
    for (int n = 0; n < 64; ++n) s += val1[(size_t)((b << 6) + n) * F_INF + g];
    s1[idx] = f2bf(s * (1.0f / 64.0f));
}

// ---------------------------------------------------------------------------
// seq[t,b,c] = (c<256) ? out2[b, t*4 + c%4] : pe[t,b,c-256]   -> bf16
// ---------------------------------------------------------------------------
__global__ void seq_kernel(const float* __restrict__ out2, const float* __restrict__ pe,
                           ushort* __restrict__ seq) {
    int idx = blockIdx.x * blockDim.x + threadIdx.x;
    if (idx >= T_DIM * B_DIM * D_T) return;
    int c = idx % D_T;
    int tb = idx / D_T;
    float v;
    if (c < 256)
        v = out2[(tb % B_DIM) * 1024 + ((tb / B_DIM) << 2) + (c & 3)];
    else
        v = pe[tb * 16 + (c - 256)];
    seq[idx] = f2bf(v);
}

// ---------------------------------------------------------------------------
// MFMA flash attention. Block = (b,h), 4 waves x 64 queries, KV chunks of 64.
// ---------------------------------------------------------------------------
__global__ __launch_bounds__(256) void attn_mfma(const ushort* __restrict__ qkv,
                                                 const int* __restrict__ lengths,
                                                 ushort* __restrict__ attno) {
    const int b = blockIdx.x >> 3;
    const int h = blockIdx.x & 7;
    const int tid = threadIdx.x;
    const int w = tid >> 6, lane = tid & 63;
    const int lr = lane & 15, lk = lane >> 4;
    __shared__ ushort Ks[64 * 40];
    __shared__ ushort Vt[48 * 72];
    __shared__ ushort Ps[4][64 * 72];
    const int len = lengths[b];
    const float scale = 0.1714985851f;  // 1/sqrt(34)
    const bf16x8 zv = {0, 0, 0, 0, 0, 0, 0, 0};

    bf16x8 qf0[4], qf1[4];
#pragma unroll
    for (int it = 0; it < 4; ++it) {
        int t = w * 64 + it * 16 + lr;
        const ushort* qrow = &qkv[(size_t)(t * 32 + b) * 960 + h * 40];
        qf0[it] = *reinterpret_cast<const bf16x8*>(qrow + lk * 8);
        qf1[it] = (lk == 0) ? *reinterpret_cast<const bf16x8*>(qrow + 32) : zv;
    }

    f32x4 oacc[4][3];
#pragma unroll
    for (int it = 0; it < 4; ++it)
#pragma unroll
        for (int dt = 0; dt < 3; ++dt) oacc[it][dt] = (f32x4){0.f, 0.f, 0.f, 0.f};
    float m[4][4], l[4][4];
#pragma unroll
    for (int it = 0; it < 4; ++it)
#pragma unroll
        for (int r = 0; r < 4; ++r) { m[it][r] = -1e30f; l[it][r] = 0.f; }

    const int nchunks = (len + 63) >> 6;
    for (int c = 0; c < nchunks; ++c) {
        __syncthreads();
        for (int idx = tid; idx < 320; idx += 256) {
            int row = idx / 5, ch = idx - row * 5;
            int j = c * 64 + row;
            const ushort* kr = &qkv[(size_t)(j * 32 + b) * 960 + 320 + h * 40];
            *reinterpret_cast<bf16x8*>(&Ks[row * 40 + ch * 8]) =
                *reinterpret_cast<const bf16x8*>(kr + ch * 8);
        }
        for (int idx = tid; idx < 64 * 48; idx += 256) {
            int j = idx / 48, d = idx - j * 48;
            ushort v = 0;
            if (d < 34) {
                int jj = c * 64 + j;
                v = qkv[(size_t)(jj * 32 + b) * 960 + 640 + h * 40 + d];
            }
            int jp = (j & 15) * 4 + (j >> 4);
            Vt[d * 72 + jp] = v;
        }
        __syncthreads();

        bf16x8 kf0[4], kf1[4];
#pragma unroll
        for (int jt = 0; jt < 4; ++jt) {
            int j = jt * 16 + lr;
            kf0[jt] = *reinterpret_cast<const bf16x8*>(&Ks[j * 40 + lk * 8]);
            kf1[jt] = (lk == 0) ? *reinterpret_cast<const bf16x8*>(&Ks[j * 40 + 32]) : zv;
        }

        const bool tail = (c * 64 + 64 > len);
#pragma unroll
        for (int it = 0; it < 4; ++it) {
            f32x4 sacc[4];
#pragma unroll
            for (int jt = 0; jt < 4; ++jt) sacc[jt] = (f32x4){0.f, 0.f, 0.f, 0.f};
#pragma unroll
            for (int jt = 0; jt < 4; ++jt) {
                sacc[jt] = __builtin_amdgcn_mfma_f32_16x16x32_bf16(qf0[it], kf0[jt],
                                                                   sacc[jt], 0, 0, 0);
                sacc[jt] = __builtin_amdgcn_mfma_f32_16x16x32_bf16(qf1[it], kf1[jt],
                                                                   sacc[jt], 0, 0, 0);
            }
            float cm[4] = {-1e30f, -1e30f, -1e30f, -1e30f};
#pragma unroll
            for (int jt = 0; jt < 4; ++jt) {
                bool dead = tail && (c * 64 + jt * 16 + lr >= len);
#pragma unroll
                for (int r = 0; r < 4; ++r) {
                    float sv = dead ? -1e30f : sacc[jt][r];
                    sacc[jt][r] = sv;
                    cm[r] = fmaxf(cm[r], sv);
                }
            }
#pragma unroll
            for (int mask = 1; mask <= 8; mask <<= 1)
#pragma unroll
                for (int r = 0; r < 4; ++r) cm[r] = fmaxf(cm[r], __shfl_xor(cm[r], mask));
#pragma unroll
            for (int r = 0; r < 4; ++r) {
                float mn = fmaxf(m[it][r], cm[r]);
                float corr = __expf((m[it][r] - mn) * scale);
                m[it][r] = mn;
                l[it][r] *= corr;
#pragma unroll
                for (int dt = 0; dt < 3; ++dt) oacc[it][dt][r] *= corr;
            }
            float ls[4] = {0.f, 0.f, 0.f, 0.f};
#pragma unroll
            for (int jt = 0; jt < 4; ++jt)
#pragma unroll
                for (int r = 0; r < 4; ++r) {
                    float e = __expf((sacc[jt][r] - m[it][r]) * scale);
                    sacc[jt][r] = e;
                    ls[r] += e;
                }
#pragma unroll
            for (int mask = 1; mask <= 8; mask <<= 1)
#pragma unroll
                for (int r = 0; r < 4; ++r) ls[r] += __shfl_xor(ls[r], mask);
#pragma unroll
            for (int r = 0; r < 4; ++r) l[it][r] += ls[r];
#pragma unroll
            for (int r = 0; r < 4; ++r) {
                int i = it * 16 + lk * 4 + r;
                uint u0 = (uint)f2bf(sacc[0][r]) | ((uint)f2bf(sacc[1][r]) << 16);
                uint u1 = (uint)f2bf(sacc[2][r]) | ((uint)f2bf(sacc[3][r]) << 16);
                uint2 pk = make_uint2(u0, u1);
                *reinterpret_cast<uint2*>(&Ps[w][i * 72 + lr * 4]) = pk;
            }
        }

        bf16x8 vf[3][2], pf[4][2];
#pragma unroll
        for (int dt = 0; dt < 3; ++dt)
#pragma unroll
            for (int ks = 0; ks < 2; ++ks)
                vf[dt][ks] = *reinterpret_cast<const bf16x8*>(
                    &Vt[(dt * 16 + lr) * 72 + ks * 32 + lk * 8]);
#pragma unroll
        for (int it = 0; it < 4; ++it)
#pragma unroll
            for (int ks = 0; ks < 2; ++ks)
                pf[it][ks] = *reinterpret_cast<const bf16x8*>(
                    &Ps[w][(it * 16 + lr) * 72 + ks * 32 + lk * 8]);
#pragma unroll
        for (int it = 0; it < 4; ++it)
#pragma unroll
            for (int dt = 0; dt < 3; ++dt)
#pragma unroll
                for (int ks = 0; ks < 2; ++ks)
                    oacc[it][dt] = __builtin_amdgcn_mfma_f32_16x16x32_bf16(
                        pf[it][ks], vf[dt][ks], oacc[it][dt], 0, 0, 0);
    }

#pragma unroll
    for (int it = 0; it < 4; ++it)
#pragma unroll
        for (int r = 0; r < 4; ++r) {
            float inv = 1.0f / l[it][r];
            int t = w * 64 + it * 16 + lk * 4 + r;
            ushort* orow = &attno[(size_t)(t * 32 + b) * 272 + h * 34];
#pragma unroll
            for (int dt = 0; dt < 3; ++dt) {
                int d = dt * 16 + lr;
                if (d < 34) orow[d] = f2bf(oacc[it][dt][r] * inv);
            }
        }
}

// ---------------------------------------------------------------------------
// LN: out = LN(bf16 X + f32 Y) * w + b  -> bf16. One wave per row (272 wide).
// ---------------------------------------------------------------------------
__global__ __launch_bounds__(64) void ln_kernel(const ushort* __restrict__ X,
                                                const float* __restrict__ Y,
                                                const float* __restrict__ w,
                                                const float* __restrict__ bsh,
                                                ushort* __restrict__ out) {
    int row = blockIdx.x;
    int tid = threadIdx.x;
    const ushort* xr = X + (size_t)row * D_T;
    const float* yr = Y + (size_t)row * D_T;
    float v[5];
    float sum = 0.f, sumsq = 0.f;
#pragma unroll
    for (int k = 0; k < 5; ++k) {
        int c = tid + k * 64;
        float t = 0.f;
        if (c < D_T) t = bf2f(xr[c]) + yr[c];
        v[k] = t;
        sum += t;
        sumsq += t * t;
    }
#pragma unroll
    for (int off = 32; off; off >>= 1) {
        sum += __shfl_down(sum, off);
        sumsq += __shfl_down(sumsq, off);
    }
    sum = __shfl(sum, 0);
    sumsq = __shfl(sumsq, 0);
    float mu = sum * (1.0f / D_T);
    float var = sumsq * (1.0f / D_T) - mu * mu;
    float inv = 1.0f / sqrtf(var + 1e-5f);
    ushort* orow = out + (size_t)row * D_T;
#pragma unroll
    for (int k = 0; k < 5; ++k) {
        int c = tid + k * 64;
        if (c < D_T) orow[c] = f2bf((v[k] - mu) * inv * w[c] + bsh[c]);
    }
}

// ---------------------------------------------------------------------------
// pool: agg[b,c] = sum_{t<len_b} seq[t,b,c] / (len_b+1)
// grid (5, 32) = (c-group, b); 256 thr = 64 c-lanes x 4 t-slices; LDS reduce.
// ---------------------------------------------------------------------------
__global__ __launch_bounds__(256) void pool_kernel(const ushort* __restrict__ seq,
                                                   const int* __restrict__ lengths,
                                                   float* __restrict__ agg) {
    const int b = blockIdx.y;
    const int c = blockIdx.x * 64 + (threadIdx.x & 63);
    const int tg = threadIdx.x >> 6;
    const int len = lengths[b];
    __shared__ float part[4][64];
    float s = 0.f;
    if (c < D_T) {
        for (int t = tg; t < len; t += 4)
            s += bf2f(seq[(size_t)(t * B_DIM + b) * D_T + c]);
    }
    part[tg][threadIdx.x & 63] = s;
    __syncthreads();
    if (tg == 0 && c < D_T) {
        float tot = part[0][threadIdx.x] + part[1][threadIdx.x] +
                    part[2][threadIdx.x] + part[3][threadIdx.x];
        agg[b * D_T + c] = tot / (float)(len + 1);
    }
}

// ---------------------------------------------------------------------------
// Head (f32): hid = relu(agg@w1+b1); logits = hid@w2+b2; softmax
// ---------------------------------------------------------------------------
__global__ __launch_bounds__(320) void head_kernel(const float* __restrict__ agg,
                                                   const float* __restrict__ w1,
                                                   const float* __restrict__ b1,
                                                   const float* __restrict__ w2,
                                                   const float* __restrict__ b2,
                                                   float* __restrict__ out) {
    int b = blockIdx.x;
    int tid = threadIdx.x;
    __shared__ float hid[D_T];
    __shared__ float arow[D_T];
    if (tid < D_T) arow[tid] = agg[b * D_T + tid];
    __syncthreads();
    if (tid < D_T) {
        float s = b1[tid];
        for (int k = 0; k < D_T; ++k) s += arow[k] * w1[k * D_T + tid];
        hid[tid] = fmaxf(s, 0.f);
    }
    __syncthreads();
    // wave 0: parallel logits reduction over k
    if (tid < 64) {
        float l0 = 0.f, l1 = 0.f;
        for (int k = tid; k < D_T; k += 64) {
            float hv = hid[k];
            l0 += hv * w2[k * 2 + 0];
            l1 += hv * w2[k * 2 + 1];
        }
#pragma unroll
        for (int off = 32; off; off >>= 1) {
            l0 += __shfl_down(l0, off);
            l1 += __shfl_down(l1, off);
        }
        if (tid == 0) {
            l0 += b2[0];
            l1 += b2[1];
            float mx = fmaxf(l0, l1);
            float e0 = expf(l0 - mx), e1 = expf(l1 - mx);
            float inv = 1.0f / (e0 + e1);
            out[b * 2 + 0] = e0 * inv;
            out[b * 2 + 1] = e1 * inv;
        }
    }
}

// ---------------------------------------------------------------------------
extern "C" void kernel_launch(void* const* d_in, const int* in_sizes, int n_in,
                              void* d_out, int out_size, void* d_ws, size_t ws_size,
                              hipStream_t stream) {
    const float* x      = (const float*)d_in[0];
    const float* times  = (const float*)d_in[1];
    const int*   lens   = (const int*)d_in[2];
    const float* R_u    = (const float*)d_in[3];
    const float* Wv1    = (const float*)d_in[4];
    const float* bv1    = (const float*)d_in[5];
    const float* Wv2    = (const float*)d_in[6];
    const float* bv2    = (const float*)d_in[7];
    const float* qkv_w  = (const float*)d_in[8];
    const float* qkv_b  = (const float*)d_in[9];
    const float* out_w  = (const float*)d_in[10];
    const float* out_b  = (const float*)d_in[11];
    const float* ln1_w  = (const float*)d_in[12];
    const float* ln1_b  = (const float*)d_in[13];
    const float* ln2_w  = (const float*)d_in[14];
    const float* ln2_b  = (const float*)d_in[15];
    const float* ffn_w1 = (const float*)d_in[16];
    const float* ffn_b1 = (const float*)d_in[17];
    const float* ffn_w2 = (const float*)d_in[18];
    const float* ffn_b2 = (const float*)d_in[19];
    const float* mlp_w1 = (const float*)d_in[20];
    const float* mlp_b1 = (const float*)d_in[21];
    const float* mlp_w2 = (const float*)d_in[22];
    const float* mlp_b2 = (const float*)d_in[23];
    float* outp = (float*)d_out;

    char* base = (char*)d_ws;
    size_t used = 0;
    auto alloc = [&](size_t bytes) -> char* {
        char* p = base + used;
        used += (bytes + 255) & ~(size_t)255;
        return p;
    };
    const int TB = T_DIM * B_DIM;  // 8192

    ushort* xn    = (ushort*)alloc((size_t)2048 * 1024 * 2);
    float*  val1  = (float*) alloc((size_t)2048 * 1024 * 4);
    ushort* s1    = (ushort*)alloc((size_t)32 * 1024 * 2);
    float*  out2  = (float*) alloc((size_t)32 * 1024 * 4);
    float*  pe    = (float*) alloc((size_t)TB * 16 * 4);
    ushort* seq   = (ushort*)alloc((size_t)TB * D_T * 2);
    ushort* qkvb  = (ushort*)alloc((size_t)TB * 960 * 2);   // head-padded bf16
    ushort* attno = (ushort*)alloc((size_t)TB * D_T * 2);
    float*  tmp   = (float*) alloc((size_t)TB * D_T * 4);
    ushort* x1    = (ushort*)alloc((size_t)TB * D_T * 2);
    ushort* h1    = (ushort*)alloc((size_t)TB * DFF_DIM * 2);
    float*  agg   = (float*) alloc((size_t)B_DIM * D_T * 4);
    ushort* wv1t  = (ushort*)alloc((size_t)1024 * 1024 * 2);
    ushort* wv2t  = (ushort*)alloc((size_t)1024 * 1024 * 2);
    ushort* qkvwt[2]; ushort* outwt[2]; ushort* f1wt[2]; ushort* f2wt[2];
    for (int l = 0; l < 2; ++l) {
        qkvwt[l] = (ushort*)alloc((size_t)272 * 816 * 2);
        outwt[l] = (ushort*)alloc((size_t)272 * 272 * 2);
        f1wt[l]  = (ushort*)alloc((size_t)272 * 1024 * 2);
        f2wt[l]  = (ushort*)alloc((size_t)1024 * 272 * 2);
    }
    if (used > ws_size) return;

    auto wconv = [&](const float* in, ushort* out, int K, int N) {
        int n = K * N;
        wconv_kernel<<<(n + 255) / 256, 256, 0, stream>>>(in, out, K, N);
    };
    wconv(Wv1, wv1t, 1024, 1024);
    wconv(Wv2, wv2t, 1024, 1024);
    for (int l = 0; l < 2; ++l) {
        wconv(qkv_w + (size_t)l * 272 * 816, qkvwt[l], 272, 816);
        wconv(out_w + (size_t)l * 272 * 272, outwt[l], 272, 272);
        wconv(ffn_w1 + (size_t)l * 272 * 1024, f1wt[l], 272, 1024);
        wconv(ffn_w2 + (size_t)l * 1024 * 272, f2wt[l], 1024, 272);
    }

    {
        int n = B_DIM * N_DIM * F_INF;
        xn_kernel<<<(n + 255) / 256, 256, 0, stream>>>(x, R_u, xn);
        int npe = TB * 8;
        pe_kernel<<<(npe + 255) / 256, 256, 0, stream>>>(times, pe);
    }

    gemm_mfma<1, 0><<<dim3(8, 16), 256, 0, stream>>>(xn, wv1t, bv1, val1, 2048, 1024, 1024);
    {
        int n = B_DIM * F_INF;
        reduce_s1_kernel<<<(n + 255) / 256, 256, 0, stream>>>(val1, s1);
    }
    gemm_mfma<1, 0><<<dim3(8, 1), 256, 0, stream>>>(s1, wv2t, bv2, out2, 32, 1024, 1024);

    {
        int n = TB * D_T;
        seq_kernel<<<(n + 255) / 256, 256, 0, stream>>>(out2, pe, seq);
    }

    hipMemsetAsync(qkvb, 0, (size_t)TB * 960 * 2, stream);

    for (int l = 0; l < 2; ++l) {
        const float* qb  = qkv_b + (size_t)l * 816;
        const float* ob  = out_b + (size_t)l * D_T;
        const float* l1w = ln1_w + (size_t)l * D_T;
        const float* l1b = ln1_b + (size_t)l * D_T;
        const float* l2w = ln2_w + (size_t)l * D_T;
        const float* l2b = ln2_b + (size_t)l * D_T;
        const float* f1b = ffn_b1 + (size_t)l * DFF_DIM;
        const float* f2b = ffn_b2 + (size_t)l * D_T;

        gemm_mfma<0, 2><<<dim3(7, 64), 256, 0, stream>>>(seq, qkvwt[l], qb, qkvb,
                                                         TB, 816, D_T);
        attn_mfma<<<B_DIM * H_DIM, 256, 0, stream>>>(qkvb, lens, attno);
        gemm_mfma<0, 0><<<dim3(3, 64), 256, 0, stream>>>(attno, outwt[l], ob, tmp,
                                                         TB, D_T, D_T);
        ln_kernel<<<TB, 64, 0, stream>>>(seq, tmp, l1w, l1b, x1);
        gemm_mfma<1, 1><<<dim3(8, 64), 256, 0, stream>>>(x1, f1wt[l], f1b, h1,
                                                         TB, DFF_DIM, D_T);
        gemm_mfma<0, 0><<<dim3(3, 64), 256, 0, stream>>>(h1, f2wt[l], f2b, tmp,
                                                         TB, D_T, DFF_DIM);
        ln_kernel<<<TB, 64, 0, stream>>>(x1, tmp, l2w, l2b, seq);
    }

    pool_kernel<<<dim3(5, B_DIM), 256, 0, stream>>>(seq, lens, agg);
    head_kernel<<<B_DIM, 320, 0, stream>>>(agg, mlp_w1, mlp_b1, mlp_w2, mlp_b2, outp);
}

// Round 5
// 393.184 us; speedup vs baseline: 2.8011x; 1.3793x over previous
//
#include <hip/hip_runtime.h>
#include <math.h>

#define T_DIM 256
#define B_DIM 32
#define N_DIM 64
#define F_INF 1024
#define D_T 272
#define H_DIM 8
#define DH_DIM 34
#define DFF_DIM 1024

typedef unsigned int uint;
typedef short bf16x8 __attribute__((ext_vector_type(8)));
typedef float f32x4 __attribute__((ext_vector_type(4)));

__device__ __forceinline__ ushort f2bf(float f) {
    uint u = __float_as_uint(f);
    uint r = (u + 0x7fffu + ((u >> 16) & 1u)) >> 16;
    return (ushort)r;
}
__device__ __forceinline__ float bf2f(ushort u) {
    return __uint_as_float(((uint)u) << 16);
}

// ---------------------------------------------------------------------------
// xn[b,n,t*4+d] = relu(x[t,b,n] * R_u[n*4+d])  -> bf16
// ---------------------------------------------------------------------------
__global__ void xn_kernel(const float* __restrict__ x, const float* __restrict__ Ru,
                          ushort* __restrict__ xn) {
    int idx = blockIdx.x * blockDim.x + threadIdx.x;
    if (idx >= B_DIM * N_DIM * F_INF) return;
    int f = idx & 1023;
    int bn = idx >> 10;
    int n = bn & 63;
    int b = bn >> 6;
    int t = f >> 2;
    int d = f & 3;
    float v = x[(t * B_DIM + b) * N_DIM + n] * Ru[(n << 2) + d];
    xn[idx] = f2bf(fmaxf(v, 0.0f));
}

// ---------------------------------------------------------------------------
// positional encoding (f32)
// ---------------------------------------------------------------------------
__global__ void pe_kernel(const float* __restrict__ times, float* __restrict__ pe) {
    int idx = blockIdx.x * blockDim.x + threadIdx.x;
    if (idx >= T_DIM * B_DIM * 8) return;
    int s = idx & 7;
    int tb = idx >> 3;
    float tv = times[tb];
    float scale = (float)pow(256.0, (double)s * (1.0 / 7.0));
    float st = tv / scale;
    pe[tb * 16 + s] = sinf(st);
    pe[tb * 16 + 8 + s] = cosf(st);
}

// ---------------------------------------------------------------------------
// merged weight convert+transpose: 10 segments, f32 [K,N] -> bf16 [N,K]
// ---------------------------------------------------------------------------
struct WSegs {
    int start[11];
    const float* src[10];
    ushort* dst[10];
    int K[10];
    int N[10];
};
__global__ __launch_bounds__(256) void wconv_all(WSegs s, int total) {
    int idx = blockIdx.x * 256 + threadIdx.x;
    if (idx >= total) return;
    int seg = 0;
    while (seg < 9 && idx >= s.start[seg + 1]) ++seg;
    int e = idx - s.start[seg];
    int N = s.N[seg], K = s.K[seg];
    int k = e / N;
    int n = e - k * N;
    s.dst[seg][(size_t)n * K + k] = f2bf(s.src[seg][e]);
}

// ---------------------------------------------------------------------------
// MFMA bf16 GEMM, T3 2-phase pipeline.
// C[M,N] = act(A[M,K] @ Bt[N,K]^T + bias[N])
// BM=64, BN=128, BK=32; 256 thr = 4 waves (2x2), wave tile 32x64.
// Double-buffered LDS; staging via global_load_lds (16B/lane), source-side
// XOR chunk swizzle (LDS stays linear); prefetch next K-tile before compute,
// single vmcnt(0)+s_barrier per step. K-tail (K%32) staged via guarded
// reg path with zero fill. M/N tails: clamped addresses (outputs discarded).
// OUT_MODE: 0 = f32 flat, 1 = bf16 flat, 2 = bf16 head-padded QKV layout.
// ---------------------------------------------------------------------------
template <int ACT, int OUT_MODE>
__global__ __launch_bounds__(256) void gemm_mfma(const ushort* __restrict__ A,
                                                 const ushort* __restrict__ Bt,
                                                 const float* __restrict__ bias,
                                                 void* __restrict__ Cout,
                                                 int M, int N, int K) {
    __shared__ ushort As[2][64 * 32];
    __shared__ ushort Bs[2][128 * 32];
    const int tid = threadIdx.x;
    const int m0 = blockIdx.y * 64;
    const int n0 = blockIdx.x * 128;
    const int w = tid >> 6, lane = tid & 63;
    const int wr = w >> 1, wc = w & 1;
    const int lr = lane & 15, lk = lane >> 4;

    const int nfull = K >> 5;
    const int ns = (K + 31) >> 5;

    // fast-path per-lane global source pointers (source-side chunk swizzle)
    const int ra = w * 16 + (lane >> 2);
    const int ca = (((lane & 3) ^ ((ra >> 1) & 3)) << 3);
    int gma = m0 + ra; if (gma > M - 1) gma = M - 1;
    const ushort* gA = &A[(size_t)gma * K + ca];
    const int rb0 = w * 32 + (lane >> 2);
    const int cb0 = (((lane & 3) ^ ((rb0 >> 1) & 3)) << 3);
    const int rb1 = rb0 + 16;
    const int cb1 = (((lane & 3) ^ ((rb1 >> 1) & 3)) << 3);
    int gnb0 = n0 + rb0; if (gnb0 > N - 1) gnb0 = N - 1;
    int gnb1 = n0 + rb1; if (gnb1 > N - 1) gnb1 = N - 1;
    const ushort* gB0 = &Bt[(size_t)gnb0 * K + cb0];
    const ushort* gB1 = &Bt[(size_t)gnb1 * K + cb1];

    f32x4 acc[2][4];
#pragma unroll
    for (int i = 0; i < 2; ++i)
#pragma unroll
        for (int j = 0; j < 4; ++j) acc[i][j] = (f32x4){0.f, 0.f, 0.f, 0.f};

    auto stage = [&](int buf, int s) {
        const int k0 = s << 5;
        if (s < nfull) {
            __builtin_amdgcn_global_load_lds(
                (const __attribute__((address_space(1))) void*)(gA + k0),
                (__attribute__((address_space(3))) void*)(&As[buf][w * 512]), 16, 0, 0);
            __builtin_amdgcn_global_load_lds(
                (const __attribute__((address_space(1))) void*)(gB0 + k0),
                (__attribute__((address_space(3))) void*)(&Bs[buf][w * 1024]), 16, 0, 0);
            __builtin_amdgcn_global_load_lds(
                (const __attribute__((address_space(1))) void*)(gB1 + k0),
                (__attribute__((address_space(3))) void*)(&Bs[buf][w * 1024 + 512]), 16, 0, 0);
        } else {
            // K-tail: guarded reg loads, zero fill, ds_write
            {
                int r = tid >> 2, p = tid & 3;
                int g = p ^ ((r >> 1) & 3);
                int gm = m0 + r; if (gm > M - 1) gm = M - 1;
                ushort v[8];
#pragma unroll
                for (int e = 0; e < 8; ++e) {
                    int gk = k0 + g * 8 + e;
                    v[e] = (gk < K) ? A[(size_t)gm * K + gk] : (ushort)0;
                }
                *reinterpret_cast<uint4*>(&As[buf][r * 32 + p * 8]) =
                    *reinterpret_cast<uint4*>(v);
            }
#pragma unroll
            for (int rr = 0; rr < 2; ++rr) {
                int r = rr * 64 + (tid >> 2), p = tid & 3;
                int g = p ^ ((r >> 1) & 3);
                int gn = n0 + r; if (gn > N - 1) gn = N - 1;
                ushort v[8];
#pragma unroll
                for (int e = 0; e < 8; ++e) {
                    int gk = k0 + g * 8 + e;
                    v[e] = (gk < K) ? Bt[(size_t)gn * K + gk] : (ushort)0;
                }
                *reinterpret_cast<uint4*>(&Bs[buf][r * 32 + p * 8]) =
                    *reinterpret_cast<uint4*>(v);
            }
        }
    };

    // prologue
    stage(0, 0);
    asm volatile("s_waitcnt vmcnt(0) lgkmcnt(0)" ::: "memory");
    __builtin_amdgcn_sched_barrier(0);
    __builtin_amdgcn_s_barrier();
    __builtin_amdgcn_sched_barrier(0);

    int cur = 0;
    for (int s = 0; s < ns; ++s) {
        if (s + 1 < ns) stage(cur ^ 1, s + 1);

        bf16x8 af[2], bf[4];
#pragma unroll
        for (int mt = 0; mt < 2; ++mt) {
            int row = wr * 32 + mt * 16 + lr;
            int ch = lk ^ ((row >> 1) & 3);
            af[mt] = *reinterpret_cast<const bf16x8*>(&As[cur][row * 32 + ch * 8]);
        }
#pragma unroll
        for (int nt = 0; nt < 4; ++nt) {
            int row = wc * 64 + nt * 16 + lr;
            int ch = lk ^ ((row >> 1) & 3);
            bf[nt] = *reinterpret_cast<const bf16x8*>(&Bs[cur][row * 32 + ch * 8]);
        }
#pragma unroll
        for (int mt = 0; mt < 2; ++mt)
#pragma unroll
            for (int nt = 0; nt < 4; ++nt)
                acc[mt][nt] = __builtin_amdgcn_mfma_f32_16x16x32_bf16(
                    af[mt], bf[nt], acc[mt][nt], 0, 0, 0);

        if (s + 1 < ns) {
            asm volatile("s_waitcnt vmcnt(0) lgkmcnt(0)" ::: "memory");
            __builtin_amdgcn_sched_barrier(0);
            __builtin_amdgcn_s_barrier();
            __builtin_amdgcn_sched_barrier(0);
        }
        cur ^= 1;
    }

    // epilogue: D layout col=lane&15, row=(lane>>4)*4+reg
#pragma unroll
    for (int nt = 0; nt < 4; ++nt) {
        int col = n0 + wc * 64 + nt * 16 + lr;
        if (col >= N) continue;
        float bv = bias[col];
        int g = 0, dcol = 0;
        if (OUT_MODE == 2) { g = col / 34; dcol = col - g * 34; }
#pragma unroll
        for (int mt = 0; mt < 2; ++mt) {
#pragma unroll
            for (int r = 0; r < 4; ++r) {
                int row = m0 + wr * 32 + mt * 16 + lk * 4 + r;
                if (row >= M) continue;
                float v = acc[mt][nt][r] + bv;
                if (ACT == 1) v = fmaxf(v, 0.0f);
                if (OUT_MODE == 0)
                    ((float*)Cout)[(size_t)row * N + col] = v;
                else if (OUT_MODE == 1)
                    ((ushort*)Cout)[(size_t)row * N + col] = f2bf(v);
                else
                    ((ushort*)Cout)[(size_t)row * 960 + g * 40 + dcol] = f2bf(v);
            }
        }
    }
}

// ---------------------------------------------------------------------------
// s1[b,g] = (1/64) * sum_n val1[(b*64+n), g]   f32 in, bf16 out
// ---------------------------------------------------------------------------
__global__ void reduce_s1_kernel(const float* __restrict__ val1, ushort* __restrict__ s1) {
    int idx = blockIdx.x * blockDim.x + threadIdx.x;
    if (idx >= B_DIM * F_INF) return;
    int b = idx >> 10;
    int g = idx & 1023;
    float s = 0.f;
#pragma unroll 8
    for (int n = 0; n < 64; ++n) s += val1[(size_t)((b << 6) + n) * F_INF + g];
    s1[idx] = f2bf(s * (1.0f / 64.0f));
}

// ---------------------------------------------------------------------------
// seq[t,b,c] = (c<256) ? out2[b, t*4 + c%4] : pe[t,b,c-256]   -> bf16
// ---------------------------------------------------------------------------
__global__ void seq_kernel(const float* __restrict__ out2, const float* __restrict__ pe,
                           ushort* __restrict__ seq) {
    int idx = blockIdx.x * blockDim.x + threadIdx.x;
    if (idx >= T_DIM * B_DIM * D_T) return;
    int c = idx % D_T;
    int tb = idx / D_T;
    float v;
    if (c < 256)
        v = out2[(tb % B_DIM) * 1024 + ((tb / B_DIM) << 2) + (c & 3)];
    else
        v = pe[tb * 16 + (c - 256)];
    seq[idx] = f2bf(v);
}

// ---------------------------------------------------------------------------
// MFMA flash attention. Block = (b,h), 4 waves x 64 queries, KV chunks of 64.
// ---------------------------------------------------------------------------
__global__ __launch_bounds__(256) void attn_mfma(const ushort* __restrict__ qkv,
                                                 const int* __restrict__ lengths,
                                                 ushort* __restrict__ attno) {
    const int b = blockIdx.x >> 3;
    const int h = blockIdx.x & 7;
    const int tid = threadIdx.x;
    const int w = tid >> 6, lane = tid & 63;
    const int lr = lane & 15, lk = lane >> 4;
    __shared__ ushort Ks[64 * 40];
    __shared__ ushort Vt[48 * 72];
    __shared__ ushort Ps[4][64 * 72];
    const int len = lengths[b];
    const float scale = 0.1714985851f;  // 1/sqrt(34)
    const bf16x8 zv = {0, 0, 0, 0, 0, 0, 0, 0};

    bf16x8 qf0[4], qf1[4];
#pragma unroll
    for (int it = 0; it < 4; ++it) {
        int t = w * 64 + it * 16 + lr;
        const ushort* qrow = &qkv[(size_t)(t * 32 + b) * 960 + h * 40];
        qf0[it] = *reinterpret_cast<const bf16x8*>(qrow + lk * 8);
        qf1[it] = (lk == 0) ? *reinterpret_cast<const bf16x8*>(qrow + 32) : zv;
    }

    f32x4 oacc[4][3];
#pragma unroll
    for (int it = 0; it < 4; ++it)
#pragma unroll
        for (int dt = 0; dt < 3; ++dt) oacc[it][dt] = (f32x4){0.f, 0.f, 0.f, 0.f};
    float m[4][4], l[4][4];
#pragma unroll
    for (int it = 0; it < 4; ++it)
#pragma unroll
        for (int r = 0; r < 4; ++r) { m[it][r] = -1e30f; l[it][r] = 0.f; }

    const int nchunks = (len + 63) >> 6;
    for (int c = 0; c < nchunks; ++c) {
        __syncthreads();
        for (int idx = tid; idx < 320; idx += 256) {
            int row = idx / 5, ch = idx - row * 5;
            int j = c * 64 + row;
            const ushort* kr = &qkv[(size_t)(j * 32 + b) * 960 + 320 + h * 40];
            *reinterpret_cast<bf16x8*>(&Ks[row * 40 + ch * 8]) =
                *reinterpret_cast<const bf16x8*>(kr + ch * 8);
        }
        for (int idx = tid; idx < 64 * 48; idx += 256) {
            int j = idx / 48, d = idx - j * 48;
            ushort v = 0;
            if (d < 34) {
                int jj = c * 64 + j;
                v = qkv[(size_t)(jj * 32 + b) * 960 + 640 + h * 40 + d];
            }
            int jp = (j & 15) * 4 + (j >> 4);
            Vt[d * 72 + jp] = v;
        }
        __syncthreads();

        bf16x8 kf0[4], kf1[4];
#pragma unroll
        for (int jt = 0; jt < 4; ++jt) {
            int j = jt * 16 + lr;
            kf0[jt] = *reinterpret_cast<const bf16x8*>(&Ks[j * 40 + lk * 8]);
            kf1[jt] = (lk == 0) ? *reinterpret_cast<const bf16x8*>(&Ks[j * 40 + 32]) : zv;
        }

        const bool tail = (c * 64 + 64 > len);
#pragma unroll
        for (int it = 0; it < 4; ++it) {
            f32x4 sacc[4];
#pragma unroll
            for (int jt = 0; jt < 4; ++jt) sacc[jt] = (f32x4){0.f, 0.f, 0.f, 0.f};
#pragma unroll
            for (int jt = 0; jt < 4; ++jt) {
                sacc[jt] = __builtin_amdgcn_mfma_f32_16x16x32_bf16(qf0[it], kf0[jt],
                                                                   sacc[jt], 0, 0, 0);
                sacc[jt] = __builtin_amdgcn_mfma_f32_16x16x32_bf16(qf1[it], kf1[jt],
                                                                   sacc[jt], 0, 0, 0);
            }
            float cm[4] = {-1e30f, -1e30f, -1e30f, -1e30f};
#pragma unroll
            for (int jt = 0; jt < 4; ++jt) {
                bool dead = tail && (c * 64 + jt * 16 + lr >= len);
#pragma unroll
                for (int r = 0; r < 4; ++r) {
                    float sv = dead ? -1e30f : sacc[jt][r];
                    sacc[jt][r] = sv;
                    cm[r] = fmaxf(cm[r], sv);
                }
            }
#pragma unroll
            for (int mask = 1; mask <= 8; mask <<= 1)
#pragma unroll
                for (int r = 0; r < 4; ++r) cm[r] = fmaxf(cm[r], __shfl_xor(cm[r], mask));
#pragma unroll
            for (int r = 0; r < 4; ++r) {
                float mn = fmaxf(m[it][r], cm[r]);
                float corr = __expf((m[it][r] - mn) * scale);
                m[it][r] = mn;
                l[it][r] *= corr;
#pragma unroll
                for (int dt = 0; dt < 3; ++dt) oacc[it][dt][r] *= corr;
            }
            float ls[4] = {0.f, 0.f, 0.f, 0.f};
#pragma unroll
            for (int jt = 0; jt < 4; ++jt)
#pragma unroll
                for (int r = 0; r < 4; ++r) {
                    float e = __expf((sacc[jt][r] - m[it][r]) * scale);
                    sacc[jt][r] = e;
                    ls[r] += e;
                }
#pragma unroll
            for (int mask = 1; mask <= 8; mask <<= 1)
#pragma unroll
                for (int r = 0; r < 4; ++r) ls[r] += __shfl_xor(ls[r], mask);
#pragma unroll
            for (int r = 0; r < 4; ++r) l[it][r] += ls[r];
#pragma unroll
            for (int r = 0; r < 4; ++r) {
                int i = it * 16 + lk * 4 + r;
                uint u0 = (uint)f2bf(sacc[0][r]) | ((uint)f2bf(sacc[1][r]) << 16);
                uint u1 = (uint)f2bf(sacc[2][r]) | ((uint)f2bf(sacc[3][r]) << 16);
                uint2 pk = make_uint2(u0, u1);
                *reinterpret_cast<uint2*>(&Ps[w][i * 72 + lr * 4]) = pk;
            }
        }

        bf16x8 vf[3][2], pf[4][2];
#pragma unroll
        for (int dt = 0; dt < 3; ++dt)
#pragma unroll
            for (int ks = 0; ks < 2; ++ks)
                vf[dt][ks] = *reinterpret_cast<const bf16x8*>(
                    &Vt[(dt * 16 + lr) * 72 + ks * 32 + lk * 8]);
#pragma unroll
        for (int it = 0; it < 4; ++it)
#pragma unroll
            for (int ks = 0; ks < 2; ++ks)
                pf[it][ks] = *reinterpret_cast<const bf16x8*>(
                    &Ps[w][(it * 16 + lr) * 72 + ks * 32 + lk * 8]);
#pragma unroll
        for (int it = 0; it < 4; ++it)
#pragma unroll
            for (int dt = 0; dt < 3; ++dt)
#pragma unroll
                for (int ks = 0; ks < 2; ++ks)
                    oacc[it][dt] = __builtin_amdgcn_mfma_f32_16x16x32_bf16(
                        pf[it][ks], vf[dt][ks], oacc[it][dt], 0, 0, 0);
    }

#pragma unroll
    for (int it = 0; it < 4; ++it)
#pragma unroll
        for (int r = 0; r < 4; ++r) {
            float inv = 1.0f / l[it][r];
            int t = w * 64 + it * 16 + lk * 4 + r;
            ushort* orow = &attno[(size_t)(t * 32 + b) * 272 + h * 34];
#pragma unroll
            for (int dt = 0; dt < 3; ++dt) {
                int d = dt * 16 + lr;
                if (d < 34) orow[d] = f2bf(oacc[it][dt][r] * inv);
            }
        }
}

// ---------------------------------------------------------------------------
// LN: out = LN(bf16 X + f32 Y) * w + b  -> bf16. One wave per row (272 wide).
// ---------------------------------------------------------------------------
__global__ __launch_bounds__(64) void ln_kernel(const ushort* __restrict__ X,
                                                const float* __restrict__ Y,
                                                const float* __restrict__ w,
                                                const float* __restrict__ bsh,
                                                ushort* __restrict__ out) {
    int row = blockIdx.x;
    int tid = threadIdx.x;
    const ushort* xr = X + (size_t)row * D_T;
    const float* yr = Y + (size_t)row * D_T;
    float v[5];
    float sum = 0.f, sumsq = 0.f;
#pragma unroll
    for (int k = 0; k < 5; ++k) {
        int c = tid + k * 64;
        float t = 0.f;
        if (c < D_T) t = bf2f(xr[c]) + yr[c];
        v[k] = t;
        sum += t;
        sumsq += t * t;
    }
#pragma unroll
    for (int off = 32; off; off >>= 1) {
        sum += __shfl_down(sum, off);
        sumsq += __shfl_down(sumsq, off);
    }
    sum = __shfl(sum, 0);
    sumsq = __shfl(sumsq, 0);
    float mu = sum * (1.0f / D_T);
    float var = sumsq * (1.0f / D_T) - mu * mu;
    float inv = 1.0f / sqrtf(var + 1e-5f);
    ushort* orow = out + (size_t)row * D_T;
#pragma unroll
    for (int k = 0; k < 5; ++k) {
        int c = tid + k * 64;
        if (c < D_T) orow[c] = f2bf((v[k] - mu) * inv * w[c] + bsh[c]);
    }
}

// ---------------------------------------------------------------------------
// pool: agg[b,c] = sum_{t<len_b} seq[t,b,c] / (len_b+1)
// ---------------------------------------------------------------------------
__global__ __launch_bounds__(256) void pool_kernel(const ushort* __restrict__ seq,
                                                   const int* __restrict__ lengths,
                                                   float* __restrict__ agg) {
    const int b = blockIdx.y;
    const int c = blockIdx.x * 64 + (threadIdx.x & 63);
    const int tg = threadIdx.x >> 6;
    const int len = lengths[b];
    __shared__ float part[4][64];
    float s = 0.f;
    if (c < D_T) {
        for (int t = tg; t < len; t += 4)
            s += bf2f(seq[(size_t)(t * B_DIM + b) * D_T + c]);
    }
    part[tg][threadIdx.x & 63] = s;
    __syncthreads();
    if (tg == 0 && c < D_T) {
        float tot = part[0][threadIdx.x] + part[1][threadIdx.x] +
                    part[2][threadIdx.x] + part[3][threadIdx.x];
        agg[b * D_T + c] = tot / (float)(len + 1);
    }
}

// ---------------------------------------------------------------------------
// Head (f32): hid = relu(agg@w1+b1); logits = hid@w2+b2; softmax
// ---------------------------------------------------------------------------
__global__ __launch_bounds__(320) void head_kernel(const float* __restrict__ agg,
                                                   const float* __restrict__ w1,
                                                   const float* __restrict__ b1,
                                                   const float* __restrict__ w2,
                                                   const float* __restrict__ b2,
                                                   float* __restrict__ out) {
    int b = blockIdx.x;
    int tid = threadIdx.x;
    __shared__ float hid[D_T];
    __shared__ float arow[D_T];
    if (tid < D_T) arow[tid] = agg[b * D_T + tid];
    __syncthreads();
    if (tid < D_T) {
        float s = b1[tid];
        for (int k = 0; k < D_T; ++k) s += arow[k] * w1[k * D_T + tid];
        hid[tid] = fmaxf(s, 0.f);
    }
    __syncthreads();
    if (tid < 64) {
        float l0 = 0.f, l1 = 0.f;
        for (int k = tid; k < D_T; k += 64) {
            float hv = hid[k];
            l0 += hv * w2[k * 2 + 0];
            l1 += hv * w2[k * 2 + 1];
        }
#pragma unroll
        for (int off = 32; off; off >>= 1) {
            l0 += __shfl_down(l0, off);
            l1 += __shfl_down(l1, off);
        }
        if (tid == 0) {
            l0 += b2[0];
            l1 += b2[1];
            float mx = fmaxf(l0, l1);
            float e0 = expf(l0 - mx), e1 = expf(l1 - mx);
            float inv = 1.0f / (e0 + e1);
            out[b * 2 + 0] = e0 * inv;
            out[b * 2 + 1] = e1 * inv;
        }
    }
}

// ---------------------------------------------------------------------------
extern "C" void kernel_launch(void* const* d_in, const int* in_sizes, int n_in,
                              void* d_out, int out_size, void* d_ws, size_t ws_size,
                              hipStream_t stream) {
    const float* x      = (const float*)d_in[0];
    const float* times  = (const float*)d_in[1];
    const int*   lens   = (const int*)d_in[2];
    const float* R_u    = (const float*)d_in[3];
    const float* Wv1    = (const float*)d_in[4];
    const float* bv1    = (const float*)d_in[5];
    const float* Wv2    = (const float*)d_in[6];
    const float* bv2    = (const float*)d_in[7];
    const float* qkv_w  = (const float*)d_in[8];
    const float* qkv_b  = (const float*)d_in[9];
    const float* out_w  = (const float*)d_in[10];
    const float* out_b  = (const float*)d_in[11];
    const float* ln1_w  = (const float*)d_in[12];
    const float* ln1_b  = (const float*)d_in[13];
    const float* ln2_w  = (const float*)d_in[14];
    const float* ln2_b  = (const float*)d_in[15];
    const float* ffn_w1 = (const float*)d_in[16];
    const float* ffn_b1 = (const float*)d_in[17];
    const float* ffn_w2 = (const float*)d_in[18];
    const float* ffn_b2 = (const float*)d_in[19];
    const float* mlp_w1 = (const float*)d_in[20];
    const float* mlp_b1 = (const float*)d_in[21];
    const float* mlp_w2 = (const float*)d_in[22];
    const float* mlp_b2 = (const float*)d_in[23];
    float* outp = (float*)d_out;

    char* base = (char*)d_ws;
    size_t used = 0;
    auto alloc = [&](size_t bytes) -> char* {
        char* p = base + used;
        used += (bytes + 255) & ~(size_t)255;
        return p;
    };
    const int TB = T_DIM * B_DIM;  // 8192

    ushort* xn    = (ushort*)alloc((size_t)2048 * 1024 * 2);
    float*  val1  = (float*) alloc((size_t)2048 * 1024 * 4);
    ushort* s1    = (ushort*)alloc((size_t)32 * 1024 * 2);
    float*  out2  = (float*) alloc((size_t)32 * 1024 * 4);
    float*  pe    = (float*) alloc((size_t)TB * 16 * 4);
    ushort* seq   = (ushort*)alloc((size_t)TB * D_T * 2);
    ushort* qkvb  = (ushort*)alloc((size_t)TB * 960 * 2);   // head-padded bf16
    ushort* attno = (ushort*)alloc((size_t)TB * D_T * 2);
    float*  tmp   = (float*) alloc((size_t)TB * D_T * 4);
    ushort* x1    = (ushort*)alloc((size_t)TB * D_T * 2);
    ushort* h1    = (ushort*)alloc((size_t)TB * DFF_DIM * 2);
    float*  agg   = (float*) alloc((size_t)B_DIM * D_T * 4);
    ushort* wv1t  = (ushort*)alloc((size_t)1024 * 1024 * 2);
    ushort* wv2t  = (ushort*)alloc((size_t)1024 * 1024 * 2);
    ushort* qkvwt[2]; ushort* outwt[2]; ushort* f1wt[2]; ushort* f2wt[2];
    for (int l = 0; l < 2; ++l) {
        qkvwt[l] = (ushort*)alloc((size_t)272 * 816 * 2);
        outwt[l] = (ushort*)alloc((size_t)272 * 272 * 2);
        f1wt[l]  = (ushort*)alloc((size_t)272 * 1024 * 2);
        f2wt[l]  = (ushort*)alloc((size_t)1024 * 272 * 2);
    }
    if (used > ws_size) return;

    // ---- merged weight convert+transpose (1 dispatch) ----
    {
        WSegs segs;
        const float* srcs[10] = {Wv1, Wv2,
                                 qkv_w, out_w, ffn_w1, ffn_w2,
                                 qkv_w + (size_t)272 * 816, out_w + (size_t)272 * 272,
                                 ffn_w1 + (size_t)272 * 1024, ffn_w2 + (size_t)1024 * 272};
        ushort* dsts[10] = {wv1t, wv2t, qkvwt[0], outwt[0], f1wt[0], f2wt[0],
                            qkvwt[1], outwt[1], f1wt[1], f2wt[1]};
        int Ks[10] = {1024, 1024, 272, 272, 272, 1024, 272, 272, 272, 1024};
        int Ns[10] = {1024, 1024, 816, 272, 1024, 272, 816, 272, 1024, 272};
        int acc = 0;
        for (int i = 0; i < 10; ++i) {
            segs.start[i] = acc;
            segs.src[i] = srcs[i];
            segs.dst[i] = dsts[i];
            segs.K[i] = Ks[i];
            segs.N[i] = Ns[i];
            acc += Ks[i] * Ns[i];
        }
        segs.start[10] = acc;
        wconv_all<<<(acc + 255) / 256, 256, 0, stream>>>(segs, acc);
    }

    {
        int n = B_DIM * N_DIM * F_INF;
        xn_kernel<<<(n + 255) / 256, 256, 0, stream>>>(x, R_u, xn);
        int npe = TB * 8;
        pe_kernel<<<(npe + 255) / 256, 256, 0, stream>>>(times, pe);
    }

    // prop1: [2048,1024] @ [1024,1024]  grid 32x8 = 256 blocks
    gemm_mfma<1, 0><<<dim3(8, 32), 256, 0, stream>>>(xn, wv1t, bv1, val1, 2048, 1024, 1024);
    {
        int n = B_DIM * F_INF;
        reduce_s1_kernel<<<(n + 255) / 256, 256, 0, stream>>>(val1, s1);
    }
    // prop2 (collapsed): [32,1024] @ [1024,1024]
    gemm_mfma<1, 0><<<dim3(8, 1), 256, 0, stream>>>(s1, wv2t, bv2, out2, 32, 1024, 1024);

    {
        int n = TB * D_T;
        seq_kernel<<<(n + 255) / 256, 256, 0, stream>>>(out2, pe, seq);
    }

    hipMemsetAsync(qkvb, 0, (size_t)TB * 960 * 2, stream);

    for (int l = 0; l < 2; ++l) {
        const float* qb  = qkv_b + (size_t)l * 816;
        const float* ob  = out_b + (size_t)l * D_T;
        const float* l1w = ln1_w + (size_t)l * D_T;
        const float* l1b = ln1_b + (size_t)l * D_T;
        const float* l2w = ln2_w + (size_t)l * D_T;
        const float* l2b = ln2_b + (size_t)l * D_T;
        const float* f1b = ffn_b1 + (size_t)l * DFF_DIM;
        const float* f2b = ffn_b2 + (size_t)l * D_T;

        // QKV: [8192,272] @ [272,816] -> bf16 head-padded. grid 128x7
        gemm_mfma<0, 2><<<dim3(7, 128), 256, 0, stream>>>(seq, qkvwt[l], qb, qkvb,
                                                          TB, 816, D_T);
        attn_mfma<<<B_DIM * H_DIM, 256, 0, stream>>>(qkvb, lens, attno);
        // out-proj: [8192,272] @ [272,272] -> f32. grid 128x3
        gemm_mfma<0, 0><<<dim3(3, 128), 256, 0, stream>>>(attno, outwt[l], ob, tmp,
                                                          TB, D_T, D_T);
        ln_kernel<<<TB, 64, 0, stream>>>(seq, tmp, l1w, l1b, x1);
        // FFN1: relu([8192,272] @ [272,1024]) -> bf16. grid 128x8
        gemm_mfma<1, 1><<<dim3(8, 128), 256, 0, stream>>>(x1, f1wt[l], f1b, h1,
                                                          TB, DFF_DIM, D_T);
        // FFN2: [8192,1024] @ [1024,272] -> f32. grid 128x3
        gemm_mfma<0, 0><<<dim3(3, 128), 256, 0, stream>>>(h1, f2wt[l], f2b, tmp,
                                                          TB, D_T, DFF_DIM);
        ln_kernel<<<TB, 64, 0, stream>>>(x1, tmp, l2w, l2b, seq);
    }

    pool_kernel<<<dim3(5, B_DIM), 256, 0, stream>>>(seq, lens, agg);
    head_kernel<<<B_DIM, 320, 0, stream>>>(agg, mlp_w1, mlp_b1, mlp_w2, mlp_b2, outp);
}

// Round 6
// 355.457 us; speedup vs baseline: 3.0984x; 1.1061x over previous
//
#include <hip/hip_runtime.h>
#include <math.h>

#define T_DIM 256
#define B_DIM 32
#define N_DIM 64
#define F_INF 1024
#define D_T 272
#define H_DIM 8
#define DH_DIM 34
#define DFF_DIM 1024

typedef unsigned int uint;
typedef short bf16x8 __attribute__((ext_vector_type(8)));
typedef float f32x4 __attribute__((ext_vector_type(4)));

__device__ __forceinline__ ushort f2bf(float f) {
    uint u = __float_as_uint(f);
    uint r = (u + 0x7fffu + ((u >> 16) & 1u)) >> 16;
    return (ushort)r;
}
__device__ __forceinline__ float bf2f(ushort u) {
    return __uint_as_float(((uint)u) << 16);
}

// ---------------------------------------------------------------------------
// xn[b,n,t*4+d] = relu(x[t,b,n] * R_u[n*4+d])  -> bf16
// ---------------------------------------------------------------------------
__global__ void xn_kernel(const float* __restrict__ x, const float* __restrict__ Ru,
                          ushort* __restrict__ xn) {
    int idx = blockIdx.x * blockDim.x + threadIdx.x;
    if (idx >= B_DIM * N_DIM * F_INF) return;
    int f = idx & 1023;
    int bn = idx >> 10;
    int n = bn & 63;
    int b = bn >> 6;
    int t = f >> 2;
    int d = f & 3;
    float v = x[(t * B_DIM + b) * N_DIM + n] * Ru[(n << 2) + d];
    xn[idx] = f2bf(fmaxf(v, 0.0f));
}

// ---------------------------------------------------------------------------
// tiled weight convert+transpose: f32 [K,N] -> bf16 [N,K], 16x16 LDS tiles,
// coalesced reads and writes. All segment dims are multiples of 16.
// ---------------------------------------------------------------------------
struct WT {
    int tstart[11];
    const float* src[10];
    ushort* dst[10];
    int K[10];
    int N[10];
    int ntn[10];  // N/16
};
__global__ __launch_bounds__(256) void wconv_tiled(WT s) {
    int tile = blockIdx.x;
    int seg = 0;
    while (seg < 9 && tile >= s.tstart[seg + 1]) ++seg;
    int ti = tile - s.tstart[seg];
    int ntn = s.ntn[seg];
    int tk = ti / ntn, tn = ti - tk * ntn;
    int K = s.K[seg], N = s.N[seg];
    __shared__ float t[16][17];
    int ty = threadIdx.x >> 4, tx = threadIdx.x & 15;
    t[ty][tx] = s.src[seg][(size_t)(tk * 16 + ty) * N + tn * 16 + tx];
    __syncthreads();
    s.dst[seg][(size_t)(tn * 16 + ty) * K + tk * 16 + tx] = f2bf(t[tx][ty]);
}

// ---------------------------------------------------------------------------
// MFMA bf16 GEMM, T3 2-phase pipeline (validated round 5).
// BM=64, BN=128, BK=32; 256 thr = 4 waves (2x2), wave tile 32x64.
// OUT_MODE: 0 = f32 flat, 1 = bf16 flat, 2 = bf16 head-padded QKV layout.
// ---------------------------------------------------------------------------
template <int ACT, int OUT_MODE>
__global__ __launch_bounds__(256) void gemm_mfma(const ushort* __restrict__ A,
                                                 const ushort* __restrict__ Bt,
                                                 const float* __restrict__ bias,
                                                 void* __restrict__ Cout,
                                                 int M, int N, int K) {
    __shared__ ushort As[2][64 * 32];
    __shared__ ushort Bs[2][128 * 32];
    const int tid = threadIdx.x;
    const int m0 = blockIdx.y * 64;
    const int n0 = blockIdx.x * 128;
    const int w = tid >> 6, lane = tid & 63;
    const int wr = w >> 1, wc = w & 1;
    const int lr = lane & 15, lk = lane >> 4;

    const int nfull = K >> 5;
    const int ns = (K + 31) >> 5;

    const int ra = w * 16 + (lane >> 2);
    const int ca = (((lane & 3) ^ ((ra >> 1) & 3)) << 3);
    int gma = m0 + ra; if (gma > M - 1) gma = M - 1;
    const ushort* gA = &A[(size_t)gma * K + ca];
    const int rb0 = w * 32 + (lane >> 2);
    const int cb0 = (((lane & 3) ^ ((rb0 >> 1) & 3)) << 3);
    const int rb1 = rb0 + 16;
    const int cb1 = (((lane & 3) ^ ((rb1 >> 1) & 3)) << 3);
    int gnb0 = n0 + rb0; if (gnb0 > N - 1) gnb0 = N - 1;
    int gnb1 = n0 + rb1; if (gnb1 > N - 1) gnb1 = N - 1;
    const ushort* gB0 = &Bt[(size_t)gnb0 * K + cb0];
    const ushort* gB1 = &Bt[(size_t)gnb1 * K + cb1];

    f32x4 acc[2][4];
#pragma unroll
    for (int i = 0; i < 2; ++i)
#pragma unroll
        for (int j = 0; j < 4; ++j) acc[i][j] = (f32x4){0.f, 0.f, 0.f, 0.f};

    auto stage = [&](int buf, int s) {
        const int k0 = s << 5;
        if (s < nfull) {
            __builtin_amdgcn_global_load_lds(
                (const __attribute__((address_space(1))) void*)(gA + k0),
                (__attribute__((address_space(3))) void*)(&As[buf][w * 512]), 16, 0, 0);
            __builtin_amdgcn_global_load_lds(
                (const __attribute__((address_space(1))) void*)(gB0 + k0),
                (__attribute__((address_space(3))) void*)(&Bs[buf][w * 1024]), 16, 0, 0);
            __builtin_amdgcn_global_load_lds(
                (const __attribute__((address_space(1))) void*)(gB1 + k0),
                (__attribute__((address_space(3))) void*)(&Bs[buf][w * 1024 + 512]), 16, 0, 0);
        } else {
            {
                int r = tid >> 2, p = tid & 3;
                int g = p ^ ((r >> 1) & 3);
                int gm = m0 + r; if (gm > M - 1) gm = M - 1;
                ushort v[8];
#pragma unroll
                for (int e = 0; e < 8; ++e) {
                    int gk = k0 + g * 8 + e;
                    v[e] = (gk < K) ? A[(size_t)gm * K + gk] : (ushort)0;
                }
                *reinterpret_cast<uint4*>(&As[buf][r * 32 + p * 8]) =
                    *reinterpret_cast<uint4*>(v);
            }
#pragma unroll
            for (int rr = 0; rr < 2; ++rr) {
                int r = rr * 64 + (tid >> 2), p = tid & 3;
                int g = p ^ ((r >> 1) & 3);
                int gn = n0 + r; if (gn > N - 1) gn = N - 1;
                ushort v[8];
#pragma unroll
                for (int e = 0; e < 8; ++e) {
                    int gk = k0 + g * 8 + e;
                    v[e] = (gk < K) ? Bt[(size_t)gn * K + gk] : (ushort)0;
                }
                *reinterpret_cast<uint4*>(&Bs[buf][r * 32 + p * 8]) =
                    *reinterpret_cast<uint4*>(v);
            }
        }
    };

    stage(0, 0);
    asm volatile("s_waitcnt vmcnt(0) lgkmcnt(0)" ::: "memory");
    __builtin_amdgcn_sched_barrier(0);
    __builtin_amdgcn_s_barrier();
    __builtin_amdgcn_sched_barrier(0);

    int cur = 0;
    for (int s = 0; s < ns; ++s) {
        if (s + 1 < ns) stage(cur ^ 1, s + 1);

        bf16x8 af[2], bf[4];
#pragma unroll
        for (int mt = 0; mt < 2; ++mt) {
            int row = wr * 32 + mt * 16 + lr;
            int ch = lk ^ ((row >> 1) & 3);
            af[mt] = *reinterpret_cast<const bf16x8*>(&As[cur][row * 32 + ch * 8]);
        }
#pragma unroll
        for (int nt = 0; nt < 4; ++nt) {
            int row = wc * 64 + nt * 16 + lr;
            int ch = lk ^ ((row >> 1) & 3);
            bf[nt] = *reinterpret_cast<const bf16x8*>(&Bs[cur][row * 32 + ch * 8]);
        }
        __builtin_amdgcn_s_setprio(1);
#pragma unroll
        for (int mt = 0; mt < 2; ++mt)
#pragma unroll
            for (int nt = 0; nt < 4; ++nt)
                acc[mt][nt] = __builtin_amdgcn_mfma_f32_16x16x32_bf16(
                    af[mt], bf[nt], acc[mt][nt], 0, 0, 0);
        __builtin_amdgcn_s_setprio(0);

        if (s + 1 < ns) {
            asm volatile("s_waitcnt vmcnt(0) lgkmcnt(0)" ::: "memory");
            __builtin_amdgcn_sched_barrier(0);
            __builtin_amdgcn_s_barrier();
            __builtin_amdgcn_sched_barrier(0);
        }
        cur ^= 1;
    }

#pragma unroll
    for (int nt = 0; nt < 4; ++nt) {
        int col = n0 + wc * 64 + nt * 16 + lr;
        if (col >= N) continue;
        float bv = bias[col];
        int g = 0, dcol = 0;
        if (OUT_MODE == 2) { g = col / 34; dcol = col - g * 34; }
#pragma unroll
        for (int mt = 0; mt < 2; ++mt) {
#pragma unroll
            for (int r = 0; r < 4; ++r) {
                int row = m0 + wr * 32 + mt * 16 + lk * 4 + r;
                if (row >= M) continue;
                float v = acc[mt][nt][r] + bv;
                if (ACT == 1) v = fmaxf(v, 0.0f);
                if (OUT_MODE == 0)
                    ((float*)Cout)[(size_t)row * N + col] = v;
                else if (OUT_MODE == 1)
                    ((ushort*)Cout)[(size_t)row * N + col] = f2bf(v);
                else
                    ((ushort*)Cout)[(size_t)row * 960 + g * 40 + dcol] = f2bf(v);
            }
        }
    }
}

// ---------------------------------------------------------------------------
// s1[b,g] = (1/64) * sum_n val1[(b*64+n), g]; bf16 in (vectorized), bf16 out.
// 4096 threads: each handles (b, group of 8 g's).
// ---------------------------------------------------------------------------
__global__ __launch_bounds__(256) void reduce_s1_kernel(const ushort* __restrict__ val1,
                                                        ushort* __restrict__ s1) {
    int idx = blockIdx.x * 256 + threadIdx.x;
    if (idx >= B_DIM * 128) return;
    int b = idx >> 7;
    int g0 = (idx & 127) << 3;
    const ushort* base = val1 + (size_t)(b << 6) * F_INF + g0;
    float s[8] = {0.f, 0.f, 0.f, 0.f, 0.f, 0.f, 0.f, 0.f};
    for (int n = 0; n < 64; ++n) {
        bf16x8 v = *reinterpret_cast<const bf16x8*>(base + (size_t)n * F_INF);
#pragma unroll
        for (int e = 0; e < 8; ++e) s[e] += bf2f((ushort)v[e]);
    }
    ushort o[8];
#pragma unroll
    for (int e = 0; e < 8; ++e) o[e] = f2bf(s[e] * (1.0f / 64.0f));
    *reinterpret_cast<uint4*>(&s1[(size_t)idx * 8]) = *reinterpret_cast<uint4*>(o);
}

// ---------------------------------------------------------------------------
// seq[t,b,c] = (c<256) ? out2[b, t*4 + c%4] : PE(t,b,c-256)   -> bf16
// PE computed inline: 256^(s/7) = 2^(8s/7).
// ---------------------------------------------------------------------------
__global__ void seq_kernel(const float* __restrict__ out2, const float* __restrict__ times,
                           ushort* __restrict__ seq) {
    int idx = blockIdx.x * blockDim.x + threadIdx.x;
    if (idx >= T_DIM * B_DIM * D_T) return;
    int c = idx % D_T;
    int tb = idx / D_T;
    float v;
    if (c < 256) {
        v = out2[(tb % B_DIM) * 1024 + ((tb / B_DIM) << 2) + (c & 3)];
    } else {
        int s = c - 256;
        int sc = (s < 8) ? s : s - 8;
        float arg = times[tb] * exp2f(-8.0f * (float)sc * (1.0f / 7.0f));
        v = (s < 8) ? sinf(arg) : cosf(arg);
    }
    seq[idx] = f2bf(v);
}

// ---------------------------------------------------------------------------
// zero the pad slots (d=34..39 per 40-wide group) of qkvb; stays zero since
// the QKV GEMM never writes them. 3 dwords per (row, group).
// ---------------------------------------------------------------------------
__global__ void pad_zero_kernel(uint* __restrict__ qkvb) {
    int idx = blockIdx.x * blockDim.x + threadIdx.x;
    if (idx >= T_DIM * B_DIM * 24 * 3) return;
    int row = idx / 72;
    int r = idx - row * 72;
    int g = r / 3, q = r - g * 3;
    qkvb[(size_t)row * 480 + g * 20 + 17 + q] = 0;
}

// ---------------------------------------------------------------------------
// MFMA flash attention. Block = (b,h), 4 waves x 64 queries, KV chunks of 64.
// Double-buffered K/V LDS, one barrier per chunk; V loads vectorized bf16x8
// (pads zero in qkvb) then LDS-transposed; loads issued before compute,
// LDS writes after (T14). setprio around MFMA clusters.
// ---------------------------------------------------------------------------
__global__ __launch_bounds__(256) void attn_mfma(const ushort* __restrict__ qkv,
                                                 const int* __restrict__ lengths,
                                                 ushort* __restrict__ attno) {
    const int b = blockIdx.x >> 3;
    const int h = blockIdx.x & 7;
    const int tid = threadIdx.x;
    const int w = tid >> 6, lane = tid & 63;
    const int lr = lane & 15, lk = lane >> 4;
    __shared__ ushort Ks[2][64 * 40];
    __shared__ ushort Vt[2][48 * 72];
    __shared__ ushort Ps[4][64 * 72];
    const int len = lengths[b];
    const float scale = 0.1714985851f;  // 1/sqrt(34)
    const bf16x8 zv = {0, 0, 0, 0, 0, 0, 0, 0};

    // zero Vt rows 40..47 (never re-staged)
    for (int i = tid; i < 2 * 8 * 72; i += 256) {
        int bb = i / 576;
        Vt[bb][40 * 72 + (i - bb * 576)] = 0;
    }

    // staging slot assignment: slot = tid (+256 for tid<64); row = slot/5, ch = slot%5
    const int srow0 = tid / 5, sch0 = tid - srow0 * 5;
    const int srow1 = (tid + 256) / 5, sch1 = (tid + 256) - srow1 * 5;
    const int sjp0 = (srow0 & 15) * 4 + (srow0 >> 4);
    const int sjp1 = (srow1 & 15) * 4 + (srow1 >> 4);
    const bool has1 = (tid < 64);
    bf16x8 kreg0, kreg1, vreg0, vreg1;

    auto LOADS = [&](int c) {
        const ushort* b0 = &qkv[(size_t)((c * 64 + srow0) * 32 + b) * 960 + h * 40];
        kreg0 = *reinterpret_cast<const bf16x8*>(b0 + 320 + sch0 * 8);
        vreg0 = *reinterpret_cast<const bf16x8*>(b0 + 640 + sch0 * 8);
        if (has1) {
            const ushort* b1 = &qkv[(size_t)((c * 64 + srow1) * 32 + b) * 960 + h * 40];
            kreg1 = *reinterpret_cast<const bf16x8*>(b1 + 320 + sch1 * 8);
            vreg1 = *reinterpret_cast<const bf16x8*>(b1 + 640 + sch1 * 8);
        }
    };
    auto WRITES = [&](int buf) {
        *reinterpret_cast<bf16x8*>(&Ks[buf][srow0 * 40 + sch0 * 8]) = kreg0;
#pragma unroll
        for (int e = 0; e < 8; ++e) Vt[buf][(sch0 * 8 + e) * 72 + sjp0] = (ushort)vreg0[e];
        if (has1) {
            *reinterpret_cast<bf16x8*>(&Ks[buf][srow1 * 40 + sch1 * 8]) = kreg1;
#pragma unroll
            for (int e = 0; e < 8; ++e) Vt[buf][(sch1 * 8 + e) * 72 + sjp1] = (ushort)vreg1[e];
        }
    };

    // Q fragments
    bf16x8 qf0[4], qf1[4];
#pragma unroll
    for (int it = 0; it < 4; ++it) {
        int t = w * 64 + it * 16 + lr;
        const ushort* qrow = &qkv[(size_t)(t * 32 + b) * 960 + h * 40];
        qf0[it] = *reinterpret_cast<const bf16x8*>(qrow + lk * 8);
        qf1[it] = (lk == 0) ? *reinterpret_cast<const bf16x8*>(qrow + 32) : zv;
    }

    f32x4 oacc[4][3];
#pragma unroll
    for (int it = 0; it < 4; ++it)
#pragma unroll
        for (int dt = 0; dt < 3; ++dt) oacc[it][dt] = (f32x4){0.f, 0.f, 0.f, 0.f};
    float m[4][4], l[4][4];
#pragma unroll
    for (int it = 0; it < 4; ++it)
#pragma unroll
        for (int r = 0; r < 4; ++r) { m[it][r] = -1e30f; l[it][r] = 0.f; }

    const int nchunks = (len + 63) >> 6;
    LOADS(0);
    WRITES(0);
    __syncthreads();

    int cur = 0;
    for (int c = 0; c < nchunks; ++c) {
        const bool pre = (c + 1 < nchunks);
        if (pre) LOADS(c + 1);  // global loads in flight during compute

        bf16x8 kf0[4], kf1[4];
#pragma unroll
        for (int jt = 0; jt < 4; ++jt) {
            int j = jt * 16 + lr;
            kf0[jt] = *reinterpret_cast<const bf16x8*>(&Ks[cur][j * 40 + lk * 8]);
            kf1[jt] = (lk == 0) ? *reinterpret_cast<const bf16x8*>(&Ks[cur][j * 40 + 32]) : zv;
        }

        const bool tail = (c * 64 + 64 > len);
#pragma unroll
        for (int it = 0; it < 4; ++it) {
            f32x4 sacc[4];
#pragma unroll
            for (int jt = 0; jt < 4; ++jt) sacc[jt] = (f32x4){0.f, 0.f, 0.f, 0.f};
            __builtin_amdgcn_s_setprio(1);
#pragma unroll
            for (int jt = 0; jt < 4; ++jt) {
                sacc[jt] = __builtin_amdgcn_mfma_f32_16x16x32_bf16(qf0[it], kf0[jt],
                                                                   sacc[jt], 0, 0, 0);
                sacc[jt] = __builtin_amdgcn_mfma_f32_16x16x32_bf16(qf1[it], kf1[jt],
                                                                   sacc[jt], 0, 0, 0);
            }
            __builtin_amdgcn_s_setprio(0);
            float cm[4] = {-1e30f, -1e30f, -1e30f, -1e30f};
#pragma unroll
            for (int jt = 0; jt < 4; ++jt) {
                bool dead = tail && (c * 64 + jt * 16 + lr >= len);
#pragma unroll
                for (int r = 0; r < 4; ++r) {
                    float sv = dead ? -1e30f : sacc[jt][r];
                    sacc[jt][r] = sv;
                    cm[r] = fmaxf(cm[r], sv);
                }
            }
#pragma unroll
            for (int mask = 1; mask <= 8; mask <<= 1)
#pragma unroll
                for (int r = 0; r < 4; ++r) cm[r] = fmaxf(cm[r], __shfl_xor(cm[r], mask));
#pragma unroll
            for (int r = 0; r < 4; ++r) {
                float mn = fmaxf(m[it][r], cm[r]);
                float corr = __expf((m[it][r] - mn) * scale);
                m[it][r] = mn;
                l[it][r] *= corr;
#pragma unroll
                for (int dt = 0; dt < 3; ++dt) oacc[it][dt][r] *= corr;
            }
            float ls[4] = {0.f, 0.f, 0.f, 0.f};
#pragma unroll
            for (int jt = 0; jt < 4; ++jt)
#pragma unroll
                for (int r = 0; r < 4; ++r) {
                    float e = __expf((sacc[jt][r] - m[it][r]) * scale);
                    sacc[jt][r] = e;
                    ls[r] += e;
                }
#pragma unroll
            for (int mask = 1; mask <= 8; mask <<= 1)
#pragma unroll
                for (int r = 0; r < 4; ++r) ls[r] += __shfl_xor(ls[r], mask);
#pragma unroll
            for (int r = 0; r < 4; ++r) l[it][r] += ls[r];
#pragma unroll
            for (int r = 0; r < 4; ++r) {
                int i = it * 16 + lk * 4 + r;
                uint u0 = (uint)f2bf(sacc[0][r]) | ((uint)f2bf(sacc[1][r]) << 16);
                uint u1 = (uint)f2bf(sacc[2][r]) | ((uint)f2bf(sacc[3][r]) << 16);
                uint2 pk = make_uint2(u0, u1);
                *reinterpret_cast<uint2*>(&Ps[w][i * 72 + lr * 4]) = pk;
            }
        }

        bf16x8 vf[3][2], pf[4][2];
#pragma unroll
        for (int dt = 0; dt < 3; ++dt)
#pragma unroll
            for (int ks = 0; ks < 2; ++ks)
                vf[dt][ks] = *reinterpret_cast<const bf16x8*>(
                    &Vt[cur][(dt * 16 + lr) * 72 + ks * 32 + lk * 8]);
#pragma unroll
        for (int it = 0; it < 4; ++it)
#pragma unroll
            for (int ks = 0; ks < 2; ++ks)
                pf[it][ks] = *reinterpret_cast<const bf16x8*>(
                    &Ps[w][(it * 16 + lr) * 72 + ks * 32 + lk * 8]);
        __builtin_amdgcn_s_setprio(1);
#pragma unroll
        for (int it = 0; it < 4; ++it)
#pragma unroll
            for (int dt = 0; dt < 3; ++dt)
#pragma unroll
                for (int ks = 0; ks < 2; ++ks)
                    oacc[it][dt] = __builtin_amdgcn_mfma_f32_16x16x32_bf16(
                        pf[it][ks], vf[dt][ks], oacc[it][dt], 0, 0, 0);
        __builtin_amdgcn_s_setprio(0);

        if (pre) WRITES(cur ^ 1);  // late LDS write-back of prefetched K/V
        __syncthreads();
        cur ^= 1;
    }

#pragma unroll
    for (int it = 0; it < 4; ++it)
#pragma unroll
        for (int r = 0; r < 4; ++r) {
            float inv = 1.0f / l[it][r];
            int t = w * 64 + it * 16 + lk * 4 + r;
            ushort* orow = &attno[(size_t)(t * 32 + b) * 272 + h * 34];
#pragma unroll
            for (int dt = 0; dt < 3; ++dt) {
                int d = dt * 16 + lr;
                if (d < 34) orow[d] = f2bf(oacc[it][dt][r] * inv);
            }
        }
}

// ---------------------------------------------------------------------------
// LN: out = LN(bf16 X + f32 Y) * w + b  -> bf16. 4 rows/block, wave per row.
// ---------------------------------------------------------------------------
__global__ __launch_bounds__(256) void ln_kernel(const ushort* __restrict__ X,
                                                 const float* __restrict__ Y,
                                                 const float* __restrict__ w,
                                                 const float* __restrict__ bsh,
                                                 ushort* __restrict__ out) {
    int row = blockIdx.x * 4 + (threadIdx.x >> 6);
    int lane = threadIdx.x & 63;
    const ushort* xr = X + (size_t)row * D_T;
    const float* yr = Y + (size_t)row * D_T;
    float v[5];
    float sum = 0.f, sumsq = 0.f;
#pragma unroll
    for (int k = 0; k < 5; ++k) {
        int c = lane + k * 64;
        float t = 0.f;
        if (c < D_T) t = bf2f(xr[c]) + yr[c];
        v[k] = t;
        sum += t;
        sumsq += t * t;
    }
#pragma unroll
    for (int off = 32; off; off >>= 1) {
        sum += __shfl_down(sum, off);
        sumsq += __shfl_down(sumsq, off);
    }
    sum = __shfl(sum, 0);
    sumsq = __shfl(sumsq, 0);
    float mu = sum * (1.0f / D_T);
    float var = sumsq * (1.0f / D_T) - mu * mu;
    float inv = 1.0f / sqrtf(var + 1e-5f);
    ushort* orow = out + (size_t)row * D_T;
#pragma unroll
    for (int k = 0; k < 5; ++k) {
        int c = lane + k * 64;
        if (c < D_T) orow[c] = f2bf((v[k] - mu) * inv * w[c] + bsh[c]);
    }
}

// ---------------------------------------------------------------------------
// fused pool + head: one block per batch element.
// ---------------------------------------------------------------------------
__global__ __launch_bounds__(256) void poolhead_kernel(const ushort* __restrict__ seq,
                                                       const int* __restrict__ lengths,
                                                       const float* __restrict__ w1,
                                                       const float* __restrict__ b1,
                                                       const float* __restrict__ w2,
                                                       const float* __restrict__ b2,
                                                       float* __restrict__ out) {
    const int b = blockIdx.x;
    const int tid = threadIdx.x;
    const int wv = tid >> 6, lane = tid & 63;
    const int len = lengths[b];
    __shared__ float part[4][D_T];
    __shared__ float agg_s[D_T];
    __shared__ float hid[D_T];

    float s[5] = {0.f, 0.f, 0.f, 0.f, 0.f};
    for (int t = wv; t < len; t += 4) {
        const ushort* row = &seq[(size_t)(t * B_DIM + b) * D_T];
#pragma unroll
        for (int k = 0; k < 5; ++k) {
            int c = lane + k * 64;
            if (c < D_T) s[k] += bf2f(row[c]);
        }
    }
#pragma unroll
    for (int k = 0; k < 5; ++k) {
        int c = lane + k * 64;
        if (c < D_T) part[wv][c] = s[k];
    }
    __syncthreads();
    float inv = 1.0f / (float)(len + 1);
    for (int c = tid; c < D_T; c += 256)
        agg_s[c] = (part[0][c] + part[1][c] + part[2][c] + part[3][c]) * inv;
    __syncthreads();
    for (int j = tid; j < D_T; j += 256) {
        float acc = b1[j];
        for (int k = 0; k < D_T; ++k) acc += agg_s[k] * w1[k * D_T + j];
        hid[j] = fmaxf(acc, 0.f);
    }
    __syncthreads();
    if (tid < 64) {
        float l0 = 0.f, l1 = 0.f;
        for (int k = tid; k < D_T; k += 64) {
            float hv = hid[k];
            l0 += hv * w2[k * 2 + 0];
            l1 += hv * w2[k * 2 + 1];
        }
#pragma unroll
        for (int off = 32; off; off >>= 1) {
            l0 += __shfl_down(l0, off);
            l1 += __shfl_down(l1, off);
        }
        if (tid == 0) {
            l0 += b2[0];
            l1 += b2[1];
            float mx = fmaxf(l0, l1);
            float e0 = expf(l0 - mx), e1 = expf(l1 - mx);
            float nrm = 1.0f / (e0 + e1);
            out[b * 2 + 0] = e0 * nrm;
            out[b * 2 + 1] = e1 * nrm;
        }
    }
}

// ---------------------------------------------------------------------------
extern "C" void kernel_launch(void* const* d_in, const int* in_sizes, int n_in,
                              void* d_out, int out_size, void* d_ws, size_t ws_size,
                              hipStream_t stream) {
    const float* x      = (const float*)d_in[0];
    const float* times  = (const float*)d_in[1];
    const int*   lens   = (const int*)d_in[2];
    const float* R_u    = (const float*)d_in[3];
    const float* Wv1    = (const float*)d_in[4];
    const float* bv1    = (const float*)d_in[5];
    const float* Wv2    = (const float*)d_in[6];
    const float* bv2    = (const float*)d_in[7];
    const float* qkv_w  = (const float*)d_in[8];
    const float* qkv_b  = (const float*)d_in[9];
    const float* out_w  = (const float*)d_in[10];
    const float* out_b  = (const float*)d_in[11];
    const float* ln1_w  = (const float*)d_in[12];
    const float* ln1_b  = (const float*)d_in[13];
    const float* ln2_w  = (const float*)d_in[14];
    const float* ln2_b  = (const float*)d_in[15];
    const float* ffn_w1 = (const float*)d_in[16];
    const float* ffn_b1 = (const float*)d_in[17];
    const float* ffn_w2 = (const float*)d_in[18];
    const float* ffn_b2 = (const float*)d_in[19];
    const float* mlp_w1 = (const float*)d_in[20];
    const float* mlp_b1 = (const float*)d_in[21];
    const float* mlp_w2 = (const float*)d_in[22];
    const float* mlp_b2 = (const float*)d_in[23];
    float* outp = (float*)d_out;

    char* base = (char*)d_ws;
    size_t used = 0;
    auto alloc = [&](size_t bytes) -> char* {
        char* p = base + used;
        used += (bytes + 255) & ~(size_t)255;
        return p;
    };
    const int TB = T_DIM * B_DIM;  // 8192

    ushort* xn    = (ushort*)alloc((size_t)2048 * 1024 * 2);
    ushort* val1  = (ushort*)alloc((size_t)2048 * 1024 * 2);   // bf16 now
    ushort* s1    = (ushort*)alloc((size_t)32 * 1024 * 2);
    float*  out2  = (float*) alloc((size_t)32 * 1024 * 4);
    ushort* seq   = (ushort*)alloc((size_t)TB * D_T * 2);
    ushort* qkvb  = (ushort*)alloc((size_t)TB * 960 * 2);      // head-padded bf16
    ushort* attno = (ushort*)alloc((size_t)TB * D_T * 2);
    float*  tmp   = (float*) alloc((size_t)TB * D_T * 4);
    ushort* x1    = (ushort*)alloc((size_t)TB * D_T * 2);
    ushort* h1    = (ushort*)alloc((size_t)TB * DFF_DIM * 2);
    ushort* wv1t  = (ushort*)alloc((size_t)1024 * 1024 * 2);
    ushort* wv2t  = (ushort*)alloc((size_t)1024 * 1024 * 2);
    ushort* qkvwt[2]; ushort* outwt[2]; ushort* f1wt[2]; ushort* f2wt[2];
    for (int l = 0; l < 2; ++l) {
        qkvwt[l] = (ushort*)alloc((size_t)272 * 816 * 2);
        outwt[l] = (ushort*)alloc((size_t)272 * 272 * 2);
        f1wt[l]  = (ushort*)alloc((size_t)272 * 1024 * 2);
        f2wt[l]  = (ushort*)alloc((size_t)1024 * 272 * 2);
    }
    if (used > ws_size) return;

    // ---- tiled weight convert+transpose (1 dispatch, coalesced) ----
    {
        WT segs;
        const float* srcs[10] = {Wv1, Wv2,
                                 qkv_w, out_w, ffn_w1, ffn_w2,
                                 qkv_w + (size_t)272 * 816, out_w + (size_t)272 * 272,
                                 ffn_w1 + (size_t)272 * 1024, ffn_w2 + (size_t)1024 * 272};
        ushort* dsts[10] = {wv1t, wv2t, qkvwt[0], outwt[0], f1wt[0], f2wt[0],
                            qkvwt[1], outwt[1], f1wt[1], f2wt[1]};
        int Ksz[10] = {1024, 1024, 272, 272, 272, 1024, 272, 272, 272, 1024};
        int Nsz[10] = {1024, 1024, 816, 272, 1024, 272, 816, 272, 1024, 272};
        int acc = 0;
        for (int i = 0; i < 10; ++i) {
            segs.tstart[i] = acc;
            segs.src[i] = srcs[i];
            segs.dst[i] = dsts[i];
            segs.K[i] = Ksz[i];
            segs.N[i] = Nsz[i];
            segs.ntn[i] = Nsz[i] / 16;
            acc += (Ksz[i] / 16) * (Nsz[i] / 16);
        }
        segs.tstart[10] = acc;
        wconv_tiled<<<acc, 256, 0, stream>>>(segs);
    }

    {
        int n = B_DIM * N_DIM * F_INF;
        xn_kernel<<<(n + 255) / 256, 256, 0, stream>>>(x, R_u, xn);
    }

    // prop1: [2048,1024] @ [1024,1024] -> bf16
    gemm_mfma<1, 1><<<dim3(8, 32), 256, 0, stream>>>(xn, wv1t, bv1, val1, 2048, 1024, 1024);
    reduce_s1_kernel<<<16, 256, 0, stream>>>(val1, s1);
    // prop2 (collapsed): [32,1024] @ [1024,1024] -> f32
    gemm_mfma<1, 0><<<dim3(8, 1), 256, 0, stream>>>(s1, wv2t, bv2, out2, 32, 1024, 1024);

    {
        int n = TB * D_T;
        seq_kernel<<<(n + 255) / 256, 256, 0, stream>>>(out2, times, seq);
    }

    // zero QKV pad slots (replaces full-buffer memset)
    {
        int n = TB * 24 * 3;
        pad_zero_kernel<<<(n + 255) / 256, 256, 0, stream>>>((uint*)qkvb);
    }

    for (int l = 0; l < 2; ++l) {
        const float* qb  = qkv_b + (size_t)l * 816;
        const float* ob  = out_b + (size_t)l * D_T;
        const float* l1w = ln1_w + (size_t)l * D_T;
        const float* l1b = ln1_b + (size_t)l * D_T;
        const float* l2w = ln2_w + (size_t)l * D_T;
        const float* l2b = ln2_b + (size_t)l * D_T;
        const float* f1b = ffn_b1 + (size_t)l * DFF_DIM;
        const float* f2b = ffn_b2 + (size_t)l * D_T;

        gemm_mfma<0, 2><<<dim3(7, 128), 256, 0, stream>>>(seq, qkvwt[l], qb, qkvb,
                                                          TB, 816, D_T);
        attn_mfma<<<B_DIM * H_DIM, 256, 0, stream>>>(qkvb, lens, attno);
        gemm_mfma<0, 0><<<dim3(3, 128), 256, 0, stream>>>(attno, outwt[l], ob, tmp,
                                                          TB, D_T, D_T);
        ln_kernel<<<TB / 4, 256, 0, stream>>>(seq, tmp, l1w, l1b, x1);
        gemm_mfma<1, 1><<<dim3(8, 128), 256, 0, stream>>>(x1, f1wt[l], f1b, h1,
                                                          TB, DFF_DIM, D_T);
        gemm_mfma<0, 0><<<dim3(3, 128), 256, 0, stream>>>(h1, f2wt[l], f2b, tmp,
                                                          TB, D_T, DFF_DIM);
        ln_kernel<<<TB / 4, 256, 0, stream>>>(x1, tmp, l2w, l2b, seq);
    }

    poolhead_kernel<<<B_DIM, 256, 0, stream>>>(seq, lens, mlp_w1, mlp_b1,
                                               mlp_w2, mlp_b2, outp);
}

// Round 7
// 336.339 us; speedup vs baseline: 3.2745x; 1.0568x over previous
//
#include <hip/hip_runtime.h>
#include <math.h>

#define T_DIM 256
#define B_DIM 32
#define N_DIM 64
#define F_INF 1024
#define D_T 272
#define H_DIM 8
#define DH_DIM 34
#define DFF_DIM 1024

typedef unsigned int uint;
typedef short bf16x8 __attribute__((ext_vector_type(8)));
typedef float f32x4 __attribute__((ext_vector_type(4)));

__device__ __forceinline__ ushort f2bf(float f) {
    uint u = __float_as_uint(f);
    uint r = (u + 0x7fffu + ((u >> 16) & 1u)) >> 16;
    return (ushort)r;
}
__device__ __forceinline__ float bf2f(ushort u) {
    return __uint_as_float(((uint)u) << 16);
}

// ---------------------------------------------------------------------------
// xn[b,n,t*4+d] = relu(x[t,b,n] * R_u[n*4+d])  -> bf16
// ---------------------------------------------------------------------------
__global__ void xn_kernel(const float* __restrict__ x, const float* __restrict__ Ru,
                          ushort* __restrict__ xn) {
    int idx = blockIdx.x * blockDim.x + threadIdx.x;
    if (idx >= B_DIM * N_DIM * F_INF) return;
    int f = idx & 1023;
    int bn = idx >> 10;
    int n = bn & 63;
    int b = bn >> 6;
    int t = f >> 2;
    int d = f & 3;
    float v = x[(t * B_DIM + b) * N_DIM + n] * Ru[(n << 2) + d];
    xn[idx] = f2bf(fmaxf(v, 0.0f));
}

// ---------------------------------------------------------------------------
// tiled weight convert+transpose: f32 [K,N] -> bf16 [N,K], 16x16 LDS tiles.
// ---------------------------------------------------------------------------
struct WT {
    int tstart[11];
    const float* src[10];
    ushort* dst[10];
    int K[10];
    int N[10];
    int ntn[10];  // N/16
};
__global__ __launch_bounds__(256) void wconv_tiled(WT s) {
    int tile = blockIdx.x;
    int seg = 0;
    while (seg < 9 && tile >= s.tstart[seg + 1]) ++seg;
    int ti = tile - s.tstart[seg];
    int ntn = s.ntn[seg];
    int tk = ti / ntn, tn = ti - tk * ntn;
    int K = s.K[seg], N = s.N[seg];
    __shared__ float t[16][17];
    int ty = threadIdx.x >> 4, tx = threadIdx.x & 15;
    t[ty][tx] = s.src[seg][(size_t)(tk * 16 + ty) * N + tn * 16 + tx];
    __syncthreads();
    s.dst[seg][(size_t)(tn * 16 + ty) * K + tk * 16 + tx] = f2bf(t[tx][ty]);
}

// ---------------------------------------------------------------------------
// MFMA bf16 GEMM, T3 2-phase pipeline (validated round 5).
// BM=64, BN=128, BK=32; 256 thr = 4 waves (2x2), wave tile 32x64.
// OUT_MODE: 0 = f32 flat, 1 = bf16 flat, 2 = bf16 head-padded QKV layout.
// ---------------------------------------------------------------------------
template <int ACT, int OUT_MODE>
__global__ __launch_bounds__(256) void gemm_mfma(const ushort* __restrict__ A,
                                                 const ushort* __restrict__ Bt,
                                                 const float* __restrict__ bias,
                                                 void* __restrict__ Cout,
                                                 int M, int N, int K) {
    __shared__ ushort As[2][64 * 32];
    __shared__ ushort Bs[2][128 * 32];
    const int tid = threadIdx.x;
    const int m0 = blockIdx.y * 64;
    const int n0 = blockIdx.x * 128;
    const int w = tid >> 6, lane = tid & 63;
    const int wr = w >> 1, wc = w & 1;
    const int lr = lane & 15, lk = lane >> 4;

    const int nfull = K >> 5;
    const int ns = (K + 31) >> 5;

    const int ra = w * 16 + (lane >> 2);
    const int ca = (((lane & 3) ^ ((ra >> 1) & 3)) << 3);
    int gma = m0 + ra; if (gma > M - 1) gma = M - 1;
    const ushort* gA = &A[(size_t)gma * K + ca];
    const int rb0 = w * 32 + (lane >> 2);
    const int cb0 = (((lane & 3) ^ ((rb0 >> 1) & 3)) << 3);
    const int rb1 = rb0 + 16;
    const int cb1 = (((lane & 3) ^ ((rb1 >> 1) & 3)) << 3);
    int gnb0 = n0 + rb0; if (gnb0 > N - 1) gnb0 = N - 1;
    int gnb1 = n0 + rb1; if (gnb1 > N - 1) gnb1 = N - 1;
    const ushort* gB0 = &Bt[(size_t)gnb0 * K + cb0];
    const ushort* gB1 = &Bt[(size_t)gnb1 * K + cb1];

    f32x4 acc[2][4];
#pragma unroll
    for (int i = 0; i < 2; ++i)
#pragma unroll
        for (int j = 0; j < 4; ++j) acc[i][j] = (f32x4){0.f, 0.f, 0.f, 0.f};

    auto stage = [&](int buf, int s) {
        const int k0 = s << 5;
        if (s < nfull) {
            __builtin_amdgcn_global_load_lds(
                (const __attribute__((address_space(1))) void*)(gA + k0),
                (__attribute__((address_space(3))) void*)(&As[buf][w * 512]), 16, 0, 0);
            __builtin_amdgcn_global_load_lds(
                (const __attribute__((address_space(1))) void*)(gB0 + k0),
                (__attribute__((address_space(3))) void*)(&Bs[buf][w * 1024]), 16, 0, 0);
            __builtin_amdgcn_global_load_lds(
                (const __attribute__((address_space(1))) void*)(gB1 + k0),
                (__attribute__((address_space(3))) void*)(&Bs[buf][w * 1024 + 512]), 16, 0, 0);
        } else {
            {
                int r = tid >> 2, p = tid & 3;
                int g = p ^ ((r >> 1) & 3);
                int gm = m0 + r; if (gm > M - 1) gm = M - 1;
                ushort v[8];
#pragma unroll
                for (int e = 0; e < 8; ++e) {
                    int gk = k0 + g * 8 + e;
                    v[e] = (gk < K) ? A[(size_t)gm * K + gk] : (ushort)0;
                }
                *reinterpret_cast<uint4*>(&As[buf][r * 32 + p * 8]) =
                    *reinterpret_cast<uint4*>(v);
            }
#pragma unroll
            for (int rr = 0; rr < 2; ++rr) {
                int r = rr * 64 + (tid >> 2), p = tid & 3;
                int g = p ^ ((r >> 1) & 3);
                int gn = n0 + r; if (gn > N - 1) gn = N - 1;
                ushort v[8];
#pragma unroll
                for (int e = 0; e < 8; ++e) {
                    int gk = k0 + g * 8 + e;
                    v[e] = (gk < K) ? Bt[(size_t)gn * K + gk] : (ushort)0;
                }
                *reinterpret_cast<uint4*>(&Bs[buf][r * 32 + p * 8]) =
                    *reinterpret_cast<uint4*>(v);
            }
        }
    };

    stage(0, 0);
    asm volatile("s_waitcnt vmcnt(0) lgkmcnt(0)" ::: "memory");
    __builtin_amdgcn_sched_barrier(0);
    __builtin_amdgcn_s_barrier();
    __builtin_amdgcn_sched_barrier(0);

    int cur = 0;
    for (int s = 0; s < ns; ++s) {
        if (s + 1 < ns) stage(cur ^ 1, s + 1);

        bf16x8 af[2], bf[4];
#pragma unroll
        for (int mt = 0; mt < 2; ++mt) {
            int row = wr * 32 + mt * 16 + lr;
            int ch = lk ^ ((row >> 1) & 3);
            af[mt] = *reinterpret_cast<const bf16x8*>(&As[cur][row * 32 + ch * 8]);
        }
#pragma unroll
        for (int nt = 0; nt < 4; ++nt) {
            int row = wc * 64 + nt * 16 + lr;
            int ch = lk ^ ((row >> 1) & 3);
            bf[nt] = *reinterpret_cast<const bf16x8*>(&Bs[cur][row * 32 + ch * 8]);
        }
        __builtin_amdgcn_s_setprio(1);
#pragma unroll
        for (int mt = 0; mt < 2; ++mt)
#pragma unroll
            for (int nt = 0; nt < 4; ++nt)
                acc[mt][nt] = __builtin_amdgcn_mfma_f32_16x16x32_bf16(
                    af[mt], bf[nt], acc[mt][nt], 0, 0, 0);
        __builtin_amdgcn_s_setprio(0);

        if (s + 1 < ns) {
            asm volatile("s_waitcnt vmcnt(0) lgkmcnt(0)" ::: "memory");
            __builtin_amdgcn_sched_barrier(0);
            __builtin_amdgcn_s_barrier();
            __builtin_amdgcn_sched_barrier(0);
        }
        cur ^= 1;
    }

#pragma unroll
    for (int nt = 0; nt < 4; ++nt) {
        int col = n0 + wc * 64 + nt * 16 + lr;
        if (col >= N) continue;
        float bv = bias[col];
        int g = 0, dcol = 0;
        if (OUT_MODE == 2) { g = col / 34; dcol = col - g * 34; }
#pragma unroll
        for (int mt = 0; mt < 2; ++mt) {
#pragma unroll
            for (int r = 0; r < 4; ++r) {
                int row = m0 + wr * 32 + mt * 16 + lk * 4 + r;
                if (row >= M) continue;
                float v = acc[mt][nt][r] + bv;
                if (ACT == 1) v = fmaxf(v, 0.0f);
                if (OUT_MODE == 0)
                    ((float*)Cout)[(size_t)row * N + col] = v;
                else if (OUT_MODE == 1)
                    ((ushort*)Cout)[(size_t)row * N + col] = f2bf(v);
                else
                    ((ushort*)Cout)[(size_t)row * 960 + g * 40 + dcol] = f2bf(v);
            }
        }
    }
}

// ---------------------------------------------------------------------------
// s1[b,g] = (1/64) * sum_n val1[(b*64+n), g]; bf16 in (vectorized), bf16 out.
// ---------------------------------------------------------------------------
__global__ __launch_bounds__(256) void reduce_s1_kernel(const ushort* __restrict__ val1,
                                                        ushort* __restrict__ s1) {
    int idx = blockIdx.x * 256 + threadIdx.x;
    if (idx >= B_DIM * 128) return;
    int b = idx >> 7;
    int g0 = (idx & 127) << 3;
    const ushort* base = val1 + (size_t)(b << 6) * F_INF + g0;
    float s[8] = {0.f, 0.f, 0.f, 0.f, 0.f, 0.f, 0.f, 0.f};
    for (int n = 0; n < 64; ++n) {
        bf16x8 v = *reinterpret_cast<const bf16x8*>(base + (size_t)n * F_INF);
#pragma unroll
        for (int e = 0; e < 8; ++e) s[e] += bf2f((ushort)v[e]);
    }
    ushort o[8];
#pragma unroll
    for (int e = 0; e < 8; ++e) o[e] = f2bf(s[e] * (1.0f / 64.0f));
    *reinterpret_cast<uint4*>(&s1[(size_t)idx * 8]) = *reinterpret_cast<uint4*>(o);
}

// ---------------------------------------------------------------------------
// seq[t,b,c] = (c<256) ? out2[b, t*4 + c%4] : PE(t,b,c-256)   -> bf16
// ---------------------------------------------------------------------------
__global__ void seq_kernel(const float* __restrict__ out2, const float* __restrict__ times,
                           ushort* __restrict__ seq) {
    int idx = blockIdx.x * blockDim.x + threadIdx.x;
    if (idx >= T_DIM * B_DIM * D_T) return;
    int c = idx % D_T;
    int tb = idx / D_T;
    float v;
    if (c < 256) {
        v = out2[(tb % B_DIM) * 1024 + ((tb / B_DIM) << 2) + (c & 3)];
    } else {
        int s = c - 256;
        int sc = (s < 8) ? s : s - 8;
        float arg = times[tb] * exp2f(-8.0f * (float)sc * (1.0f / 7.0f));
        v = (s < 8) ? sinf(arg) : cosf(arg);
    }
    seq[idx] = f2bf(v);
}

// ---------------------------------------------------------------------------
// zero the pad slots (d=34..39 per 40-wide group) of qkvb.
// ---------------------------------------------------------------------------
__global__ void pad_zero_kernel(uint* __restrict__ qkvb) {
    int idx = blockIdx.x * blockDim.x + threadIdx.x;
    if (idx >= T_DIM * B_DIM * 24 * 3) return;
    int row = idx / 72;
    int r = idx - row * 72;
    int g = r / 3, q = r - g * 3;
    qkvb[(size_t)row * 480 + g * 20 + 17 + q] = 0;
}

// ---------------------------------------------------------------------------
// MFMA flash attention (validated round 6).
// ---------------------------------------------------------------------------
__global__ __launch_bounds__(256) void attn_mfma(const ushort* __restrict__ qkv,
                                                 const int* __restrict__ lengths,
                                                 ushort* __restrict__ attno) {
    const int b = blockIdx.x >> 3;
    const int h = blockIdx.x & 7;
    const int tid = threadIdx.x;
    const int w = tid >> 6, lane = tid & 63;
    const int lr = lane & 15, lk = lane >> 4;
    __shared__ ushort Ks[2][64 * 40];
    __shared__ ushort Vt[2][48 * 72];
    __shared__ ushort Ps[4][64 * 72];
    const int len = lengths[b];
    const float scale = 0.1714985851f;  // 1/sqrt(34)
    const bf16x8 zv = {0, 0, 0, 0, 0, 0, 0, 0};

    for (int i = tid; i < 2 * 8 * 72; i += 256) {
        int bb = i / 576;
        Vt[bb][40 * 72 + (i - bb * 576)] = 0;
    }

    const int srow0 = tid / 5, sch0 = tid - srow0 * 5;
    const int srow1 = (tid + 256) / 5, sch1 = (tid + 256) - srow1 * 5;
    const int sjp0 = (srow0 & 15) * 4 + (srow0 >> 4);
    const int sjp1 = (srow1 & 15) * 4 + (srow1 >> 4);
    const bool has1 = (tid < 64);
    bf16x8 kreg0, kreg1, vreg0, vreg1;

    auto LOADS = [&](int c) {
        const ushort* b0 = &qkv[(size_t)((c * 64 + srow0) * 32 + b) * 960 + h * 40];
        kreg0 = *reinterpret_cast<const bf16x8*>(b0 + 320 + sch0 * 8);
        vreg0 = *reinterpret_cast<const bf16x8*>(b0 + 640 + sch0 * 8);
        if (has1) {
            const ushort* b1 = &qkv[(size_t)((c * 64 + srow1) * 32 + b) * 960 + h * 40];
            kreg1 = *reinterpret_cast<const bf16x8*>(b1 + 320 + sch1 * 8);
            vreg1 = *reinterpret_cast<const bf16x8*>(b1 + 640 + sch1 * 8);
        }
    };
    auto WRITES = [&](int buf) {
        *reinterpret_cast<bf16x8*>(&Ks[buf][srow0 * 40 + sch0 * 8]) = kreg0;
#pragma unroll
        for (int e = 0; e < 8; ++e) Vt[buf][(sch0 * 8 + e) * 72 + sjp0] = (ushort)vreg0[e];
        if (has1) {
            *reinterpret_cast<bf16x8*>(&Ks[buf][srow1 * 40 + sch1 * 8]) = kreg1;
#pragma unroll
            for (int e = 0; e < 8; ++e) Vt[buf][(sch1 * 8 + e) * 72 + sjp1] = (ushort)vreg1[e];
        }
    };

    bf16x8 qf0[4], qf1[4];
#pragma unroll
    for (int it = 0; it < 4; ++it) {
        int t = w * 64 + it * 16 + lr;
        const ushort* qrow = &qkv[(size_t)(t * 32 + b) * 960 + h * 40];
        qf0[it] = *reinterpret_cast<const bf16x8*>(qrow + lk * 8);
        qf1[it] = (lk == 0) ? *reinterpret_cast<const bf16x8*>(qrow + 32) : zv;
    }

    f32x4 oacc[4][3];
#pragma unroll
    for (int it = 0; it < 4; ++it)
#pragma unroll
        for (int dt = 0; dt < 3; ++dt) oacc[it][dt] = (f32x4){0.f, 0.f, 0.f, 0.f};
    float m[4][4], l[4][4];
#pragma unroll
    for (int it = 0; it < 4; ++it)
#pragma unroll
        for (int r = 0; r < 4; ++r) { m[it][r] = -1e30f; l[it][r] = 0.f; }

    const int nchunks = (len + 63) >> 6;
    LOADS(0);
    WRITES(0);
    __syncthreads();

    int cur = 0;
    for (int c = 0; c < nchunks; ++c) {
        const bool pre = (c + 1 < nchunks);
        if (pre) LOADS(c + 1);

        bf16x8 kf0[4], kf1[4];
#pragma unroll
        for (int jt = 0; jt < 4; ++jt) {
            int j = jt * 16 + lr;
            kf0[jt] = *reinterpret_cast<const bf16x8*>(&Ks[cur][j * 40 + lk * 8]);
            kf1[jt] = (lk == 0) ? *reinterpret_cast<const bf16x8*>(&Ks[cur][j * 40 + 32]) : zv;
        }

        const bool tail = (c * 64 + 64 > len);
#pragma unroll
        for (int it = 0; it < 4; ++it) {
            f32x4 sacc[4];
#pragma unroll
            for (int jt = 0; jt < 4; ++jt) sacc[jt] = (f32x4){0.f, 0.f, 0.f, 0.f};
            __builtin_amdgcn_s_setprio(1);
#pragma unroll
            for (int jt = 0; jt < 4; ++jt) {
                sacc[jt] = __builtin_amdgcn_mfma_f32_16x16x32_bf16(qf0[it], kf0[jt],
                                                                   sacc[jt], 0, 0, 0);
                sacc[jt] = __builtin_amdgcn_mfma_f32_16x16x32_bf16(qf1[it], kf1[jt],
                                                                   sacc[jt], 0, 0, 0);
            }
            __builtin_amdgcn_s_setprio(0);
            float cm[4] = {-1e30f, -1e30f, -1e30f, -1e30f};
#pragma unroll
            for (int jt = 0; jt < 4; ++jt) {
                bool dead = tail && (c * 64 + jt * 16 + lr >= len);
#pragma unroll
                for (int r = 0; r < 4; ++r) {
                    float sv = dead ? -1e30f : sacc[jt][r];
                    sacc[jt][r] = sv;
                    cm[r] = fmaxf(cm[r], sv);
                }
            }
#pragma unroll
            for (int mask = 1; mask <= 8; mask <<= 1)
#pragma unroll
                for (int r = 0; r < 4; ++r) cm[r] = fmaxf(cm[r], __shfl_xor(cm[r], mask));
#pragma unroll
            for (int r = 0; r < 4; ++r) {
                float mn = fmaxf(m[it][r], cm[r]);
                float corr = __expf((m[it][r] - mn) * scale);
                m[it][r] = mn;
                l[it][r] *= corr;
#pragma unroll
                for (int dt = 0; dt < 3; ++dt) oacc[it][dt][r] *= corr;
            }
            float ls[4] = {0.f, 0.f, 0.f, 0.f};
#pragma unroll
            for (int jt = 0; jt < 4; ++jt)
#pragma unroll
                for (int r = 0; r < 4; ++r) {
                    float e = __expf((sacc[jt][r] - m[it][r]) * scale);
                    sacc[jt][r] = e;
                    ls[r] += e;
                }
#pragma unroll
            for (int mask = 1; mask <= 8; mask <<= 1)
#pragma unroll
                for (int r = 0; r < 4; ++r) ls[r] += __shfl_xor(ls[r], mask);
#pragma unroll
            for (int r = 0; r < 4; ++r) l[it][r] += ls[r];
#pragma unroll
            for (int r = 0; r < 4; ++r) {
                int i = it * 16 + lk * 4 + r;
                uint u0 = (uint)f2bf(sacc[0][r]) | ((uint)f2bf(sacc[1][r]) << 16);
                uint u1 = (uint)f2bf(sacc[2][r]) | ((uint)f2bf(sacc[3][r]) << 16);
                uint2 pk = make_uint2(u0, u1);
                *reinterpret_cast<uint2*>(&Ps[w][i * 72 + lr * 4]) = pk;
            }
        }

        bf16x8 vf[3][2], pf[4][2];
#pragma unroll
        for (int dt = 0; dt < 3; ++dt)
#pragma unroll
            for (int ks = 0; ks < 2; ++ks)
                vf[dt][ks] = *reinterpret_cast<const bf16x8*>(
                    &Vt[cur][(dt * 16 + lr) * 72 + ks * 32 + lk * 8]);
#pragma unroll
        for (int it = 0; it < 4; ++it)
#pragma unroll
            for (int ks = 0; ks < 2; ++ks)
                pf[it][ks] = *reinterpret_cast<const bf16x8*>(
                    &Ps[w][(it * 16 + lr) * 72 + ks * 32 + lk * 8]);
        __builtin_amdgcn_s_setprio(1);
#pragma unroll
        for (int it = 0; it < 4; ++it)
#pragma unroll
            for (int dt = 0; dt < 3; ++dt)
#pragma unroll
                for (int ks = 0; ks < 2; ++ks)
                    oacc[it][dt] = __builtin_amdgcn_mfma_f32_16x16x32_bf16(
                        pf[it][ks], vf[dt][ks], oacc[it][dt], 0, 0, 0);
        __builtin_amdgcn_s_setprio(0);

        if (pre) WRITES(cur ^ 1);
        __syncthreads();
        cur ^= 1;
    }

#pragma unroll
    for (int it = 0; it < 4; ++it)
#pragma unroll
        for (int r = 0; r < 4; ++r) {
            float inv = 1.0f / l[it][r];
            int t = w * 64 + it * 16 + lk * 4 + r;
            ushort* orow = &attno[(size_t)(t * 32 + b) * 272 + h * 34];
#pragma unroll
            for (int dt = 0; dt < 3; ++dt) {
                int d = dt * 16 + lr;
                if (d < 34) orow[d] = f2bf(oacc[it][dt][r] * inv);
            }
        }
}

// ---------------------------------------------------------------------------
// LN: out = LN(bf16 X + f32 Y) * w + b  -> bf16. 4 rows/block, wave per row.
// ---------------------------------------------------------------------------
__global__ __launch_bounds__(256) void ln_kernel(const ushort* __restrict__ X,
                                                 const float* __restrict__ Y,
                                                 const float* __restrict__ w,
                                                 const float* __restrict__ bsh,
                                                 ushort* __restrict__ out) {
    int row = blockIdx.x * 4 + (threadIdx.x >> 6);
    int lane = threadIdx.x & 63;
    const ushort* xr = X + (size_t)row * D_T;
    const float* yr = Y + (size_t)row * D_T;
    float v[5];
    float sum = 0.f, sumsq = 0.f;
#pragma unroll
    for (int k = 0; k < 5; ++k) {
        int c = lane + k * 64;
        float t = 0.f;
        if (c < D_T) t = bf2f(xr[c]) + yr[c];
        v[k] = t;
        sum += t;
        sumsq += t * t;
    }
#pragma unroll
    for (int off = 32; off; off >>= 1) {
        sum += __shfl_down(sum, off);
        sumsq += __shfl_down(sumsq, off);
    }
    sum = __shfl(sum, 0);
    sumsq = __shfl(sumsq, 0);
    float mu = sum * (1.0f / D_T);
    float var = sumsq * (1.0f / D_T) - mu * mu;
    float inv = 1.0f / sqrtf(var + 1e-5f);
    ushort* orow = out + (size_t)row * D_T;
#pragma unroll
    for (int k = 0; k < 5; ++k) {
        int c = lane + k * 64;
        if (c < D_T) orow[c] = f2bf((v[k] - mu) * inv * w[c] + bsh[c]);
    }
}

// ---------------------------------------------------------------------------
// pool stage 1: partial[chunk][b][272] = sum over 32 t-rows (masked by len).
// grid (8, 32) = (t-chunk, b); 256 thr, tid<136 handles a 2-bf16 pair.
// ---------------------------------------------------------------------------
__global__ __launch_bounds__(256) void pool_partial(const ushort* __restrict__ seq,
                                                    const int* __restrict__ lengths,
                                                    float* __restrict__ partial) {
    const int chunk = blockIdx.x;
    const int b = blockIdx.y;
    const int tid = threadIdx.x;
    if (tid >= 136) return;
    const int len = lengths[b];
    float s0 = 0.f, s1 = 0.f;
    int t0 = chunk * 32;
    int tmax = len - t0;
    if (tmax > 32) tmax = 32;
#pragma unroll 4
    for (int r = 0; r < tmax; ++r) {
        uint u = *reinterpret_cast<const uint*>(
            &seq[(size_t)((t0 + r) * B_DIM + b) * D_T + tid * 2]);
        s0 += __uint_as_float(u << 16);
        s1 += __uint_as_float(u & 0xffff0000u);
    }
    float* p = &partial[(size_t)(chunk * B_DIM + b) * D_T + tid * 2];
    p[0] = s0;
    p[1] = s1;
}

// ---------------------------------------------------------------------------
// head: agg = (sum partials)/(len+1); hid = relu(agg@w1+b1);
// logits = hid@w2+b2; softmax. One block per b.
// ---------------------------------------------------------------------------
__global__ __launch_bounds__(256) void head_kernel(const float* __restrict__ partial,
                                                   const int* __restrict__ lengths,
                                                   const float* __restrict__ w1,
                                                   const float* __restrict__ b1,
                                                   const float* __restrict__ w2,
                                                   const float* __restrict__ b2,
                                                   float* __restrict__ out) {
    const int b = blockIdx.x;
    const int tid = threadIdx.x;
    const int len = lengths[b];
    __shared__ float agg_s[D_T];
    __shared__ float hid[D_T];
    float inv = 1.0f / (float)(len + 1);
    for (int c = tid; c < D_T; c += 256) {
        float s = 0.f;
#pragma unroll
        for (int ch = 0; ch < 8; ++ch)
            s += partial[(size_t)(ch * B_DIM + b) * D_T + c];
        agg_s[c] = s * inv;
    }
    __syncthreads();
    for (int j = tid; j < D_T; j += 256) {
        float acc = b1[j];
        for (int k = 0; k < D_T; ++k) acc += agg_s[k] * w1[k * D_T + j];
        hid[j] = fmaxf(acc, 0.f);
    }
    __syncthreads();
    if (tid < 64) {
        float l0 = 0.f, l1 = 0.f;
        for (int k = tid; k < D_T; k += 64) {
            float hv = hid[k];
            l0 += hv * w2[k * 2 + 0];
            l1 += hv * w2[k * 2 + 1];
        }
#pragma unroll
        for (int off = 32; off; off >>= 1) {
            l0 += __shfl_down(l0, off);
            l1 += __shfl_down(l1, off);
        }
        if (tid == 0) {
            l0 += b2[0];
            l1 += b2[1];
            float mx = fmaxf(l0, l1);
            float e0 = expf(l0 - mx), e1 = expf(l1 - mx);
            float nrm = 1.0f / (e0 + e1);
            out[b * 2 + 0] = e0 * nrm;
            out[b * 2 + 1] = e1 * nrm;
        }
    }
}

// ---------------------------------------------------------------------------
extern "C" void kernel_launch(void* const* d_in, const int* in_sizes, int n_in,
                              void* d_out, int out_size, void* d_ws, size_t ws_size,
                              hipStream_t stream) {
    const float* x      = (const float*)d_in[0];
    const float* times  = (const float*)d_in[1];
    const int*   lens   = (const int*)d_in[2];
    const float* R_u    = (const float*)d_in[3];
    const float* Wv1    = (const float*)d_in[4];
    const float* bv1    = (const float*)d_in[5];
    const float* Wv2    = (const float*)d_in[6];
    const float* bv2    = (const float*)d_in[7];
    const float* qkv_w  = (const float*)d_in[8];
    const float* qkv_b  = (const float*)d_in[9];
    const float* out_w  = (const float*)d_in[10];
    const float* out_b  = (const float*)d_in[11];
    const float* ln1_w  = (const float*)d_in[12];
    const float* ln1_b  = (const float*)d_in[13];
    const float* ln2_w  = (const float*)d_in[14];
    const float* ln2_b  = (const float*)d_in[15];
    const float* ffn_w1 = (const float*)d_in[16];
    const float* ffn_b1 = (const float*)d_in[17];
    const float* ffn_w2 = (const float*)d_in[18];
    const float* ffn_b2 = (const float*)d_in[19];
    const float* mlp_w1 = (const float*)d_in[20];
    const float* mlp_b1 = (const float*)d_in[21];
    const float* mlp_w2 = (const float*)d_in[22];
    const float* mlp_b2 = (const float*)d_in[23];
    float* outp = (float*)d_out;

    char* base = (char*)d_ws;
    size_t used = 0;
    auto alloc = [&](size_t bytes) -> char* {
        char* p = base + used;
        used += (bytes + 255) & ~(size_t)255;
        return p;
    };
    const int TB = T_DIM * B_DIM;  // 8192

    ushort* xn    = (ushort*)alloc((size_t)2048 * 1024 * 2);
    ushort* val1  = (ushort*)alloc((size_t)2048 * 1024 * 2);
    ushort* s1    = (ushort*)alloc((size_t)32 * 1024 * 2);
    float*  out2  = (float*) alloc((size_t)32 * 1024 * 4);
    ushort* seq   = (ushort*)alloc((size_t)TB * D_T * 2);
    ushort* qkvb  = (ushort*)alloc((size_t)TB * 960 * 2);
    ushort* attno = (ushort*)alloc((size_t)TB * D_T * 2);
    float*  tmp   = (float*) alloc((size_t)TB * D_T * 4);
    ushort* x1    = (ushort*)alloc((size_t)TB * D_T * 2);
    ushort* h1    = (ushort*)alloc((size_t)TB * DFF_DIM * 2);
    float*  ppart = (float*) alloc((size_t)8 * B_DIM * D_T * 4);
    ushort* wv1t  = (ushort*)alloc((size_t)1024 * 1024 * 2);
    ushort* wv2t  = (ushort*)alloc((size_t)1024 * 1024 * 2);
    ushort* qkvwt[2]; ushort* outwt[2]; ushort* f1wt[2]; ushort* f2wt[2];
    for (int l = 0; l < 2; ++l) {
        qkvwt[l] = (ushort*)alloc((size_t)272 * 816 * 2);
        outwt[l] = (ushort*)alloc((size_t)272 * 272 * 2);
        f1wt[l]  = (ushort*)alloc((size_t)272 * 1024 * 2);
        f2wt[l]  = (ushort*)alloc((size_t)1024 * 272 * 2);
    }
    if (used > ws_size) return;

    {
        WT segs;
        const float* srcs[10] = {Wv1, Wv2,
                                 qkv_w, out_w, ffn_w1, ffn_w2,
                                 qkv_w + (size_t)272 * 816, out_w + (size_t)272 * 272,
                                 ffn_w1 + (size_t)272 * 1024, ffn_w2 + (size_t)1024 * 272};
        ushort* dsts[10] = {wv1t, wv2t, qkvwt[0], outwt[0], f1wt[0], f2wt[0],
                            qkvwt[1], outwt[1], f1wt[1], f2wt[1]};
        int Ksz[10] = {1024, 1024, 272, 272, 272, 1024, 272, 272, 272, 1024};
        int Nsz[10] = {1024, 1024, 816, 272, 1024, 272, 816, 272, 1024, 272};
        int acc = 0;
        for (int i = 0; i < 10; ++i) {
            segs.tstart[i] = acc;
            segs.src[i] = srcs[i];
            segs.dst[i] = dsts[i];
            segs.K[i] = Ksz[i];
            segs.N[i] = Nsz[i];
            segs.ntn[i] = Nsz[i] / 16;
            acc += (Ksz[i] / 16) * (Nsz[i] / 16);
        }
        segs.tstart[10] = acc;
        wconv_tiled<<<acc, 256, 0, stream>>>(segs);
    }

    {
        int n = B_DIM * N_DIM * F_INF;
        xn_kernel<<<(n + 255) / 256, 256, 0, stream>>>(x, R_u, xn);
    }

    gemm_mfma<1, 1><<<dim3(8, 32), 256, 0, stream>>>(xn, wv1t, bv1, val1, 2048, 1024, 1024);
    reduce_s1_kernel<<<16, 256, 0, stream>>>(val1, s1);
    gemm_mfma<1, 0><<<dim3(8, 1), 256, 0, stream>>>(s1, wv2t, bv2, out2, 32, 1024, 1024);

    {
        int n = TB * D_T;
        seq_kernel<<<(n + 255) / 256, 256, 0, stream>>>(out2, times, seq);
    }

    {
        int n = TB * 24 * 3;
        pad_zero_kernel<<<(n + 255) / 256, 256, 0, stream>>>((uint*)qkvb);
    }

    for (int l = 0; l < 2; ++l) {
        const float* qb  = qkv_b + (size_t)l * 816;
        const float* ob  = out_b + (size_t)l * D_T;
        const float* l1w = ln1_w + (size_t)l * D_T;
        const float* l1b = ln1_b + (size_t)l * D_T;
        const float* l2w = ln2_w + (size_t)l * D_T;
        const float* l2b = ln2_b + (size_t)l * D_T;
        const float* f1b = ffn_b1 + (size_t)l * DFF_DIM;
        const float* f2b = ffn_b2 + (size_t)l * D_T;

        gemm_mfma<0, 2><<<dim3(7, 128), 256, 0, stream>>>(seq, qkvwt[l], qb, qkvb,
                                                          TB, 816, D_T);
        attn_mfma<<<B_DIM * H_DIM, 256, 0, stream>>>(qkvb, lens, attno);
        gemm_mfma<0, 0><<<dim3(3, 128), 256, 0, stream>>>(attno, outwt[l], ob, tmp,
                                                          TB, D_T, D_T);
        ln_kernel<<<TB / 4, 256, 0, stream>>>(seq, tmp, l1w, l1b, x1);
        gemm_mfma<1, 1><<<dim3(8, 128), 256, 0, stream>>>(x1, f1wt[l], f1b, h1,
                                                          TB, DFF_DIM, D_T);
        gemm_mfma<0, 0><<<dim3(3, 128), 256, 0, stream>>>(h1, f2wt[l], f2b, tmp,
                                                          TB, D_T, DFF_DIM);
        ln_kernel<<<TB / 4, 256, 0, stream>>>(x1, tmp, l2w, l2b, seq);
    }

    pool_partial<<<dim3(8, B_DIM), 256, 0, stream>>>(seq, lens, ppart);
    head_kernel<<<B_DIM, 256, 0, stream>>>(ppart, lens, mlp_w1, mlp_b1,
                                           mlp_w2, mlp_b2, outp);
}

// Round 8
// 316.899 us; speedup vs baseline: 3.4754x; 1.0613x over previous
//
#include <hip/hip_runtime.h>
#include <math.h>

#define T_DIM 256
#define B_DIM 32
#define N_DIM 64
#define F_INF 1024
#define D_T 272
#define D_TP 288   // K-padded row stride for 272-wide activations
#define H_DIM 8
#define DH_DIM 34
#define DFF_DIM 1024

typedef unsigned int uint;
typedef short bf16x8 __attribute__((ext_vector_type(8)));
typedef float f32x4 __attribute__((ext_vector_type(4)));

__device__ __forceinline__ ushort f2bf(float f) {
    uint u = __float_as_uint(f);
    uint r = (u + 0x7fffu + ((u >> 16) & 1u)) >> 16;
    return (ushort)r;
}
__device__ __forceinline__ float bf2f(ushort u) {
    return __uint_as_float(((uint)u) << 16);
}

// ---------------------------------------------------------------------------
// xn[b,n,t*4+d] = relu(x[t,b,n] * R_u[n*4+d])  -> bf16
// ---------------------------------------------------------------------------
__global__ void xn_kernel(const float* __restrict__ x, const float* __restrict__ Ru,
                          ushort* __restrict__ xn) {
    int idx = blockIdx.x * blockDim.x + threadIdx.x;
    if (idx >= B_DIM * N_DIM * F_INF) return;
    int f = idx & 1023;
    int bn = idx >> 10;
    int n = bn & 63;
    int b = bn >> 6;
    int t = f >> 2;
    int d = f & 3;
    float v = x[(t * B_DIM + b) * N_DIM + n] * Ru[(n << 2) + d];
    xn[idx] = f2bf(fmaxf(v, 0.0f));
}

// ---------------------------------------------------------------------------
// tiled weight convert+transpose: f32 [K,N] -> bf16 [N,Kp] (Kp-padded rows,
// pad pre-zeroed by memset). 16x16 LDS tiles, coalesced both sides.
// ---------------------------------------------------------------------------
struct WT {
    int tstart[11];
    const float* src[10];
    ushort* dst[10];
    int K[10];
    int N[10];
    int Kp[10];
    int ntn[10];  // N/16
};
__global__ __launch_bounds__(256) void wconv_tiled(WT s) {
    int tile = blockIdx.x;
    int seg = 0;
    while (seg < 9 && tile >= s.tstart[seg + 1]) ++seg;
    int ti = tile - s.tstart[seg];
    int ntn = s.ntn[seg];
    int tk = ti / ntn, tn = ti - tk * ntn;
    int K = s.K[seg], N = s.N[seg], Kp = s.Kp[seg];
    __shared__ float t[16][17];
    int ty = threadIdx.x >> 4, tx = threadIdx.x & 15;
    t[ty][tx] = s.src[seg][(size_t)(tk * 16 + ty) * N + tn * 16 + tx];
    __syncthreads();
    s.dst[seg][(size_t)(tn * 16 + ty) * Kp + tk * 16 + tx] = f2bf(t[tx][ty]);
    (void)K;
}

// ---------------------------------------------------------------------------
// MFMA bf16 GEMM, 3-deep pipeline with counted vmcnt (T3+T4).
// BM=64, BN=128, BK=32; 256 thr = 4 waves (2x2), wave tile 32x64.
// K must be %32 (all operands K-padded). Kstride = row stride of A/Bt.
// OUT_MODE: 0 = f32 flat, 1 = bf16 flat, 2 = bf16 head-padded QKV layout,
//           3 = f32 split-K partial (blockIdx.y = ksplit, m0 = 0, no bias).
// ---------------------------------------------------------------------------
template <int ACT, int OUT_MODE>
__global__ __launch_bounds__(256) void gemm_mfma(const ushort* __restrict__ A,
                                                 const ushort* __restrict__ Bt,
                                                 const float* __restrict__ bias,
                                                 void* __restrict__ Cout,
                                                 int M, int N, int K, int Kstride) {
    __shared__ ushort As[3][64 * 32];
    __shared__ ushort Bs[3][128 * 32];
    const int tid = threadIdx.x;
    const int m0 = (OUT_MODE == 3) ? 0 : blockIdx.y * 64;
    const int n0 = blockIdx.x * 128;
    if (OUT_MODE == 3) {
        A += (size_t)blockIdx.y * K;
        Bt += (size_t)blockIdx.y * K;
    }
    const int w = tid >> 6, lane = tid & 63;
    const int wr = w >> 1, wc = w & 1;
    const int lr = lane & 15, lk = lane >> 4;

    const int ns = K >> 5;

    const int ra = w * 16 + (lane >> 2);
    const int ca = (((lane & 3) ^ ((ra >> 1) & 3)) << 3);
    int gma = m0 + ra; if (gma > M - 1) gma = M - 1;
    const ushort* gA = &A[(size_t)gma * Kstride + ca];
    const int rb0 = w * 32 + (lane >> 2);
    const int cb0 = (((lane & 3) ^ ((rb0 >> 1) & 3)) << 3);
    const int rb1 = rb0 + 16;
    const int cb1 = (((lane & 3) ^ ((rb1 >> 1) & 3)) << 3);
    int gnb0 = n0 + rb0; if (gnb0 > N - 1) gnb0 = N - 1;
    int gnb1 = n0 + rb1; if (gnb1 > N - 1) gnb1 = N - 1;
    const ushort* gB0 = &Bt[(size_t)gnb0 * Kstride + cb0];
    const ushort* gB1 = &Bt[(size_t)gnb1 * Kstride + cb1];

    f32x4 acc[2][4];
#pragma unroll
    for (int i = 0; i < 2; ++i)
#pragma unroll
        for (int j = 0; j < 4; ++j) acc[i][j] = (f32x4){0.f, 0.f, 0.f, 0.f};

    auto stage = [&](int buf, int s) {
        const int k0 = s << 5;
        __builtin_amdgcn_global_load_lds(
            (const __attribute__((address_space(1))) void*)(gA + k0),
            (__attribute__((address_space(3))) void*)(&As[buf][w * 512]), 16, 0, 0);
        __builtin_amdgcn_global_load_lds(
            (const __attribute__((address_space(1))) void*)(gB0 + k0),
            (__attribute__((address_space(3))) void*)(&Bs[buf][w * 1024]), 16, 0, 0);
        __builtin_amdgcn_global_load_lds(
            (const __attribute__((address_space(1))) void*)(gB1 + k0),
            (__attribute__((address_space(3))) void*)(&Bs[buf][w * 1024 + 512]), 16, 0, 0);
    };

    // prologue: two stages in flight
    stage(0, 0);
    stage(1, 1);
    asm volatile("s_waitcnt vmcnt(3)" ::: "memory");   // stage 0 complete
    __builtin_amdgcn_sched_barrier(0);
    __builtin_amdgcn_s_barrier();
    __builtin_amdgcn_sched_barrier(0);

    int cur = 0;
    for (int s = 0; s < ns; ++s) {
        int stg = cur + 2; if (stg >= 3) stg -= 3;
        if (s + 2 < ns) stage(stg, s + 2);

        bf16x8 af[2], bf[4];
#pragma unroll
        for (int mt = 0; mt < 2; ++mt) {
            int row = wr * 32 + mt * 16 + lr;
            int ch = lk ^ ((row >> 1) & 3);
            af[mt] = *reinterpret_cast<const bf16x8*>(&As[cur][row * 32 + ch * 8]);
        }
#pragma unroll
        for (int nt = 0; nt < 4; ++nt) {
            int row = wc * 64 + nt * 16 + lr;
            int ch = lk ^ ((row >> 1) & 3);
            bf[nt] = *reinterpret_cast<const bf16x8*>(&Bs[cur][row * 32 + ch * 8]);
        }
        __builtin_amdgcn_s_setprio(1);
#pragma unroll
        for (int mt = 0; mt < 2; ++mt)
#pragma unroll
            for (int nt = 0; nt < 4; ++nt)
                acc[mt][nt] = __builtin_amdgcn_mfma_f32_16x16x32_bf16(
                    af[mt], bf[nt], acc[mt][nt], 0, 0, 0);
        __builtin_amdgcn_s_setprio(0);

        if (s + 1 < ns) {
            if (s + 2 < ns)
                asm volatile("s_waitcnt vmcnt(3)" ::: "memory");  // next buf ready
            else
                asm volatile("s_waitcnt vmcnt(0)" ::: "memory");
            __builtin_amdgcn_sched_barrier(0);
            __builtin_amdgcn_s_barrier();
            __builtin_amdgcn_sched_barrier(0);
        }
        cur = (cur == 2) ? 0 : cur + 1;
    }

    // epilogue: D layout col=lane&15, row=(lane>>4)*4+reg
#pragma unroll
    for (int nt = 0; nt < 4; ++nt) {
        int col = n0 + wc * 64 + nt * 16 + lr;
        if (col >= N) continue;
        float bv = (OUT_MODE == 3) ? 0.f : bias[col];
        int g = 0, dcol = 0;
        if (OUT_MODE == 2) { g = col / 34; dcol = col - g * 34; }
#pragma unroll
        for (int mt = 0; mt < 2; ++mt) {
#pragma unroll
            for (int r = 0; r < 4; ++r) {
                int row = m0 + wr * 32 + mt * 16 + lk * 4 + r;
                if (row >= M) continue;
                float v = acc[mt][nt][r] + bv;
                if (ACT == 1) v = fmaxf(v, 0.0f);
                if (OUT_MODE == 0)
                    ((float*)Cout)[(size_t)row * N + col] = v;
                else if (OUT_MODE == 1)
                    ((ushort*)Cout)[(size_t)row * N + col] = f2bf(v);
                else if (OUT_MODE == 2)
                    ((ushort*)Cout)[(size_t)row * 960 + g * 40 + dcol] = f2bf(v);
                else
                    ((float*)Cout)[(size_t)(blockIdx.y * M + row) * N + col] = v;
            }
        }
    }
}

// ---------------------------------------------------------------------------
// s1[b,g] = (1/64) * sum_n val1[(b*64+n), g]; bf16 in (vectorized), bf16 out.
// ---------------------------------------------------------------------------
__global__ __launch_bounds__(256) void reduce_s1_kernel(const ushort* __restrict__ val1,
                                                        ushort* __restrict__ s1) {
    int idx = blockIdx.x * 256 + threadIdx.x;
    if (idx >= B_DIM * 128) return;
    int b = idx >> 7;
    int g0 = (idx & 127) << 3;
    const ushort* base = val1 + (size_t)(b << 6) * F_INF + g0;
    float s[8] = {0.f, 0.f, 0.f, 0.f, 0.f, 0.f, 0.f, 0.f};
    for (int n = 0; n < 64; ++n) {
        bf16x8 v = *reinterpret_cast<const bf16x8*>(base + (size_t)n * F_INF);
#pragma unroll
        for (int e = 0; e < 8; ++e) s[e] += bf2f((ushort)v[e]);
    }
    ushort o[8];
#pragma unroll
    for (int e = 0; e < 8; ++e) o[e] = f2bf(s[e] * (1.0f / 64.0f));
    *reinterpret_cast<uint4*>(&s1[(size_t)idx * 8]) = *reinterpret_cast<uint4*>(o);
}

// ---------------------------------------------------------------------------
// prop2 split-K reduce: out2[b,g] = relu(sum_ks part[ks][b][g] + bv2[g])
// ---------------------------------------------------------------------------
__global__ __launch_bounds__(256) void reduce_p2_kernel(const float* __restrict__ part,
                                                        const float* __restrict__ bv2,
                                                        float* __restrict__ out2) {
    int idx = blockIdx.x * 256 + threadIdx.x;
    if (idx >= B_DIM * F_INF) return;
    int g = idx & 1023;
    float s = bv2[g];
#pragma unroll
    for (int ks = 0; ks < 4; ++ks) s += part[(size_t)ks * B_DIM * F_INF + idx];
    out2[idx] = fmaxf(s, 0.f);
}

// ---------------------------------------------------------------------------
// seq[t,b,c] (stride 288) = c<256 ? out2 : c<272 ? PE : 0   -> bf16
// ---------------------------------------------------------------------------
__global__ void seq_kernel(const float* __restrict__ out2, const float* __restrict__ times,
                           ushort* __restrict__ seq) {
    int idx = blockIdx.x * blockDim.x + threadIdx.x;
    if (idx >= T_DIM * B_DIM * D_TP) return;
    int c = idx % D_TP;
    int tb = idx / D_TP;
    float v;
    if (c < 256) {
        v = out2[(tb % B_DIM) * 1024 + ((tb / B_DIM) << 2) + (c & 3)];
    } else if (c < 272) {
        int s = c - 256;
        int sc = (s < 8) ? s : s - 8;
        float arg = times[tb] * exp2f(-8.0f * (float)sc * (1.0f / 7.0f));
        v = (s < 8) ? sinf(arg) : cosf(arg);
    } else {
        v = 0.f;
    }
    seq[idx] = f2bf(v);
}

// ---------------------------------------------------------------------------
// one-time pad zeroing: qkvb head-pads + x1/attno K-pad columns (272..287).
// ---------------------------------------------------------------------------
__global__ void init_pads_kernel(uint* __restrict__ qkvb, uint* __restrict__ x1,
                                 uint* __restrict__ attno) {
    const int TB = T_DIM * B_DIM;
    int idx = blockIdx.x * blockDim.x + threadIdx.x;
    if (idx < TB * 8) {
        int row = idx >> 3, q = idx & 7;
        x1[(size_t)row * 144 + 136 + q] = 0;  // 288 ushorts = 144 dwords; pad @136
        attno[(size_t)row * 144 + 136 + q] = 0;
        return;
    }
    idx -= TB * 8;
    if (idx >= TB * 72) return;
    int row = idx / 72;
    int r = idx - row * 72;
    int g = r / 3, q = r - g * 3;
    qkvb[(size_t)row * 480 + g * 20 + 17 + q] = 0;
}

// ---------------------------------------------------------------------------
// MFMA flash attention (validated round 6; attno stride now 288).
// ---------------------------------------------------------------------------
__global__ __launch_bounds__(256) void attn_mfma(const ushort* __restrict__ qkv,
                                                 const int* __restrict__ lengths,
                                                 ushort* __restrict__ attno) {
    const int b = blockIdx.x >> 3;
    const int h = blockIdx.x & 7;
    const int tid = threadIdx.x;
    const int w = tid >> 6, lane = tid & 63;
    const int lr = lane & 15, lk = lane >> 4;
    __shared__ ushort Ks[2][64 * 40];
    __shared__ ushort Vt[2][48 * 72];
    __shared__ ushort Ps[4][64 * 72];
    const int len = lengths[b];
    const float scale = 0.1714985851f;  // 1/sqrt(34)
    const bf16x8 zv = {0, 0, 0, 0, 0, 0, 0, 0};

    for (int i = tid; i < 2 * 8 * 72; i += 256) {
        int bb = i / 576;
        Vt[bb][40 * 72 + (i - bb * 576)] = 0;
    }

    const int srow0 = tid / 5, sch0 = tid - srow0 * 5;
    const int srow1 = (tid + 256) / 5, sch1 = (tid + 256) - srow1 * 5;
    const int sjp0 = (srow0 & 15) * 4 + (srow0 >> 4);
    const int sjp1 = (srow1 & 15) * 4 + (srow1 >> 4);
    const bool has1 = (tid < 64);
    bf16x8 kreg0, kreg1, vreg0, vreg1;

    auto LOADS = [&](int c) {
        const ushort* b0 = &qkv[(size_t)((c * 64 + srow0) * 32 + b) * 960 + h * 40];
        kreg0 = *reinterpret_cast<const bf16x8*>(b0 + 320 + sch0 * 8);
        vreg0 = *reinterpret_cast<const bf16x8*>(b0 + 640 + sch0 * 8);
        if (has1) {
            const ushort* b1 = &qkv[(size_t)((c * 64 + srow1) * 32 + b) * 960 + h * 40];
            kreg1 = *reinterpret_cast<const bf16x8*>(b1 + 320 + sch1 * 8);
            vreg1 = *reinterpret_cast<const bf16x8*>(b1 + 640 + sch1 * 8);
        }
    };
    auto WRITES = [&](int buf) {
        *reinterpret_cast<bf16x8*>(&Ks[buf][srow0 * 40 + sch0 * 8]) = kreg0;
#pragma unroll
        for (int e = 0; e < 8; ++e) Vt[buf][(sch0 * 8 + e) * 72 + sjp0] = (ushort)vreg0[e];
        if (has1) {
            *reinterpret_cast<bf16x8*>(&Ks[buf][srow1 * 40 + sch1 * 8]) = kreg1;
#pragma unroll
            for (int e = 0; e < 8; ++e) Vt[buf][(sch1 * 8 + e) * 72 + sjp1] = (ushort)vreg1[e];
        }
    };

    bf16x8 qf0[4], qf1[4];
#pragma unroll
    for (int it = 0; it < 4; ++it) {
        int t = w * 64 + it * 16 + lr;
        const ushort* qrow = &qkv[(size_t)(t * 32 + b) * 960 + h * 40];
        qf0[it] = *reinterpret_cast<const bf16x8*>(qrow + lk * 8);
        qf1[it] = (lk == 0) ? *reinterpret_cast<const bf16x8*>(qrow + 32) : zv;
    }

    f32x4 oacc[4][3];
#pragma unroll
    for (int it = 0; it < 4; ++it)
#pragma unroll
        for (int dt = 0; dt < 3; ++dt) oacc[it][dt] = (f32x4){0.f, 0.f, 0.f, 0.f};
    float m[4][4], l[4][4];
#pragma unroll
    for (int it = 0; it < 4; ++it)
#pragma unroll
        for (int r = 0; r < 4; ++r) { m[it][r] = -1e30f; l[it][r] = 0.f; }

    const int nchunks = (len + 63) >> 6;
    LOADS(0);
    WRITES(0);
    __syncthreads();

    int cur = 0;
    for (int c = 0; c < nchunks; ++c) {
        const bool pre = (c + 1 < nchunks);
        if (pre) LOADS(c + 1);

        bf16x8 kf0[4], kf1[4];
#pragma unroll
        for (int jt = 0; jt < 4; ++jt) {
            int j = jt * 16 + lr;
            kf0[jt] = *reinterpret_cast<const bf16x8*>(&Ks[cur][j * 40 + lk * 8]);
            kf1[jt] = (lk == 0) ? *reinterpret_cast<const bf16x8*>(&Ks[cur][j * 40 + 32]) : zv;
        }

        const bool tail = (c * 64 + 64 > len);
#pragma unroll
        for (int it = 0; it < 4; ++it) {
            f32x4 sacc[4];
#pragma unroll
            for (int jt = 0; jt < 4; ++jt) sacc[jt] = (f32x4){0.f, 0.f, 0.f, 0.f};
            __builtin_amdgcn_s_setprio(1);
#pragma unroll
            for (int jt = 0; jt < 4; ++jt) {
                sacc[jt] = __builtin_amdgcn_mfma_f32_16x16x32_bf16(qf0[it], kf0[jt],
                                                                   sacc[jt], 0, 0, 0);
                sacc[jt] = __builtin_amdgcn_mfma_f32_16x16x32_bf16(qf1[it], kf1[jt],
                                                                   sacc[jt], 0, 0, 0);
            }
            __builtin_amdgcn_s_setprio(0);
            float cm[4] = {-1e30f, -1e30f, -1e30f, -1e30f};
#pragma unroll
            for (int jt = 0; jt < 4; ++jt) {
                bool dead = tail && (c * 64 + jt * 16 + lr >= len);
#pragma unroll
                for (int r = 0; r < 4; ++r) {
                    float sv = dead ? -1e30f : sacc[jt][r];
                    sacc[jt][r] = sv;
                    cm[r] = fmaxf(cm[r], sv);
                }
            }
#pragma unroll
            for (int mask = 1; mask <= 8; mask <<= 1)
#pragma unroll
                for (int r = 0; r < 4; ++r) cm[r] = fmaxf(cm[r], __shfl_xor(cm[r], mask));
#pragma unroll
            for (int r = 0; r < 4; ++r) {
                float mn = fmaxf(m[it][r], cm[r]);
                float corr = __expf((m[it][r] - mn) * scale);
                m[it][r] = mn;
                l[it][r] *= corr;
#pragma unroll
                for (int dt = 0; dt < 3; ++dt) oacc[it][dt][r] *= corr;
            }
            float ls[4] = {0.f, 0.f, 0.f, 0.f};
#pragma unroll
            for (int jt = 0; jt < 4; ++jt)
#pragma unroll
                for (int r = 0; r < 4; ++r) {
                    float e = __expf((sacc[jt][r] - m[it][r]) * scale);
                    sacc[jt][r] = e;
                    ls[r] += e;
                }
#pragma unroll
            for (int mask = 1; mask <= 8; mask <<= 1)
#pragma unroll
                for (int r = 0; r < 4; ++r) ls[r] += __shfl_xor(ls[r], mask);
#pragma unroll
            for (int r = 0; r < 4; ++r) l[it][r] += ls[r];
#pragma unroll
            for (int r = 0; r < 4; ++r) {
                int i = it * 16 + lk * 4 + r;
                uint u0 = (uint)f2bf(sacc[0][r]) | ((uint)f2bf(sacc[1][r]) << 16);
                uint u1 = (uint)f2bf(sacc[2][r]) | ((uint)f2bf(sacc[3][r]) << 16);
                uint2 pk = make_uint2(u0, u1);
                *reinterpret_cast<uint2*>(&Ps[w][i * 72 + lr * 4]) = pk;
            }
        }

        bf16x8 vf[3][2], pf[4][2];
#pragma unroll
        for (int dt = 0; dt < 3; ++dt)
#pragma unroll
            for (int ks = 0; ks < 2; ++ks)
                vf[dt][ks] = *reinterpret_cast<const bf16x8*>(
                    &Vt[cur][(dt * 16 + lr) * 72 + ks * 32 + lk * 8]);
#pragma unroll
        for (int it = 0; it < 4; ++it)
#pragma unroll
            for (int ks = 0; ks < 2; ++ks)
                pf[it][ks] = *reinterpret_cast<const bf16x8*>(
                    &Ps[w][(it * 16 + lr) * 72 + ks * 32 + lk * 8]);
        __builtin_amdgcn_s_setprio(1);
#pragma unroll
        for (int it = 0; it < 4; ++it)
#pragma unroll
            for (int dt = 0; dt < 3; ++dt)
#pragma unroll
                for (int ks = 0; ks < 2; ++ks)
                    oacc[it][dt] = __builtin_amdgcn_mfma_f32_16x16x32_bf16(
                        pf[it][ks], vf[dt][ks], oacc[it][dt], 0, 0, 0);
        __builtin_amdgcn_s_setprio(0);

        if (pre) WRITES(cur ^ 1);
        __syncthreads();
        cur ^= 1;
    }

#pragma unroll
    for (int it = 0; it < 4; ++it)
#pragma unroll
        for (int r = 0; r < 4; ++r) {
            float inv = 1.0f / l[it][r];
            int t = w * 64 + it * 16 + lk * 4 + r;
            ushort* orow = &attno[(size_t)(t * 32 + b) * D_TP + h * 34];
#pragma unroll
            for (int dt = 0; dt < 3; ++dt) {
                int d = dt * 16 + lr;
                if (d < 34) orow[d] = f2bf(oacc[it][dt][r] * inv);
            }
        }
}

// ---------------------------------------------------------------------------
// LN: out = LN(bf16 X + f32 Y) * w + b  -> bf16. 4 rows/block, wave per row.
// X/out stride 288, Y stride 272.
// ---------------------------------------------------------------------------
__global__ __launch_bounds__(256) void ln_kernel(const ushort* __restrict__ X,
                                                 const float* __restrict__ Y,
                                                 const float* __restrict__ w,
                                                 const float* __restrict__ bsh,
                                                 ushort* __restrict__ out) {
    int row = blockIdx.x * 4 + (threadIdx.x >> 6);
    int lane = threadIdx.x & 63;
    const ushort* xr = X + (size_t)row * D_TP;
    const float* yr = Y + (size_t)row * D_T;
    float v[5];
    float sum = 0.f, sumsq = 0.f;
#pragma unroll
    for (int k = 0; k < 5; ++k) {
        int c = lane + k * 64;
        float t = 0.f;
        if (c < D_T) t = bf2f(xr[c]) + yr[c];
        v[k] = t;
        sum += t;
        sumsq += t * t;
    }
#pragma unroll
    for (int off = 32; off; off >>= 1) {
        sum += __shfl_down(sum, off);
        sumsq += __shfl_down(sumsq, off);
    }
    sum = __shfl(sum, 0);
    sumsq = __shfl(sumsq, 0);
    float mu = sum * (1.0f / D_T);
    float var = sumsq * (1.0f / D_T) - mu * mu;
    float inv = 1.0f / sqrtf(var + 1e-5f);
    ushort* orow = out + (size_t)row * D_TP;
#pragma unroll
    for (int k = 0; k < 5; ++k) {
        int c = lane + k * 64;
        if (c < D_T) orow[c] = f2bf((v[k] - mu) * inv * w[c] + bsh[c]);
    }
}

// ---------------------------------------------------------------------------
// pool stage 1: partial[chunk][b][272] over 32 t-rows (seq stride 288).
// ---------------------------------------------------------------------------
__global__ __launch_bounds__(256) void pool_partial(const ushort* __restrict__ seq,
                                                    const int* __restrict__ lengths,
                                                    float* __restrict__ partial) {
    const int chunk = blockIdx.x;
    const int b = blockIdx.y;
    const int tid = threadIdx.x;
    if (tid >= 136) return;
    const int len = lengths[b];
    float s0 = 0.f, s1 = 0.f;
    int t0 = chunk * 32;
    int tmax = len - t0;
    if (tmax > 32) tmax = 32;
#pragma unroll 4
    for (int r = 0; r < tmax; ++r) {
        uint u = *reinterpret_cast<const uint*>(
            &seq[(size_t)((t0 + r) * B_DIM + b) * D_TP + tid * 2]);
        s0 += __uint_as_float(u << 16);
        s1 += __uint_as_float(u & 0xffff0000u);
    }
    float* p = &partial[(size_t)(chunk * B_DIM + b) * D_T + tid * 2];
    p[0] = s0;
    p[1] = s1;
}

// ---------------------------------------------------------------------------
// head: agg = (sum partials)/(len+1); hid = relu(agg@w1+b1);
// logits = hid@w2+b2; softmax. One block per b.
// ---------------------------------------------------------------------------
__global__ __launch_bounds__(256) void head_kernel(const float* __restrict__ partial,
                                                   const int* __restrict__ lengths,
                                                   const float* __restrict__ w1,
                                                   const float* __restrict__ b1,
                                                   const float* __restrict__ w2,
                                                   const float* __restrict__ b2,
                                                   float* __restrict__ out) {
    const int b = blockIdx.x;
    const int tid = threadIdx.x;
    const int len = lengths[b];
    __shared__ float agg_s[D_T];
    __shared__ float hid[D_T];
    float inv = 1.0f / (float)(len + 1);
    for (int c = tid; c < D_T; c += 256) {
        float s = 0.f;
#pragma unroll
        for (int ch = 0; ch < 8; ++ch)
            s += partial[(size_t)(ch * B_DIM + b) * D_T + c];
        agg_s[c] = s * inv;
    }
    __syncthreads();
    for (int j = tid; j < D_T; j += 256) {
        float acc = b1[j];
        for (int k = 0; k < D_T; ++k) acc += agg_s[k] * w1[k * D_T + j];
        hid[j] = fmaxf(acc, 0.f);
    }
    __syncthreads();
    if (tid < 64) {
        float l0 = 0.f, l1 = 0.f;
        for (int k = tid; k < D_T; k += 64) {
            float hv = hid[k];
            l0 += hv * w2[k * 2 + 0];
            l1 += hv * w2[k * 2 + 1];
        }
#pragma unroll
        for (int off = 32; off; off >>= 1) {
            l0 += __shfl_down(l0, off);
            l1 += __shfl_down(l1, off);
        }
        if (tid == 0) {
            l0 += b2[0];
            l1 += b2[1];
            float mx = fmaxf(l0, l1);
            float e0 = expf(l0 - mx), e1 = expf(l1 - mx);
            float nrm = 1.0f / (e0 + e1);
            out[b * 2 + 0] = e0 * nrm;
            out[b * 2 + 1] = e1 * nrm;
        }
    }
}

// ---------------------------------------------------------------------------
extern "C" void kernel_launch(void* const* d_in, const int* in_sizes, int n_in,
                              void* d_out, int out_size, void* d_ws, size_t ws_size,
                              hipStream_t stream) {
    const float* x      = (const float*)d_in[0];
    const float* times  = (const float*)d_in[1];
    const int*   lens   = (const int*)d_in[2];
    const float* R_u    = (const float*)d_in[3];
    const float* Wv1    = (const float*)d_in[4];
    const float* bv1    = (const float*)d_in[5];
    const float* Wv2    = (const float*)d_in[6];
    const float* bv2    = (const float*)d_in[7];
    const float* qkv_w  = (const float*)d_in[8];
    const float* qkv_b  = (const float*)d_in[9];
    const float* out_w  = (const float*)d_in[10];
    const float* out_b  = (const float*)d_in[11];
    const float* ln1_w  = (const float*)d_in[12];
    const float* ln1_b  = (const float*)d_in[13];
    const float* ln2_w  = (const float*)d_in[14];
    const float* ln2_b  = (const float*)d_in[15];
    const float* ffn_w1 = (const float*)d_in[16];
    const float* ffn_b1 = (const float*)d_in[17];
    const float* ffn_w2 = (const float*)d_in[18];
    const float* ffn_b2 = (const float*)d_in[19];
    const float* mlp_w1 = (const float*)d_in[20];
    const float* mlp_b1 = (const float*)d_in[21];
    const float* mlp_w2 = (const float*)d_in[22];
    const float* mlp_b2 = (const float*)d_in[23];
    float* outp = (float*)d_out;

    char* base = (char*)d_ws;
    size_t used = 0;
    auto alloc = [&](size_t bytes) -> char* {
        char* p = base + used;
        used += (bytes + 255) & ~(size_t)255;
        return p;
    };
    const int TB = T_DIM * B_DIM;  // 8192

    ushort* xn    = (ushort*)alloc((size_t)2048 * 1024 * 2);
    ushort* val1  = (ushort*)alloc((size_t)2048 * 1024 * 2);
    ushort* s1    = (ushort*)alloc((size_t)32 * 1024 * 2);
    float*  p2p   = (float*) alloc((size_t)4 * 32 * 1024 * 4);
    float*  out2  = (float*) alloc((size_t)32 * 1024 * 4);
    ushort* seq   = (ushort*)alloc((size_t)TB * D_TP * 2);
    ushort* qkvb  = (ushort*)alloc((size_t)TB * 960 * 2);
    ushort* attno = (ushort*)alloc((size_t)TB * D_TP * 2);
    float*  tmp   = (float*) alloc((size_t)TB * D_T * 4);
    ushort* x1    = (ushort*)alloc((size_t)TB * D_TP * 2);
    ushort* h1    = (ushort*)alloc((size_t)TB * DFF_DIM * 2);
    float*  ppart = (float*) alloc((size_t)8 * B_DIM * D_T * 4);
    ushort* wv1t  = (ushort*)alloc((size_t)1024 * 1024 * 2);
    ushort* wv2t  = (ushort*)alloc((size_t)1024 * 1024 * 2);
    ushort* qkvwt[2]; ushort* outwt[2]; ushort* f1wt[2]; ushort* f2wt[2];
    for (int l = 0; l < 2; ++l) {
        qkvwt[l] = (ushort*)alloc((size_t)816 * D_TP * 2);
        outwt[l] = (ushort*)alloc((size_t)272 * D_TP * 2);
        f1wt[l]  = (ushort*)alloc((size_t)1024 * D_TP * 2);
        f2wt[l]  = (ushort*)alloc((size_t)272 * 1024 * 2);
    }
    if (used > ws_size) return;

    // zero the K-padded weight buffers (pad cols must be 0), then transpose.
    for (int l = 0; l < 2; ++l) {
        hipMemsetAsync(qkvwt[l], 0, (size_t)816 * D_TP * 2, stream);
        hipMemsetAsync(outwt[l], 0, (size_t)272 * D_TP * 2, stream);
        hipMemsetAsync(f1wt[l], 0, (size_t)1024 * D_TP * 2, stream);
    }
    {
        WT segs;
        const float* srcs[10] = {Wv1, Wv2,
                                 qkv_w, out_w, ffn_w1, ffn_w2,
                                 qkv_w + (size_t)272 * 816, out_w + (size_t)272 * 272,
                                 ffn_w1 + (size_t)272 * 1024, ffn_w2 + (size_t)1024 * 272};
        ushort* dsts[10] = {wv1t, wv2t, qkvwt[0], outwt[0], f1wt[0], f2wt[0],
                            qkvwt[1], outwt[1], f1wt[1], f2wt[1]};
        int Ksz[10] = {1024, 1024, 272, 272, 272, 1024, 272, 272, 272, 1024};
        int Nsz[10] = {1024, 1024, 816, 272, 1024, 272, 816, 272, 1024, 272};
        int Kpd[10] = {1024, 1024, D_TP, D_TP, D_TP, 1024, D_TP, D_TP, D_TP, 1024};
        int acc = 0;
        for (int i = 0; i < 10; ++i) {
            segs.tstart[i] = acc;
            segs.src[i] = srcs[i];
            segs.dst[i] = dsts[i];
            segs.K[i] = Ksz[i];
            segs.N[i] = Nsz[i];
            segs.Kp[i] = Kpd[i];
            segs.ntn[i] = Nsz[i] / 16;
            acc += (Ksz[i] / 16) * (Nsz[i] / 16);
        }
        segs.tstart[10] = acc;
        wconv_tiled<<<acc, 256, 0, stream>>>(segs);
    }

    {
        int n = B_DIM * N_DIM * F_INF;
        xn_kernel<<<(n + 255) / 256, 256, 0, stream>>>(x, R_u, xn);
    }

    // prop1: [2048,1024]@[1024,1024] -> bf16
    gemm_mfma<1, 1><<<dim3(8, 32), 256, 0, stream>>>(xn, wv1t, bv1, val1,
                                                     2048, 1024, 1024, 1024);
    reduce_s1_kernel<<<16, 256, 0, stream>>>(val1, s1);
    // prop2 split-K x4: partials [4][32][1024]
    gemm_mfma<0, 3><<<dim3(8, 4), 256, 0, stream>>>(s1, wv2t, nullptr, p2p,
                                                    32, 1024, 256, 1024);
    reduce_p2_kernel<<<128, 256, 0, stream>>>(p2p, bv2, out2);

    {
        int n = TB * D_TP;
        seq_kernel<<<(n + 255) / 256, 256, 0, stream>>>(out2, times, seq);
    }
    {
        int n = TB * 8 + TB * 72;
        init_pads_kernel<<<(n + 255) / 256, 256, 0, stream>>>((uint*)qkvb, (uint*)x1,
                                                              (uint*)attno);
    }

    for (int l = 0; l < 2; ++l) {
        const float* qb  = qkv_b + (size_t)l * 816;
        const float* ob  = out_b + (size_t)l * D_T;
        const float* l1w = ln1_w + (size_t)l * D_T;
        const float* l1b = ln1_b + (size_t)l * D_T;
        const float* l2w = ln2_w + (size_t)l * D_T;
        const float* l2b = ln2_b + (size_t)l * D_T;
        const float* f1b = ffn_b1 + (size_t)l * DFF_DIM;
        const float* f2b = ffn_b2 + (size_t)l * D_T;

        // QKV: [8192,288]@[288,816] -> bf16 head-padded
        gemm_mfma<0, 2><<<dim3(7, 128), 256, 0, stream>>>(seq, qkvwt[l], qb, qkvb,
                                                          TB, 816, D_TP, D_TP);
        attn_mfma<<<B_DIM * H_DIM, 256, 0, stream>>>(qkvb, lens, attno);
        // out-proj: [8192,288]@[288,272] -> f32
        gemm_mfma<0, 0><<<dim3(3, 128), 256, 0, stream>>>(attno, outwt[l], ob, tmp,
                                                          TB, D_T, D_TP, D_TP);
        ln_kernel<<<TB / 4, 256, 0, stream>>>(seq, tmp, l1w, l1b, x1);
        // FFN1: relu([8192,288]@[288,1024]) -> bf16
        gemm_mfma<1, 1><<<dim3(8, 128), 256, 0, stream>>>(x1, f1wt[l], f1b, h1,
                                                          TB, DFF_DIM, D_TP, D_TP);
        // FFN2: [8192,1024]@[1024,272] -> f32
        gemm_mfma<0, 0><<<dim3(3, 128), 256, 0, stream>>>(h1, f2wt[l], f2b, tmp,
                                                          TB, D_T, 1024, 1024);
        ln_kernel<<<TB / 4, 256, 0, stream>>>(x1, tmp, l2w, l2b, seq);
    }

    pool_partial<<<dim3(8, B_DIM), 256, 0, stream>>>(seq, lens, ppart);
    head_kernel<<<B_DIM, 256, 0, stream>>>(ppart, lens, mlp_w1, mlp_b1,
                                           mlp_w2, mlp_b2, outp);
}